// Round 2
// baseline (2948.625 us; speedup 1.0000x reference)
//
#include <hip/hip_runtime.h>
#include <hip/hip_bf16.h>

#define EE 160000
#define EQ 40000   // EE/4
#define NNODES 10000

using bf16 = __hip_bfloat16;

__device__ __forceinline__ float silu_f(float x) { return x / (1.0f + __expf(-x)); }
__device__ __forceinline__ float b2f(bf16 v) { return __bfloat162float(v); }
__device__ __forceinline__ bf16 f2b(float v) { return __float2bfloat16(v); }

// pack two f32 -> bf16x2 word (RNE), unpack back
__device__ __forceinline__ unsigned bfbits(float v) {
    union { float f; unsigned u; } a; a.f = v;
    return (a.u + 0x7fffu + ((a.u >> 16) & 1u)) >> 16;
}
__device__ __forceinline__ unsigned pack2(float a, float b) {
    return bfbits(a) | (bfbits(b) << 16);
}
__device__ __forceinline__ void unpack2(unsigned u, float& a, float& b) {
    union { unsigned x; float f; } lo, hi;
    lo.x = u << 16; hi.x = u & 0xffff0000u;
    a = lo.f; b = hi.f;
}

// constants: 1/(16*sqrt(8)), 0.5/sqrt(8), 1/sqrt(8)
#define INV_AVGN_SQM 0.02209708691207961f
#define HALF_INV_SQM 0.17677669529663687f
#define INV_SQM      0.35355339059327373f

// ---------------------------------------------------------------------------
// kA: tb-MLP 16->128->128->128 + cutoff + env-MLP 128->48, chunked accumul.
// 128 thr/block; h in per-thread LDS column (packed bf16x2, 32KB). No barriers.
// ---------------------------------------------------------------------------
__global__ __launch_bounds__(128, 1) void kA(
    const float* __restrict__ ea, const float* __restrict__ eemb,
    const float* __restrict__ nat, const float* __restrict__ elen,
    const float* __restrict__ w0, const float* __restrict__ w1,
    const float* __restrict__ w2, const float* __restrict__ wm0,
    const int* __restrict__ eidx,
    unsigned* __restrict__ latfT, unsigned* __restrict__ winiT,
    bf16* __restrict__ eaT, float* __restrict__ cutb, float* __restrict__ env0)
{
    __shared__ unsigned hbuf[64 * 128];
    const int tid = threadIdx.x;
    const int e = blockIdx.x * 128 + tid;
    const int ctr = eidx[e];
    const int ngb = eidx[EE + e];

    float tin[16];
#pragma unroll
    for (int k = 0; k < 4; k++) tin[k] = nat[ctr * 4 + k];
#pragma unroll
    for (int k = 0; k < 4; k++) tin[4 + k] = nat[ngb * 4 + k];
#pragma unroll
    for (int k = 0; k < 8; k++) tin[8 + k] = eemb[e * 8 + k];

    const float x = elen[e];
    const float x2 = x * x, x4 = x2 * x2, x6 = x4 * x2, x7 = x6 * x, x8 = x7 * x;
    float cutv = 1.0f - 28.0f * x6 + 48.0f * x7 - 21.0f * x8;
    cutv = (x < 1.0f) ? cutv : 0.0f;
    cutb[e] = cutv;

    // stage 0: h0 = silu(tin @ w0) -> hbuf
#pragma unroll
    for (int jc = 0; jc < 4; jc++) {
        float a[32];
#pragma unroll
        for (int j = 0; j < 32; j++) a[j] = 0.0f;
#pragma unroll
        for (int k = 0; k < 16; k++) {
            const float v = tin[k];
            const float* r = w0 + k * 128 + jc * 32;
#pragma unroll
            for (int j = 0; j < 32; j++) a[j] = fmaf(v, r[j], a[j]);
        }
#pragma unroll
        for (int i = 0; i < 16; i++)
            hbuf[(jc * 16 + i) * 128 + tid] = pack2(silu_f(a[2 * i]), silu_f(a[2 * i + 1]));
    }

    // stage 1: h1 = silu(h0 @ w1); defer writes of chunks 0..2 (reg buffer)
    unsigned rb[48];
#pragma unroll
    for (int jc = 0; jc < 4; jc++) {
        float a[32];
#pragma unroll
        for (int j = 0; j < 32; j++) a[j] = 0.0f;
        for (int kp = 0; kp < 64; kp++) {
            float v0, v1; unpack2(hbuf[kp * 128 + tid], v0, v1);
            const float* r0 = w1 + (2 * kp) * 128 + jc * 32;
            const float* r1 = r0 + 128;
#pragma unroll
            for (int j = 0; j < 32; j++) a[j] = fmaf(v1, r1[j], fmaf(v0, r0[j], a[j]));
        }
        if (jc < 3) {
#pragma unroll
            for (int i = 0; i < 16; i++)
                rb[jc * 16 + i] = pack2(silu_f(a[2 * i]), silu_f(a[2 * i + 1]));
        } else {
#pragma unroll
            for (int i = 0; i < 16; i++)
                hbuf[(48 + i) * 128 + tid] = pack2(silu_f(a[2 * i]), silu_f(a[2 * i + 1]));
        }
    }
#pragma unroll
    for (int w = 0; w < 48; w++) hbuf[w * 128 + tid] = rb[w];

    // stage 2+3: latents = (h1 @ w2)*cut -> latfT; ewv = latents @ wm0
    float ewv[48];
#pragma unroll
    for (int c = 0; c < 48; c++) ewv[c] = 0.0f;
#pragma unroll
    for (int jc = 0; jc < 4; jc++) {
        float a[32];
#pragma unroll
        for (int j = 0; j < 32; j++) a[j] = 0.0f;
        for (int kp = 0; kp < 64; kp++) {
            float v0, v1; unpack2(hbuf[kp * 128 + tid], v0, v1);
            const float* r0 = w2 + (2 * kp) * 128 + jc * 32;
            const float* r1 = r0 + 128;
#pragma unroll
            for (int j = 0; j < 32; j++) a[j] = fmaf(v1, r1[j], fmaf(v0, r0[j], a[j]));
        }
#pragma unroll
        for (int i = 0; i < 16; i++) {
            const float l0 = a[2 * i] * cutv;
            const float l1 = a[2 * i + 1] * cutv;
            latfT[(jc * 16 + i) * EE + e] = pack2(l0, l1);
            const float* m0 = wm0 + (jc * 32 + 2 * i) * 48;
            const float* m1 = m0 + 48;
#pragma unroll
            for (int c = 0; c < 48; c++) ewv[c] = fmaf(l1, m1[c], fmaf(l0, m0[c], ewv[c]));
        }
    }

    // w_init -> winiT packed: word i*4+uh = (wini[i][2uh], wini[i][2uh+1])
#pragma unroll
    for (int i = 0; i < 3; i++)
#pragma unroll
        for (int uh = 0; uh < 4; uh++)
            winiT[(i * 4 + uh) * EE + e] =
                pack2(ewv[(2 * uh) * 3 + i], ewv[(2 * uh + 1) * 3 + i]);

    float eav[9];
#pragma unroll
    for (int d = 0; d < 9; d++) {
        eav[d] = ea[e * 9 + d];
        eaT[d * EE + e] = f2b(eav[d]);
    }
#pragma unroll
    for (int u = 0; u < 8; u++) {
        float* dst = env0 + (ctr * 8 + u) * 9;
        const float a0 = ewv[24 + u * 3 + 0];
        const float a1 = ewv[24 + u * 3 + 1];
        const float a2 = ewv[24 + u * 3 + 2];
        atomicAdd(dst + 0, a0 * eav[0]);
        atomicAdd(dst + 1, a1 * eav[1]);
        atomicAdd(dst + 2, a1 * eav[2]);
        atomicAdd(dst + 3, a1 * eav[3]);
        atomicAdd(dst + 4, a2 * eav[4]);
        atomicAdd(dst + 5, a2 * eav[5]);
        atomicAdd(dst + 6, a2 * eav[6]);
        atomicAdd(dst + 7, a2 * eav[7]);
        atomicAdd(dst + 8, a2 * eav[8]);
    }
}

// ---------------------------------------------------------------------------
// kEnv: env_c[n,u,d] = (1/(16*sqrt8)) * sum_v Wl[ir(d),u,v]*env[n,v,d], in place
// ---------------------------------------------------------------------------
__global__ void kEnv(const float* __restrict__ wl, float* __restrict__ env)
{
    const int t = blockIdx.x * 256 + threadIdx.x;
    if (t >= NNODES * 9) return;
    const int n = t / 9;
    const int d = t - n * 9;
    const int ir = (d == 0) ? 0 : ((d < 4) ? 1 : 2);
    float v[8];
#pragma unroll
    for (int q = 0; q < 8; q++) v[q] = env[(n * 8 + q) * 9 + d];
    float o[8];
#pragma unroll
    for (int u = 0; u < 8; u++) {
        float s = 0.0f;
#pragma unroll
        for (int q = 0; q < 8; q++) s = fmaf(wl[ir * 64 + u * 8 + q], v[q], s);
        o[u] = s * INV_AVGN_SQM;
    }
#pragma unroll
    for (int u = 0; u < 8; u++) env[(n * 8 + u) * 9 + d] = o[u];
}

// ---------------------------------------------------------------------------
// kC1: layer-0 interact + invariants (u-pair loop, packed I/O)
// ---------------------------------------------------------------------------
__global__ __launch_bounds__(256, 1) void kC1(
    const unsigned* __restrict__ winiT, const bf16* __restrict__ eaT,
    const float* __restrict__ envc, const int* __restrict__ eidx,
    unsigned* __restrict__ newfT, unsigned* __restrict__ latfT)
{
    const int e = blockIdx.x * 256 + threadIdx.x;
    const int ctr = eidx[e];
    float eav[9];
#pragma unroll
    for (int d = 0; d < 9; d++) eav[d] = b2f(eaT[d * EE + e]);
    const float* ec = envc + ctr * 72;
#pragma unroll
    for (int uh = 0; uh < 4; uh++) {
        const int u0 = 2 * uh;
        float wi0[3], wi1[3];
#pragma unroll
        for (int i = 0; i < 3; i++) unpack2(winiT[(i * 4 + uh) * EE + e], wi0[i], wi1[i]);
        float nf0[9], nf1[9];
        {
            const float ec00 = ec[u0 * 9 + 0];
            const float ec10 = ec[(u0 + 1) * 9 + 0];
            const float f00 = wi0[0] * eav[0];
            const float f10 = wi1[0] * eav[0];
#pragma unroll
            for (int d = 0; d < 9; d++) {
                const int irr = (d == 0) ? 0 : ((d < 4) ? 1 : 2);
                const float fa = wi0[irr] * eav[d];
                const float fb = wi1[irr] * eav[d];
                nf0[d] = fa * ec00 + ec[u0 * 9 + d] * f00;
                nf1[d] = fb * ec10 + ec[(u0 + 1) * 9 + d] * f10;
            }
        }
#pragma unroll
        for (int d = 0; d < 9; d++) newfT[(d * 4 + uh) * EE + e] = pack2(nf0[d], nf1[d]);
        const float s00 = nf0[0] * nf0[0] + 1e-8f;
        const float s01 = nf0[1]*nf0[1] + nf0[2]*nf0[2] + nf0[3]*nf0[3] + 1e-8f;
        const float s02 = nf0[4]*nf0[4] + nf0[5]*nf0[5] + nf0[6]*nf0[6] + nf0[7]*nf0[7] + nf0[8]*nf0[8] + 1e-8f;
        const float s10 = nf1[0] * nf1[0] + 1e-8f;
        const float s11 = nf1[1]*nf1[1] + nf1[2]*nf1[2] + nf1[3]*nf1[3] + 1e-8f;
        const float s12 = nf1[4]*nf1[4] + nf1[5]*nf1[5] + nf1[6]*nf1[6] + nf1[7]*nf1[7] + nf1[8]*nf1[8] + 1e-8f;
        latfT[(64 + 3 * uh + 0) * EE + e] = pack2(sqrtf(s00), sqrtf(s01));
        latfT[(64 + 3 * uh + 1) * EE + e] = pack2(sqrtf(s02), sqrtf(s10));
        latfT[(64 + 3 * uh + 2) * EE + e] = pack2(sqrtf(s11), sqrtf(s12));
    }
}

// ---------------------------------------------------------------------------
// kC2: layer-0 pe_linear pair. 4 edges/thread (stride EQ), y = ir*4 + u-pair.
// ---------------------------------------------------------------------------
__global__ __launch_bounds__(256, 1) void kC2(
    const unsigned* __restrict__ latfT, const unsigned* __restrict__ winiT,
    const bf16* __restrict__ eaT, const unsigned* __restrict__ newfT,
    const float* __restrict__ l2fo, const float* __restrict__ l2fn,
    unsigned* __restrict__ feat1T)
{
    const int e0 = blockIdx.x * 256 + threadIdx.x;
    if (e0 >= EQ) return;
    const int ir = blockIdx.y >> 2;
    const int uh = blockIdx.y & 3;
    const int d0 = (ir == 0) ? 0 : ((ir == 1) ? 1 : 4);
    const int nd = (ir == 0) ? 1 : ((ir == 1) ? 3 : 5);
    float accO[4][16], accN[4][16];
#pragma unroll
    for (int m = 0; m < 4; m++)
#pragma unroll
        for (int q = 0; q < 16; q++) { accO[m][q] = 0.0f; accN[m][q] = 0.0f; }
    for (int w = 0; w < 76; w++) {
        float lf0[4], lf1[4];
#pragma unroll
        for (int m = 0; m < 4; m++) unpack2(latfT[w * EE + e0 + EQ * m], lf0[m], lf1[m]);
        const float* wo0 = l2fo + (2 * w) * 192 + ir * 64 + uh * 16;
        const float* wo1 = wo0 + 192;
        const float* wn0 = l2fn + (2 * w) * 192 + ir * 64 + uh * 16;
        const float* wn1 = wn0 + 192;
#pragma unroll
        for (int q = 0; q < 16; q++) {
            const float a0 = wo0[q], a1 = wo1[q];
            const float b0 = wn0[q], b1 = wn1[q];
#pragma unroll
            for (int m = 0; m < 4; m++) {
                accO[m][q] = fmaf(lf1[m], a1, fmaf(lf0[m], a0, accO[m][q]));
                accN[m][q] = fmaf(lf1[m], b1, fmaf(lf0[m], b0, accN[m][q]));
            }
        }
    }
#pragma unroll
    for (int m = 0; m < 4; m++) {
        const int e = e0 + EQ * m;
        float wv[8];
#pragma unroll
        for (int q = 0; q < 4; q++) unpack2(winiT[(ir * 4 + q) * EE + e], wv[2 * q], wv[2 * q + 1]);
        for (int dd = 0; dd < nd; dd++) {
            const int d = d0 + dd;
            const float ead = b2f(eaT[d * EE + e]);
            float nfv[8];
#pragma unroll
            for (int q = 0; q < 4; q++) unpack2(newfT[(d * 4 + q) * EE + e], nfv[2 * q], nfv[2 * q + 1]);
            float s0 = 0.0f, s1 = 0.0f;
#pragma unroll
            for (int v = 0; v < 8; v++) {
                const float fe = wv[v] * ead;
                s0 += accO[m][v] * fe + accN[m][v] * nfv[v];
                s1 += accO[m][8 + v] * fe + accN[m][8 + v] * nfv[v];
            }
            feat1T[(d * 4 + uh) * EE + e] = pack2(s0 * HALF_INV_SQM, s1 * HALF_INV_SQM);
        }
    }
}

// ---------------------------------------------------------------------------
// kC3: latent resnet + env-MLP1 + env1 scatter. Deferred in-place lat writes.
// ---------------------------------------------------------------------------
__global__ __launch_bounds__(256, 1) void kC3(
    unsigned* __restrict__ latfT, const float* __restrict__ latw,
    const float* __restrict__ wm1, const bf16* __restrict__ eaT,
    const float* __restrict__ cutb, const int* __restrict__ eidx,
    float* __restrict__ env1)
{
    const int e = blockIdx.x * 256 + threadIdx.x;
    const float cutv = cutb[e];
    float wc[24];
#pragma unroll
    for (int c = 0; c < 24; c++) wc[c] = 0.0f;
    unsigned rbuf[48];
#pragma unroll
    for (int jc = 0; jc < 4; jc++) {
        float a[32];
#pragma unroll
        for (int j = 0; j < 32; j++) a[j] = 0.0f;
        for (int w = 0; w < 76; w++) {
            float v0, v1; unpack2(latfT[w * EE + e], v0, v1);
            const float* r0 = latw + (2 * w) * 128 + jc * 32;
            const float* r1 = r0 + 128;
#pragma unroll
            for (int j = 0; j < 32; j++) a[j] = fmaf(v1, r1[j], fmaf(v0, r0[j], a[j]));
        }
#pragma unroll
        for (int i = 0; i < 16; i++) {
            float o0, o1; unpack2(latfT[(jc * 16 + i) * EE + e], o0, o1);
            const float l0 = 0.5f * o0 + 0.5f * silu_f(a[2 * i]) * cutv;
            const float l1 = 0.5f * o1 + 0.5f * silu_f(a[2 * i + 1]) * cutv;
            const float* m0 = wm1 + (jc * 32 + 2 * i) * 24;
            const float* m1 = m0 + 24;
#pragma unroll
            for (int c = 0; c < 24; c++) wc[c] = fmaf(l1, m1[c], fmaf(l0, m0[c], wc[c]));
            if (jc < 3) rbuf[jc * 16 + i] = pack2(l0, l1);
            else        latfT[(48 + i) * EE + e] = pack2(l0, l1);
        }
    }
#pragma unroll
    for (int w = 0; w < 48; w++) latfT[w * EE + e] = rbuf[w];

    const int ctr = eidx[e];
    float eav[9];
#pragma unroll
    for (int d = 0; d < 9; d++) eav[d] = b2f(eaT[d * EE + e]);
#pragma unroll
    for (int u = 0; u < 8; u++) {
        float* dst = env1 + (ctr * 8 + u) * 9;
        const float a0 = wc[u * 3 + 0];
        const float a1 = wc[u * 3 + 1];
        const float a2 = wc[u * 3 + 2];
        atomicAdd(dst + 0, a0 * eav[0]);
        atomicAdd(dst + 1, a1 * eav[1]);
        atomicAdd(dst + 2, a1 * eav[2]);
        atomicAdd(dst + 3, a1 * eav[3]);
        atomicAdd(dst + 4, a2 * eav[4]);
        atomicAdd(dst + 5, a2 * eav[5]);
        atomicAdd(dst + 6, a2 * eav[6]);
        atomicAdd(dst + 7, a2 * eav[7]);
        atomicAdd(dst + 8, a2 * eav[8]);
    }
}

// ---------------------------------------------------------------------------
// kE1: layer-1 interact + invariants
// ---------------------------------------------------------------------------
__global__ __launch_bounds__(256, 1) void kE1(
    const unsigned* __restrict__ feat1T, const float* __restrict__ envc,
    const int* __restrict__ eidx, unsigned* __restrict__ newfT,
    unsigned* __restrict__ latfT)
{
    const int e = blockIdx.x * 256 + threadIdx.x;
    const int ctr = eidx[e];
    const float* ec = envc + ctr * 72;
#pragma unroll
    for (int uh = 0; uh < 4; uh++) {
        const int u0 = 2 * uh;
        float f0[9], f1[9];
#pragma unroll
        for (int d = 0; d < 9; d++) unpack2(feat1T[(d * 4 + uh) * EE + e], f0[d], f1[d]);
        const float ec00 = ec[u0 * 9 + 0];
        const float ec10 = ec[(u0 + 1) * 9 + 0];
        float nf0[9], nf1[9];
#pragma unroll
        for (int d = 0; d < 9; d++) {
            nf0[d] = f0[d] * ec00 + ec[u0 * 9 + d] * f0[0];
            nf1[d] = f1[d] * ec10 + ec[(u0 + 1) * 9 + d] * f1[0];
        }
#pragma unroll
        for (int d = 0; d < 9; d++) newfT[(d * 4 + uh) * EE + e] = pack2(nf0[d], nf1[d]);
        const float s00 = nf0[0] * nf0[0] + 1e-8f;
        const float s01 = nf0[1]*nf0[1] + nf0[2]*nf0[2] + nf0[3]*nf0[3] + 1e-8f;
        const float s02 = nf0[4]*nf0[4] + nf0[5]*nf0[5] + nf0[6]*nf0[6] + nf0[7]*nf0[7] + nf0[8]*nf0[8] + 1e-8f;
        const float s10 = nf1[0] * nf1[0] + 1e-8f;
        const float s11 = nf1[1]*nf1[1] + nf1[2]*nf1[2] + nf1[3]*nf1[3] + 1e-8f;
        const float s12 = nf1[4]*nf1[4] + nf1[5]*nf1[5] + nf1[6]*nf1[6] + nf1[7]*nf1[7] + nf1[8]*nf1[8] + 1e-8f;
        latfT[(64 + 3 * uh + 0) * EE + e] = pack2(sqrtf(s00), sqrtf(s01));
        latfT[(64 + 3 * uh + 1) * EE + e] = pack2(sqrtf(s02), sqrtf(s10));
        latfT[(64 + 3 * uh + 2) * EE + e] = pack2(sqrtf(s11), sqrtf(s12));
    }
}

// ---------------------------------------------------------------------------
// kE2: final irrep-1 pe_linear + final_w dot. 4 edges/thread, y = u-pair,
// partial sums combined via f32 atomicAdd into zeroed d_out.
// ---------------------------------------------------------------------------
__global__ __launch_bounds__(256, 1) void kE2(
    const unsigned* __restrict__ latfT, const unsigned* __restrict__ feat1T,
    const unsigned* __restrict__ newfT,
    const float* __restrict__ l2fo, const float* __restrict__ l2fn,
    const float* __restrict__ finw, float* __restrict__ outp)
{
    const int e0 = blockIdx.x * 256 + threadIdx.x;
    if (e0 >= EQ) return;
    const int uh = blockIdx.y;
    float accO[4][16], accN[4][16], wf[4][2];
#pragma unroll
    for (int m = 0; m < 4; m++) {
#pragma unroll
        for (int q = 0; q < 16; q++) { accO[m][q] = 0.0f; accN[m][q] = 0.0f; }
        wf[m][0] = 0.0f; wf[m][1] = 0.0f;
    }
    for (int w = 0; w < 76; w++) {
        float lf0[4], lf1[4];
#pragma unroll
        for (int m = 0; m < 4; m++) unpack2(latfT[w * EE + e0 + EQ * m], lf0[m], lf1[m]);
        const float* wo0 = l2fo + (2 * w) * 192 + 64 + uh * 16;
        const float* wo1 = wo0 + 192;
        const float* wn0 = l2fn + (2 * w) * 192 + 64 + uh * 16;
        const float* wn1 = wn0 + 192;
#pragma unroll
        for (int q = 0; q < 16; q++) {
            const float a0 = wo0[q], a1 = wo1[q];
            const float b0 = wn0[q], b1 = wn1[q];
#pragma unroll
            for (int m = 0; m < 4; m++) {
                accO[m][q] = fmaf(lf1[m], a1, fmaf(lf0[m], a0, accO[m][q]));
                accN[m][q] = fmaf(lf1[m], b1, fmaf(lf0[m], b0, accN[m][q]));
            }
        }
        const float fa0 = finw[(2 * w) * 8 + 2 * uh];
        const float fa1 = finw[(2 * w) * 8 + 2 * uh + 1];
        const float fb0 = finw[(2 * w + 1) * 8 + 2 * uh];
        const float fb1 = finw[(2 * w + 1) * 8 + 2 * uh + 1];
#pragma unroll
        for (int m = 0; m < 4; m++) {
            wf[m][0] = fmaf(lf1[m], fb0, fmaf(lf0[m], fa0, wf[m][0]));
            wf[m][1] = fmaf(lf1[m], fb1, fmaf(lf0[m], fa1, wf[m][1]));
        }
    }
#pragma unroll
    for (int m = 0; m < 4; m++) {
        const int e = e0 + EQ * m;
#pragma unroll
        for (int dd = 0; dd < 3; dd++) {
            const int d = 1 + dd;
            float f1v[8], nfv[8];
#pragma unroll
            for (int q = 0; q < 4; q++) {
                unpack2(feat1T[(d * 4 + q) * EE + e], f1v[2 * q], f1v[2 * q + 1]);
                unpack2(newfT[(d * 4 + q) * EE + e], nfv[2 * q], nfv[2 * q + 1]);
            }
            float s0 = 0.0f, s1 = 0.0f;
#pragma unroll
            for (int v = 0; v < 8; v++) {
                s0 += accO[m][v] * f1v[v] + accN[m][v] * nfv[v];
                s1 += accO[m][8 + v] * f1v[v] + accN[m][8 + v] * nfv[v];
            }
            const float od = (wf[m][0] * s0 + wf[m][1] * s1) * (HALF_INV_SQM * INV_SQM);
            atomicAdd(&outp[e * 3 + dd], od);
        }
    }
}

// ---------------------------------------------------------------------------
extern "C" void kernel_launch(void* const* d_in, const int* in_sizes, int n_in,
                              void* d_out, int out_size, void* d_ws, size_t ws_size,
                              hipStream_t stream)
{
    const float* ea   = (const float*)d_in[0];
    const float* eemb = (const float*)d_in[1];
    const float* nat  = (const float*)d_in[2];
    const float* elen = (const float*)d_in[3];
    const float* w0   = (const float*)d_in[4];
    const float* w1   = (const float*)d_in[5];
    const float* w2   = (const float*)d_in[6];
    const float* wm0  = (const float*)d_in[7];
    const float* wm1  = (const float*)d_in[8];
    const float* envl = (const float*)d_in[9];
    const float* latw = (const float*)d_in[10];
    const float* l2fn = (const float*)d_in[11];
    const float* l2fo = (const float*)d_in[12];
    const float* finw = (const float*)d_in[13];
    const int*   eidx = (const int*)d_in[14];

    char* ws = (char*)d_ws;
    unsigned* latfT  = (unsigned*)(ws + 0);           // [76 words][E]
    unsigned* newfT  = (unsigned*)(ws + 48640000);    // [36][E]
    unsigned* feat1T = (unsigned*)(ws + 71680000);    // [36][E]
    unsigned* winiT  = (unsigned*)(ws + 94720000);    // [12][E]
    bf16*     eaT    = (bf16*)(ws + 102400000);       // [9][E]
    float*    cutb   = (float*)(ws + 105280000);      // [E]
    float*    env0   = (float*)(ws + 105920000);      // [N*8*9]
    float*    env1   = (float*)(ws + 108800000);      // [N*8*9]

    hipMemsetAsync(env0, 0, 2u * 720000u * 4u, stream);
    hipMemsetAsync(d_out, 0, (size_t)EE * 3u * 4u, stream);

    kA<<<1250, 128, 0, stream>>>(ea, eemb, nat, elen, w0, w1, w2, wm0, eidx,
                                 latfT, winiT, eaT, cutb, env0);
    kEnv<<<352, 256, 0, stream>>>(envl + 0, env0);
    kC1<<<625, 256, 0, stream>>>(winiT, eaT, env0, eidx, newfT, latfT);
    kC2<<<dim3(157, 12), 256, 0, stream>>>(latfT, winiT, eaT, newfT,
                                           l2fo + 0, l2fn + 0, feat1T);
    kC3<<<625, 256, 0, stream>>>(latfT, latw, wm1, eaT, cutb, eidx, env1);
    kEnv<<<352, 256, 0, stream>>>(envl + 192, env1);
    kE1<<<625, 256, 0, stream>>>(feat1T, env1, eidx, newfT, latfT);
    kE2<<<dim3(157, 4), 256, 0, stream>>>(latfT, feat1T, newfT,
                                          l2fo + 29184, l2fn + 29184, finw,
                                          (float*)d_out);
}

// Round 3
// 1983.383 us; speedup vs baseline: 1.4867x; 1.4867x over previous
//
#include <hip/hip_runtime.h>
#include <hip/hip_bf16.h>

#define EE 160000
#define NNODES 10000

using bf16 = __hip_bfloat16;

__device__ __forceinline__ float silu_f(float x) { return x / (1.0f + __expf(-x)); }
__device__ __forceinline__ float b2f(bf16 v) { return __bfloat162float(v); }
__device__ __forceinline__ bf16 f2b(float v) { return __float2bfloat16(v); }

__device__ __forceinline__ unsigned bfbits(float v) {
    union { float f; unsigned u; } a; a.f = v;
    return (a.u + 0x7fffu + ((a.u >> 16) & 1u)) >> 16;
}
__device__ __forceinline__ unsigned pack2(float a, float b) {
    return bfbits(a) | (bfbits(b) << 16);
}
__device__ __forceinline__ void unpack2(unsigned u, float& a, float& b) {
    union { unsigned x; float f; } lo, hi;
    lo.x = u << 16; hi.x = u & 0xffff0000u;
    a = lo.f; b = hi.f;
}

// 1/(16*sqrt(8)), 0.5/sqrt(8), 1/sqrt(8)
#define INV_AVGN_SQM 0.02209708691207961f
#define HALF_INV_SQM 0.17677669529663687f
#define INV_SQM      0.35355339059327373f

// ---------------------------------------------------------------------------
// CSR build: count -> scan -> fill
// ---------------------------------------------------------------------------
__global__ void kCnt(const int* __restrict__ eidx, int* __restrict__ deg)
{
    const int e = blockIdx.x * 256 + threadIdx.x;
    atomicAdd(&deg[eidx[e]], 1);
}

__global__ void kScan(const int* __restrict__ deg, int* __restrict__ off)
{
    __shared__ int part[256];
    const int t = threadIdx.x;
    int loc[40];
    int s = 0;
#pragma unroll
    for (int i = 0; i < 40; i++) {
        const int idx = t * 40 + i;
        const int v = (idx < NNODES) ? deg[idx] : 0;
        loc[i] = s;
        s += v;
    }
    part[t] = s;
    __syncthreads();
    for (int d = 1; d < 256; d <<= 1) {
        const int v = (t >= d) ? part[t - d] : 0;
        __syncthreads();
        part[t] += v;
        __syncthreads();
    }
    const int base = (t == 0) ? 0 : part[t - 1];
#pragma unroll
    for (int i = 0; i < 40; i++) {
        const int idx = t * 40 + i;
        if (idx < NNODES) off[idx] = base + loc[i];
    }
    if (t == 255) off[NNODES] = part[255];
}

__global__ void kFill(const int* __restrict__ eidx, int* __restrict__ cur,
                      const int* __restrict__ off, int* __restrict__ elist)
{
    const int e = blockIdx.x * 256 + threadIdx.x;
    const int c = eidx[e];
    const int pos = atomicAdd(&cur[c], 1);
    elist[off[c] + pos] = e;
}

// ---------------------------------------------------------------------------
// kEnvG: gather env + fused env-linear. One thread per (node, d).
// env_c[n,u,d] = (1/(16*sqrt8)) * sum_v Wl[ir,u,v] * sum_{e in n} wcur[e,v,ir]*ea[e,d]
// ---------------------------------------------------------------------------
__global__ void kEnvG(const float* __restrict__ wcur, const float* __restrict__ ea,
                      const int* __restrict__ off, const int* __restrict__ elist,
                      const float* __restrict__ wl, float* __restrict__ envc)
{
    const int t = blockIdx.x * 256 + threadIdx.x;
    if (t >= NNODES * 9) return;
    const int n = t / 9;
    const int d = t - n * 9;
    const int irr = (d == 0) ? 0 : ((d < 4) ? 1 : 2);
    float v[8];
#pragma unroll
    for (int q = 0; q < 8; q++) v[q] = 0.0f;
    const int b = off[n], en = off[n + 1];
    for (int j = b; j < en; j++) {
        const int e = elist[j];
        const float ad = ea[e * 9 + d];
        const float* wr = wcur + e * 24 + irr;
#pragma unroll
        for (int q = 0; q < 8; q++) v[q] = fmaf(wr[q * 3], ad, v[q]);
    }
#pragma unroll
    for (int u = 0; u < 8; u++) {
        float s = 0.0f;
#pragma unroll
        for (int q = 0; q < 8; q++) s = fmaf(wl[irr * 64 + u * 8 + q], v[q], s);
        envc[n * 72 + u * 9 + d] = s * INV_AVGN_SQM;
    }
}

// ---------------------------------------------------------------------------
// kA: tb-MLP 16->128->128->128 + cutoff + env-MLP 128->48 (chunked, no spill)
// ---------------------------------------------------------------------------
__global__ __launch_bounds__(128, 1) void kA(
    const float* __restrict__ ea, const float* __restrict__ eemb,
    const float* __restrict__ nat, const float* __restrict__ elen,
    const float* __restrict__ w0, const float* __restrict__ w1,
    const float* __restrict__ w2, const float* __restrict__ wm0,
    const int* __restrict__ eidx,
    unsigned* __restrict__ latfT, unsigned* __restrict__ winiT,
    bf16* __restrict__ eaT, float* __restrict__ cutb,
    float* __restrict__ wcur0)
{
    __shared__ unsigned hbuf[64 * 128];
    const int tid = threadIdx.x;
    const int e = blockIdx.x * 128 + tid;
    const int ctr = eidx[e];
    const int ngb = eidx[EE + e];

    float tin[16];
#pragma unroll
    for (int k = 0; k < 4; k++) tin[k] = nat[ctr * 4 + k];
#pragma unroll
    for (int k = 0; k < 4; k++) tin[4 + k] = nat[ngb * 4 + k];
#pragma unroll
    for (int k = 0; k < 8; k++) tin[8 + k] = eemb[e * 8 + k];

    const float x = elen[e];
    const float x2 = x * x, x4 = x2 * x2, x6 = x4 * x2, x7 = x6 * x, x8 = x7 * x;
    float cutv = 1.0f - 28.0f * x6 + 48.0f * x7 - 21.0f * x8;
    cutv = (x < 1.0f) ? cutv : 0.0f;
    cutb[e] = cutv;

    // stage 0
#pragma unroll
    for (int jc = 0; jc < 4; jc++) {
        float a[32];
#pragma unroll
        for (int j = 0; j < 32; j++) a[j] = 0.0f;
#pragma unroll
        for (int k = 0; k < 16; k++) {
            const float v = tin[k];
            const float* r = w0 + k * 128 + jc * 32;
#pragma unroll
            for (int j = 0; j < 32; j++) a[j] = fmaf(v, r[j], a[j]);
        }
#pragma unroll
        for (int i = 0; i < 16; i++)
            hbuf[(jc * 16 + i) * 128 + tid] = pack2(silu_f(a[2 * i]), silu_f(a[2 * i + 1]));
    }

    // stage 1 (deferred writes avoid in-place hazard)
    unsigned rb[48];
#pragma unroll
    for (int jc = 0; jc < 4; jc++) {
        float a[32];
#pragma unroll
        for (int j = 0; j < 32; j++) a[j] = 0.0f;
        for (int kp = 0; kp < 64; kp++) {
            float v0, v1; unpack2(hbuf[kp * 128 + tid], v0, v1);
            const float* r0 = w1 + (2 * kp) * 128 + jc * 32;
            const float* r1 = r0 + 128;
#pragma unroll
            for (int j = 0; j < 32; j++) a[j] = fmaf(v1, r1[j], fmaf(v0, r0[j], a[j]));
        }
        if (jc < 3) {
#pragma unroll
            for (int i = 0; i < 16; i++)
                rb[jc * 16 + i] = pack2(silu_f(a[2 * i]), silu_f(a[2 * i + 1]));
        } else {
#pragma unroll
            for (int i = 0; i < 16; i++)
                hbuf[(48 + i) * 128 + tid] = pack2(silu_f(a[2 * i]), silu_f(a[2 * i + 1]));
        }
    }
#pragma unroll
    for (int w = 0; w < 48; w++) hbuf[w * 128 + tid] = rb[w];

    // stage 2+3
    float ewv[48];
#pragma unroll
    for (int c = 0; c < 48; c++) ewv[c] = 0.0f;
#pragma unroll
    for (int jc = 0; jc < 4; jc++) {
        float a[32];
#pragma unroll
        for (int j = 0; j < 32; j++) a[j] = 0.0f;
        for (int kp = 0; kp < 64; kp++) {
            float v0, v1; unpack2(hbuf[kp * 128 + tid], v0, v1);
            const float* r0 = w2 + (2 * kp) * 128 + jc * 32;
            const float* r1 = r0 + 128;
#pragma unroll
            for (int j = 0; j < 32; j++) a[j] = fmaf(v1, r1[j], fmaf(v0, r0[j], a[j]));
        }
#pragma unroll
        for (int i = 0; i < 16; i++) {
            const float l0 = a[2 * i] * cutv;
            const float l1 = a[2 * i + 1] * cutv;
            latfT[(jc * 16 + i) * EE + e] = pack2(l0, l1);
            const float* m0 = wm0 + (jc * 32 + 2 * i) * 48;
            const float* m1 = m0 + 48;
#pragma unroll
            for (int c = 0; c < 48; c++) ewv[c] = fmaf(l1, m1[c], fmaf(l0, m0[c], ewv[c]));
        }
    }

#pragma unroll
    for (int i = 0; i < 3; i++)
#pragma unroll
        for (int uh = 0; uh < 4; uh++)
            winiT[(i * 4 + uh) * EE + e] =
                pack2(ewv[(2 * uh) * 3 + i], ewv[(2 * uh + 1) * 3 + i]);

#pragma unroll
    for (int d = 0; d < 9; d++) eaT[d * EE + e] = f2b(ea[e * 9 + d]);

    // w_cur layer-0 -> [E][24] f32 (contiguous per edge)
#pragma unroll
    for (int c = 0; c < 24; c++) wcur0[e * 24 + c] = ewv[24 + c];
}

// ---------------------------------------------------------------------------
// kC1: layer-0 interact + invariants
// ---------------------------------------------------------------------------
__global__ __launch_bounds__(256, 1) void kC1(
    const unsigned* __restrict__ winiT, const bf16* __restrict__ eaT,
    const float* __restrict__ envc, const int* __restrict__ eidx,
    unsigned* __restrict__ newfT, unsigned* __restrict__ latfT)
{
    const int e = blockIdx.x * 256 + threadIdx.x;
    const int ctr = eidx[e];
    float eav[9];
#pragma unroll
    for (int d = 0; d < 9; d++) eav[d] = b2f(eaT[d * EE + e]);
    const float* ec = envc + ctr * 72;
#pragma unroll
    for (int uh = 0; uh < 4; uh++) {
        const int u0 = 2 * uh;
        float wi0[3], wi1[3];
#pragma unroll
        for (int i = 0; i < 3; i++) unpack2(winiT[(i * 4 + uh) * EE + e], wi0[i], wi1[i]);
        float nf0[9], nf1[9];
        const float ec00 = ec[u0 * 9 + 0];
        const float ec10 = ec[(u0 + 1) * 9 + 0];
        const float f00 = wi0[0] * eav[0];
        const float f10 = wi1[0] * eav[0];
#pragma unroll
        for (int d = 0; d < 9; d++) {
            const int irr = (d == 0) ? 0 : ((d < 4) ? 1 : 2);
            const float fa = wi0[irr] * eav[d];
            const float fb = wi1[irr] * eav[d];
            nf0[d] = fa * ec00 + ec[u0 * 9 + d] * f00;
            nf1[d] = fb * ec10 + ec[(u0 + 1) * 9 + d] * f10;
        }
#pragma unroll
        for (int d = 0; d < 9; d++) newfT[(d * 4 + uh) * EE + e] = pack2(nf0[d], nf1[d]);
        const float s00 = nf0[0] * nf0[0] + 1e-8f;
        const float s01 = nf0[1]*nf0[1] + nf0[2]*nf0[2] + nf0[3]*nf0[3] + 1e-8f;
        const float s02 = nf0[4]*nf0[4] + nf0[5]*nf0[5] + nf0[6]*nf0[6] + nf0[7]*nf0[7] + nf0[8]*nf0[8] + 1e-8f;
        const float s10 = nf1[0] * nf1[0] + 1e-8f;
        const float s11 = nf1[1]*nf1[1] + nf1[2]*nf1[2] + nf1[3]*nf1[3] + 1e-8f;
        const float s12 = nf1[4]*nf1[4] + nf1[5]*nf1[5] + nf1[6]*nf1[6] + nf1[7]*nf1[7] + nf1[8]*nf1[8] + 1e-8f;
        latfT[(64 + 3 * uh + 0) * EE + e] = pack2(sqrtf(s00), sqrtf(s01));
        latfT[(64 + 3 * uh + 1) * EE + e] = pack2(sqrtf(s02), sqrtf(s10));
        latfT[(64 + 3 * uh + 2) * EE + e] = pack2(sqrtf(s11), sqrtf(s12));
    }
}

// ---------------------------------------------------------------------------
// kC2: layer-0 pe_linear pair. 1 edge/thread; y = ir*2 + u-half (6 y-blocks).
// acc 32+32 regs -> no spill.
// ---------------------------------------------------------------------------
__global__ __launch_bounds__(256, 1) void kC2(
    const unsigned* __restrict__ latfT, const unsigned* __restrict__ winiT,
    const bf16* __restrict__ eaT, const unsigned* __restrict__ newfT,
    const float* __restrict__ l2fo, const float* __restrict__ l2fn,
    unsigned* __restrict__ feat1T)
{
    const int e = blockIdx.x * 256 + threadIdx.x;
    const int ir = blockIdx.y >> 1;
    const int uh2 = blockIdx.y & 1;           // u in [uh2*4, uh2*4+4)
    const int d0 = (ir == 0) ? 0 : ((ir == 1) ? 1 : 4);
    const int nd = (ir == 0) ? 1 : ((ir == 1) ? 3 : 5);
    float accO[32], accN[32];
#pragma unroll
    for (int q = 0; q < 32; q++) { accO[q] = 0.0f; accN[q] = 0.0f; }
    for (int w = 0; w < 76; w++) {
        float lf0, lf1; unpack2(latfT[w * EE + e], lf0, lf1);
        const float* wo0 = l2fo + (2 * w) * 192 + ir * 64 + uh2 * 32;
        const float* wo1 = wo0 + 192;
        const float* wn0 = l2fn + (2 * w) * 192 + ir * 64 + uh2 * 32;
        const float* wn1 = wn0 + 192;
#pragma unroll
        for (int q = 0; q < 32; q++) {
            accO[q] = fmaf(lf1, wo1[q], fmaf(lf0, wo0[q], accO[q]));
            accN[q] = fmaf(lf1, wn1[q], fmaf(lf0, wn0[q], accN[q]));
        }
    }
    float wv[8];
#pragma unroll
    for (int q = 0; q < 4; q++) unpack2(winiT[(ir * 4 + q) * EE + e], wv[2 * q], wv[2 * q + 1]);
    for (int dd = 0; dd < nd; dd++) {
        const int d = d0 + dd;
        const float ead = b2f(eaT[d * EE + e]);
        float nfv[8];
#pragma unroll
        for (int q = 0; q < 4; q++) unpack2(newfT[(d * 4 + q) * EE + e], nfv[2 * q], nfv[2 * q + 1]);
        float s[4];
#pragma unroll
        for (int up = 0; up < 4; up++) {
            float t = 0.0f;
#pragma unroll
            for (int v = 0; v < 8; v++)
                t += accO[up * 8 + v] * (wv[v] * ead) + accN[up * 8 + v] * nfv[v];
            s[up] = t * HALF_INV_SQM;
        }
        feat1T[(d * 4 + uh2 * 2 + 0) * EE + e] = pack2(s[0], s[1]);
        feat1T[(d * 4 + uh2 * 2 + 1) * EE + e] = pack2(s[2], s[3]);
    }
}

// ---------------------------------------------------------------------------
// kC3: latent resnet + env-MLP1 -> wcur1 [E][24] f32. No atomics.
// ---------------------------------------------------------------------------
__global__ __launch_bounds__(256, 1) void kC3(
    unsigned* __restrict__ latfT, const float* __restrict__ latw,
    const float* __restrict__ wm1, const float* __restrict__ cutb,
    float* __restrict__ wcur1)
{
    const int e = blockIdx.x * 256 + threadIdx.x;
    const float cutv = cutb[e];
    float wc[24];
#pragma unroll
    for (int c = 0; c < 24; c++) wc[c] = 0.0f;
    unsigned rbuf[48];
#pragma unroll
    for (int jc = 0; jc < 4; jc++) {
        float a[32];
#pragma unroll
        for (int j = 0; j < 32; j++) a[j] = 0.0f;
        for (int w = 0; w < 76; w++) {
            float v0, v1; unpack2(latfT[w * EE + e], v0, v1);
            const float* r0 = latw + (2 * w) * 128 + jc * 32;
            const float* r1 = r0 + 128;
#pragma unroll
            for (int j = 0; j < 32; j++) a[j] = fmaf(v1, r1[j], fmaf(v0, r0[j], a[j]));
        }
#pragma unroll
        for (int i = 0; i < 16; i++) {
            float o0, o1; unpack2(latfT[(jc * 16 + i) * EE + e], o0, o1);
            const float l0 = 0.5f * o0 + 0.5f * silu_f(a[2 * i]) * cutv;
            const float l1 = 0.5f * o1 + 0.5f * silu_f(a[2 * i + 1]) * cutv;
            const float* m0 = wm1 + (jc * 32 + 2 * i) * 24;
            const float* m1 = m0 + 24;
#pragma unroll
            for (int c = 0; c < 24; c++) wc[c] = fmaf(l1, m1[c], fmaf(l0, m0[c], wc[c]));
            if (jc < 3) rbuf[jc * 16 + i] = pack2(l0, l1);
            else        latfT[(48 + i) * EE + e] = pack2(l0, l1);
        }
    }
#pragma unroll
    for (int w = 0; w < 48; w++) latfT[w * EE + e] = rbuf[w];
#pragma unroll
    for (int c = 0; c < 24; c++) wcur1[e * 24 + c] = wc[c];
}

// ---------------------------------------------------------------------------
// kE1: layer-1 interact + invariants
// ---------------------------------------------------------------------------
__global__ __launch_bounds__(256, 1) void kE1(
    const unsigned* __restrict__ feat1T, const float* __restrict__ envc,
    const int* __restrict__ eidx, unsigned* __restrict__ newfT,
    unsigned* __restrict__ latfT)
{
    const int e = blockIdx.x * 256 + threadIdx.x;
    const int ctr = eidx[e];
    const float* ec = envc + ctr * 72;
#pragma unroll
    for (int uh = 0; uh < 4; uh++) {
        const int u0 = 2 * uh;
        float f0[9], f1[9];
#pragma unroll
        for (int d = 0; d < 9; d++) unpack2(feat1T[(d * 4 + uh) * EE + e], f0[d], f1[d]);
        const float ec00 = ec[u0 * 9 + 0];
        const float ec10 = ec[(u0 + 1) * 9 + 0];
        float nf0[9], nf1[9];
#pragma unroll
        for (int d = 0; d < 9; d++) {
            nf0[d] = f0[d] * ec00 + ec[u0 * 9 + d] * f0[0];
            nf1[d] = f1[d] * ec10 + ec[(u0 + 1) * 9 + d] * f1[0];
        }
#pragma unroll
        for (int d = 0; d < 9; d++) newfT[(d * 4 + uh) * EE + e] = pack2(nf0[d], nf1[d]);
        const float s00 = nf0[0] * nf0[0] + 1e-8f;
        const float s01 = nf0[1]*nf0[1] + nf0[2]*nf0[2] + nf0[3]*nf0[3] + 1e-8f;
        const float s02 = nf0[4]*nf0[4] + nf0[5]*nf0[5] + nf0[6]*nf0[6] + nf0[7]*nf0[7] + nf0[8]*nf0[8] + 1e-8f;
        const float s10 = nf1[0] * nf1[0] + 1e-8f;
        const float s11 = nf1[1]*nf1[1] + nf1[2]*nf1[2] + nf1[3]*nf1[3] + 1e-8f;
        const float s12 = nf1[4]*nf1[4] + nf1[5]*nf1[5] + nf1[6]*nf1[6] + nf1[7]*nf1[7] + nf1[8]*nf1[8] + 1e-8f;
        latfT[(64 + 3 * uh + 0) * EE + e] = pack2(sqrtf(s00), sqrtf(s01));
        latfT[(64 + 3 * uh + 1) * EE + e] = pack2(sqrtf(s02), sqrtf(s10));
        latfT[(64 + 3 * uh + 2) * EE + e] = pack2(sqrtf(s11), sqrtf(s12));
    }
}

// ---------------------------------------------------------------------------
// kE2: final irrep-1 pe_linear + final_w dot; y = u-half; partials to pout.
// ---------------------------------------------------------------------------
__global__ __launch_bounds__(256, 1) void kE2(
    const unsigned* __restrict__ latfT, const unsigned* __restrict__ feat1T,
    const unsigned* __restrict__ newfT,
    const float* __restrict__ l2fo, const float* __restrict__ l2fn,
    const float* __restrict__ finw, float* __restrict__ pout)
{
    const int e = blockIdx.x * 256 + threadIdx.x;
    const int uh2 = blockIdx.y;               // u in [uh2*4, uh2*4+4)
    float accO[32], accN[32], wf[4];
#pragma unroll
    for (int q = 0; q < 32; q++) { accO[q] = 0.0f; accN[q] = 0.0f; }
#pragma unroll
    for (int m = 0; m < 4; m++) wf[m] = 0.0f;
    for (int w = 0; w < 76; w++) {
        float lf0, lf1; unpack2(latfT[w * EE + e], lf0, lf1);
        const float* wo0 = l2fo + (2 * w) * 192 + 64 + uh2 * 32;
        const float* wo1 = wo0 + 192;
        const float* wn0 = l2fn + (2 * w) * 192 + 64 + uh2 * 32;
        const float* wn1 = wn0 + 192;
#pragma unroll
        for (int q = 0; q < 32; q++) {
            accO[q] = fmaf(lf1, wo1[q], fmaf(lf0, wo0[q], accO[q]));
            accN[q] = fmaf(lf1, wn1[q], fmaf(lf0, wn0[q], accN[q]));
        }
        const float* f0 = finw + (2 * w) * 8 + uh2 * 4;
        const float* f1 = f0 + 8;
#pragma unroll
        for (int m = 0; m < 4; m++) wf[m] = fmaf(lf1, f1[m], fmaf(lf0, f0[m], wf[m]));
    }
#pragma unroll
    for (int dd = 0; dd < 3; dd++) {
        const int d = 1 + dd;
        float f1v[8], nfv[8];
#pragma unroll
        for (int q = 0; q < 4; q++) {
            unpack2(feat1T[(d * 4 + q) * EE + e], f1v[2 * q], f1v[2 * q + 1]);
            unpack2(newfT[(d * 4 + q) * EE + e], nfv[2 * q], nfv[2 * q + 1]);
        }
        float od = 0.0f;
#pragma unroll
        for (int up = 0; up < 4; up++) {
            float s = 0.0f;
#pragma unroll
            for (int v = 0; v < 8; v++)
                s += accO[up * 8 + v] * f1v[v] + accN[up * 8 + v] * nfv[v];
            od = fmaf(wf[up], s, od);
        }
        pout[(uh2 * EE + e) * 3 + dd] = od * (HALF_INV_SQM * INV_SQM);
    }
}

__global__ void kOut(const float* __restrict__ pout, float* __restrict__ outp)
{
    const int t = blockIdx.x * 256 + threadIdx.x;
    if (t >= EE * 3) return;
    outp[t] = pout[t] + pout[EE * 3 + t];
}

// ---------------------------------------------------------------------------
extern "C" void kernel_launch(void* const* d_in, const int* in_sizes, int n_in,
                              void* d_out, int out_size, void* d_ws, size_t ws_size,
                              hipStream_t stream)
{
    const float* ea   = (const float*)d_in[0];
    const float* eemb = (const float*)d_in[1];
    const float* nat  = (const float*)d_in[2];
    const float* elen = (const float*)d_in[3];
    const float* w0   = (const float*)d_in[4];
    const float* w1   = (const float*)d_in[5];
    const float* w2   = (const float*)d_in[6];
    const float* wm0  = (const float*)d_in[7];
    const float* wm1  = (const float*)d_in[8];
    const float* envl = (const float*)d_in[9];
    const float* latw = (const float*)d_in[10];
    const float* l2fn = (const float*)d_in[11];
    const float* l2fo = (const float*)d_in[12];
    const float* finw = (const float*)d_in[13];
    const int*   eidx = (const int*)d_in[14];

    char* ws = (char*)d_ws;
    unsigned* latfT  = (unsigned*)(ws + 0);            // [76][E] u32
    unsigned* newfT  = (unsigned*)(ws + 48640000);     // [36][E]; also wcur1 [E][24] f32
    unsigned* feat1T = (unsigned*)(ws + 71680000);     // [36][E]; also wcur0 [E][24] f32
    unsigned* winiT  = (unsigned*)(ws + 94720000);     // [12][E]; also pout [2][E][3] f32
    bf16*     eaT    = (bf16*)(ws + 102400000);        // [9][E]
    float*    cutb   = (float*)(ws + 105280000);       // [E]
    float*    env0   = (float*)(ws + 105920000);       // [N*72]
    float*    env1   = (float*)(ws + 108800000);       // [N*72]
    int*      deg    = (int*)(ws + 111680000);         // [N]
    int*      cur    = (int*)(ws + 111720000);         // [N]
    int*      off    = (int*)(ws + 111760000);         // [N+1]
    int*      elist  = (int*)(ws + 111920016);         // [E]

    float* wcur0 = (float*)feat1T;
    float* wcur1 = (float*)newfT;
    float* pout  = (float*)winiT;

    hipMemsetAsync(deg, 0, 80000, stream);  // deg + cur contiguous

    kCnt <<<625, 256, 0, stream>>>(eidx, deg);
    kScan<<<1, 256, 0, stream>>>(deg, off);
    kFill<<<625, 256, 0, stream>>>(eidx, cur, off, elist);

    kA<<<1250, 128, 0, stream>>>(ea, eemb, nat, elen, w0, w1, w2, wm0, eidx,
                                 latfT, winiT, eaT, cutb, wcur0);
    kEnvG<<<352, 256, 0, stream>>>(wcur0, ea, off, elist, envl + 0, env0);
    kC1<<<625, 256, 0, stream>>>(winiT, eaT, env0, eidx, newfT, latfT);
    kC2<<<dim3(625, 6), 256, 0, stream>>>(latfT, winiT, eaT, newfT,
                                          l2fo + 0, l2fn + 0, feat1T);
    kC3<<<625, 256, 0, stream>>>(latfT, latw, wm1, cutb, wcur1);
    kEnvG<<<352, 256, 0, stream>>>(wcur1, ea, off, elist, envl + 192, env1);
    kE1<<<625, 256, 0, stream>>>(feat1T, env1, eidx, newfT, latfT);
    kE2<<<dim3(625, 2), 256, 0, stream>>>(latfT, feat1T, newfT,
                                          l2fo + 29184, l2fn + 29184, finw, pout);
    kOut<<<1875, 256, 0, stream>>>(pout, (float*)d_out);
}

// Round 4
// 995.043 us; speedup vs baseline: 2.9633x; 1.9933x over previous
//
#include <hip/hip_runtime.h>
#include <hip/hip_bf16.h>

#define EE 160000
#define NNODES 10000

using bf16 = __hip_bfloat16;
using bf16x8 = __attribute__((ext_vector_type(8))) short;
using f32x4  = __attribute__((ext_vector_type(4))) float;

__device__ __forceinline__ float silu_f(float x) { return x / (1.0f + __expf(-x)); }
__device__ __forceinline__ float b2f(bf16 v) { return __bfloat162float(v); }
__device__ __forceinline__ bf16 f2b(float v) { return __float2bfloat16(v); }

__device__ __forceinline__ unsigned bfbits(float v) {
    union { float f; unsigned u; } a; a.f = v;
    return (a.u + 0x7fffu + ((a.u >> 16) & 1u)) >> 16;
}
__device__ __forceinline__ unsigned pack2(float a, float b) {
    return bfbits(a) | (bfbits(b) << 16);
}
__device__ __forceinline__ void unpack2(unsigned u, float& a, float& b) {
    union { unsigned x; float f; } lo, hi;
    lo.x = u << 16; hi.x = u & 0xffff0000u;
    a = lo.f; b = hi.f;
}
__device__ __forceinline__ float bs2f(short s) {
    union { unsigned u; float f; } x; x.u = ((unsigned)(unsigned short)s) << 16;
    return x.f;
}

// 1/(16*sqrt(8)), 0.5/sqrt(8), 1/sqrt(8)
#define INV_AVGN_SQM 0.02209708691207961f
#define HALF_INV_SQM 0.17677669529663687f
#define INV_SQM      0.35355339059327373f

// ---------------------------------------------------------------------------
// CSR build
// ---------------------------------------------------------------------------
__global__ void kCnt(const int* __restrict__ eidx, int* __restrict__ deg)
{
    const int e = blockIdx.x * 256 + threadIdx.x;
    atomicAdd(&deg[eidx[e]], 1);
}

__global__ void kScan(const int* __restrict__ deg, int* __restrict__ off)
{
    __shared__ int part[256];
    const int t = threadIdx.x;
    int loc[40];
    int s = 0;
#pragma unroll
    for (int i = 0; i < 40; i++) {
        const int idx = t * 40 + i;
        const int v = (idx < NNODES) ? deg[idx] : 0;
        loc[i] = s;
        s += v;
    }
    part[t] = s;
    __syncthreads();
    for (int d = 1; d < 256; d <<= 1) {
        const int v = (t >= d) ? part[t - d] : 0;
        __syncthreads();
        part[t] += v;
        __syncthreads();
    }
    const int base = (t == 0) ? 0 : part[t - 1];
#pragma unroll
    for (int i = 0; i < 40; i++) {
        const int idx = t * 40 + i;
        if (idx < NNODES) off[idx] = base + loc[i];
    }
    if (t == 255) off[NNODES] = part[255];
}

__global__ void kFill(const int* __restrict__ eidx, int* __restrict__ cur,
                      const int* __restrict__ off, int* __restrict__ elist)
{
    const int e = blockIdx.x * 256 + threadIdx.x;
    const int c = eidx[e];
    const int pos = atomicAdd(&cur[c], 1);
    elist[off[c] + pos] = e;
}

// ---------------------------------------------------------------------------
// kEnvG: gather env + fused env-linear (per node,d)
// ---------------------------------------------------------------------------
__global__ void kEnvG(const float* __restrict__ wcur, const float* __restrict__ ea,
                      const int* __restrict__ off, const int* __restrict__ elist,
                      const float* __restrict__ wl, float* __restrict__ envc)
{
    const int t = blockIdx.x * 256 + threadIdx.x;
    if (t >= NNODES * 9) return;
    const int n = t / 9;
    const int d = t - n * 9;
    const int irr = (d == 0) ? 0 : ((d < 4) ? 1 : 2);
    float v[8];
#pragma unroll
    for (int q = 0; q < 8; q++) v[q] = 0.0f;
    const int b = off[n], en = off[n + 1];
    for (int j = b; j < en; j++) {
        const int e = elist[j];
        const float ad = ea[e * 9 + d];
        const float* wr = wcur + (size_t)e * 24 + irr;
#pragma unroll
        for (int q = 0; q < 8; q++) v[q] = fmaf(wr[q * 3], ad, v[q]);
    }
#pragma unroll
    for (int u = 0; u < 8; u++) {
        float s = 0.0f;
#pragma unroll
        for (int q = 0; q < 8; q++) s = fmaf(wl[irr * 64 + u * 8 + q], v[q], s);
        envc[n * 72 + u * 9 + d] = s * INV_AVGN_SQM;
    }
}

// ---------------------------------------------------------------------------
// kA0: inputs gather + cutoff + stage0 (16->128) -> h08 tiled layout; eaT; pad
// h08 layout: [E/32][16][32][8] bf16 ; latf8 pad chunk 19 zeroed
// ---------------------------------------------------------------------------
__global__ __launch_bounds__(256) void kA0(
    const float* __restrict__ ea, const float* __restrict__ eemb,
    const float* __restrict__ nat, const float* __restrict__ elen,
    const float* __restrict__ w0, const int* __restrict__ eidx,
    short* __restrict__ h08, short* __restrict__ latf8s,
    bf16* __restrict__ eaT, float* __restrict__ cutb)
{
    __shared__ float w0s[16 * 128];
    const int t = threadIdx.x;
    const int e = blockIdx.x * 256 + t;
#pragma unroll
    for (int p = 0; p < 8; p++) { const int idx = p * 256 + t; w0s[idx] = w0[idx]; }
    __syncthreads();

    const int ctr = eidx[e];
    const int ngb = eidx[EE + e];
    float tin[16];
#pragma unroll
    for (int k = 0; k < 4; k++) tin[k] = nat[ctr * 4 + k];
#pragma unroll
    for (int k = 0; k < 4; k++) tin[4 + k] = nat[ngb * 4 + k];
#pragma unroll
    for (int k = 0; k < 8; k++) tin[8 + k] = eemb[e * 8 + k];

    const float x = elen[e];
    const float x2 = x * x, x4 = x2 * x2, x6 = x4 * x2, x7 = x6 * x, x8 = x7 * x;
    float cutv = 1.0f - 28.0f * x6 + 48.0f * x7 - 21.0f * x8;
    cutv = (x < 1.0f) ? cutv : 0.0f;
    cutb[e] = cutv;

    const size_t tb = (size_t)(e >> 5);
    const int el = e & 31;
#pragma unroll
    for (int jc = 0; jc < 4; jc++) {
        float a[32];
#pragma unroll
        for (int j = 0; j < 32; j++) a[j] = 0.0f;
#pragma unroll
        for (int k = 0; k < 16; k++) {
            const float v = tin[k];
#pragma unroll
            for (int j = 0; j < 32; j++) a[j] = fmaf(v, w0s[k * 128 + jc * 32 + j], a[j]);
        }
#pragma unroll
        for (int cc = 0; cc < 4; cc++) {
            bf16x8 hv;
#pragma unroll
            for (int jj = 0; jj < 8; jj++) hv[jj] = (short)bfbits(silu_f(a[cc * 8 + jj]));
            *(bf16x8*)(h08 + tb * 4096 + (jc * 4 + cc) * 256 + el * 8) = hv;
        }
    }
    // zero latf8 pad chunk (k = 152..159)
    bf16x8 z;
#pragma unroll
    for (int jj = 0; jj < 8; jj++) z[jj] = 0;
    *(bf16x8*)(latf8s + tb * 5120 + 19 * 256 + el * 8) = z;

#pragma unroll
    for (int d = 0; d < 9; d++) eaT[(size_t)d * EE + e] = f2b(ea[e * 9 + d]);
}

// ---------------------------------------------------------------------------
// kAm: MFMA chain h0@w1 -> silu -> @w2 -> *cut -> latents ; latents@wm0 -> ewv
// block: 64 edges, 4 waves (2m x 2n). Weights staged bf16 in LDS [n][136].
// ---------------------------------------------------------------------------
__global__ __launch_bounds__(256, 2) void kAm(
    const short* __restrict__ h08, const float* __restrict__ w1,
    const float* __restrict__ w2, const float* __restrict__ wm0,
    const float* __restrict__ cutb, unsigned* __restrict__ latf8w,
    float* __restrict__ winiF, float* __restrict__ wcur0)
{
    __shared__ short Bs[128 * 136];
    __shared__ short A2[64 * 136];
    __shared__ short A3[64 * 136];
    const int t = threadIdx.x;
    const int eb = blockIdx.x * 64;
    const int lane = t & 63, wid = t >> 6;
    const int wm = wid >> 1, wn = wid & 1;
    const int l15 = lane & 15, kq = lane >> 4;
    const f32x4 zz = {0.f, 0.f, 0.f, 0.f};

    // stage B <- w1
#pragma unroll
    for (int p = 0; p < 68; p++) {
        const int idx = p * 256 + t;
        const int n = idx & 127, k = idx >> 7;
        const float v = (k < 128) ? w1[k * 128 + n] : 0.f;
        Bs[n * 136 + k] = (short)bfbits(v);
    }
    float cutR[2][4];
#pragma unroll
    for (int mi = 0; mi < 2; mi++)
#pragma unroll
        for (int r = 0; r < 4; r++)
            cutR[mi][r] = cutb[eb + wm * 32 + mi * 16 + kq * 4 + r];
    __syncthreads();

    // GEMM1: h1 = silu(h0 @ w1) -> A2
    {
        f32x4 acc[8];
#pragma unroll
        for (int q = 0; q < 8; q++) acc[q] = zz;
        const size_t ab = (size_t)((eb >> 5) + wm) * 4096 + l15 * 8;
#pragma unroll
        for (int ks = 0; ks < 4; ks++) {
            const bf16x8 a0 = *(const bf16x8*)(h08 + ab + (ks * 4 + kq) * 256);
            const bf16x8 a1 = *(const bf16x8*)(h08 + ab + (ks * 4 + kq) * 256 + 128);
            const short* bp = Bs + (wn * 64 + l15) * 136 + ks * 32 + kq * 8;
#pragma unroll
            for (int ni = 0; ni < 4; ni++) {
                const bf16x8 b = *(const bf16x8*)(bp + ni * 16 * 136);
                acc[ni]     = __builtin_amdgcn_mfma_f32_16x16x32_bf16(a0, b, acc[ni], 0, 0, 0);
                acc[4 + ni] = __builtin_amdgcn_mfma_f32_16x16x32_bf16(a1, b, acc[4 + ni], 0, 0, 0);
            }
        }
#pragma unroll
        for (int mi = 0; mi < 2; mi++)
#pragma unroll
            for (int ni = 0; ni < 4; ni++)
#pragma unroll
                for (int r = 0; r < 4; r++)
                    A2[(wm * 32 + mi * 16 + kq * 4 + r) * 136 + wn * 64 + ni * 16 + l15] =
                        (short)bfbits(silu_f(acc[mi * 4 + ni][r]));
    }
    __syncthreads();
    // stage B <- w2
#pragma unroll
    for (int p = 0; p < 68; p++) {
        const int idx = p * 256 + t;
        const int n = idx & 127, k = idx >> 7;
        const float v = (k < 128) ? w2[k * 128 + n] : 0.f;
        Bs[n * 136 + k] = (short)bfbits(v);
    }
    __syncthreads();

    // GEMM2: latents = (h1 @ w2) * cut -> A3
    {
        f32x4 acc[8];
#pragma unroll
        for (int q = 0; q < 8; q++) acc[q] = zz;
#pragma unroll
        for (int ks = 0; ks < 4; ks++) {
            const short* ap = A2 + (wm * 32 + l15) * 136 + ks * 32 + kq * 8;
            const bf16x8 a0 = *(const bf16x8*)(ap);
            const bf16x8 a1 = *(const bf16x8*)(ap + 16 * 136);
            const short* bp = Bs + (wn * 64 + l15) * 136 + ks * 32 + kq * 8;
#pragma unroll
            for (int ni = 0; ni < 4; ni++) {
                const bf16x8 b = *(const bf16x8*)(bp + ni * 16 * 136);
                acc[ni]     = __builtin_amdgcn_mfma_f32_16x16x32_bf16(a0, b, acc[ni], 0, 0, 0);
                acc[4 + ni] = __builtin_amdgcn_mfma_f32_16x16x32_bf16(a1, b, acc[4 + ni], 0, 0, 0);
            }
        }
#pragma unroll
        for (int mi = 0; mi < 2; mi++)
#pragma unroll
            for (int ni = 0; ni < 4; ni++)
#pragma unroll
                for (int r = 0; r < 4; r++)
                    A3[(wm * 32 + mi * 16 + kq * 4 + r) * 136 + wn * 64 + ni * 16 + l15] =
                        (short)bfbits(acc[mi * 4 + ni][r] * cutR[mi][r]);
    }
    __syncthreads();
    // stage B <- wm0 (48 cols) ; copy A3 -> latf8
#pragma unroll
    for (int p = 0; p < 68; p++) {
        const int idx = p * 256 + t;
        const int n = idx & 127, k = idx >> 7;
        const float v = (k < 128 && n < 48) ? wm0[k * 48 + n] : 0.f;
        Bs[n * 136 + k] = (short)bfbits(v);
    }
#pragma unroll
    for (int p = 0; p < 16; p++) {
        const int ii = p * 256 + t;
        const int e = ii & 63, w = ii >> 6;
        const unsigned u = *(const unsigned*)&A3[e * 136 + 2 * w];
        const int eg = eb + e;
        latf8w[(size_t)(eg >> 5) * 2560 + (w >> 2) * 128 + (eg & 31) * 4 + (w & 3)] = u;
    }
    __syncthreads();

    // GEMM3: ewv = latents @ wm0 (wn==0 waves only)
    if (wn == 0) {
        f32x4 acc[8];
#pragma unroll
        for (int q = 0; q < 8; q++) acc[q] = zz;
#pragma unroll
        for (int ks = 0; ks < 4; ks++) {
            const short* ap = A3 + (wm * 32 + l15) * 136 + ks * 32 + kq * 8;
            const bf16x8 a0 = *(const bf16x8*)(ap);
            const bf16x8 a1 = *(const bf16x8*)(ap + 16 * 136);
            const short* bp = Bs + l15 * 136 + ks * 32 + kq * 8;
#pragma unroll
            for (int ni = 0; ni < 4; ni++) {
                const bf16x8 b = *(const bf16x8*)(bp + ni * 16 * 136);
                acc[ni]     = __builtin_amdgcn_mfma_f32_16x16x32_bf16(a0, b, acc[ni], 0, 0, 0);
                acc[4 + ni] = __builtin_amdgcn_mfma_f32_16x16x32_bf16(a1, b, acc[4 + ni], 0, 0, 0);
            }
        }
#pragma unroll
        for (int mi = 0; mi < 2; mi++)
#pragma unroll
            for (int ni = 0; ni < 3; ni++)
#pragma unroll
                for (int r = 0; r < 4; r++) {
                    const int c = ni * 16 + l15;
                    if (c < 48) {
                        const int e = eb + wm * 32 + mi * 16 + kq * 4 + r;
                        const float v = acc[mi * 4 + ni][r];
                        if (c < 24) winiF[(size_t)c * EE + e] = v;
                        else        wcur0[(size_t)e * 24 + (c - 24)] = v;
                    }
                }
    }
}

// ---------------------------------------------------------------------------
// kGemm: C[chE][N] = latf8[e0..][160] @ B(desc1++desc2++desc3), out bf16 [N][chE]
// block: 64 edges x 128 cols (2x2 waves, wave tile 32x64)
// ---------------------------------------------------------------------------
__global__ __launch_bounds__(256, 3) void kGemm(
    const short* __restrict__ A8, int e0, int chE,
    const float* __restrict__ p1, int ld1, int o1, int n1,
    const float* __restrict__ p2, int ld2, int o2, int n2,
    const float* __restrict__ p3, int ld3, int o3, int n3,
    unsigned* __restrict__ Wg)
{
    __shared__ short Bs[128 * 168];
    const int t = threadIdx.x;
    const int Nval = n1 + n2 + n3;
    const int colbase = blockIdx.y * 128;
#pragma unroll
    for (int p = 0; p < 84; p++) {
        const int idx = p * 256 + t;
        const int n = idx & 127, k = idx >> 7;
        float v = 0.f;
        const int ng = colbase + n;
        if (k < 152 && ng < Nval) {
            if (ng < n1)            v = p1[k * ld1 + o1 + ng];
            else if (ng < n1 + n2)  v = p2[k * ld2 + o2 + (ng - n1)];
            else                    v = p3[k * ld3 + o3 + (ng - n1 - n2)];
        }
        Bs[n * 168 + k] = (short)bfbits(v);
    }
    __syncthreads();

    const int lane = t & 63, wid = t >> 6;
    const int wm = wid >> 1, wn = wid & 1;
    const int l15 = lane & 15, kq = lane >> 4;
    const f32x4 zz = {0.f, 0.f, 0.f, 0.f};
    f32x4 acc[8];
#pragma unroll
    for (int q = 0; q < 8; q++) acc[q] = zz;
    const size_t ab = (size_t)(((e0 + blockIdx.x * 64) >> 5) + wm) * 5120 + l15 * 8;
#pragma unroll
    for (int ks = 0; ks < 5; ks++) {
        const bf16x8 a0 = *(const bf16x8*)(A8 + ab + (ks * 4 + kq) * 256);
        const bf16x8 a1 = *(const bf16x8*)(A8 + ab + (ks * 4 + kq) * 256 + 128);
        const short* bp = Bs + (wn * 64 + l15) * 168 + ks * 32 + kq * 8;
#pragma unroll
        for (int ni = 0; ni < 4; ni++) {
            const bf16x8 b = *(const bf16x8*)(bp + ni * 16 * 168);
            acc[ni]     = __builtin_amdgcn_mfma_f32_16x16x32_bf16(a0, b, acc[ni], 0, 0, 0);
            acc[4 + ni] = __builtin_amdgcn_mfma_f32_16x16x32_bf16(a1, b, acc[4 + ni], 0, 0, 0);
        }
    }
    const int ebL = blockIdx.x * 64 + wm * 32 + (kq << 2);
#pragma unroll
    for (int mi = 0; mi < 2; mi++)
#pragma unroll
        for (int ni = 0; ni < 4; ni++) {
            const int col = colbase + wn * 64 + ni * 16 + l15;
            if (col < Nval) {
                const int eL = ebL + mi * 16;
                const f32x4 v = acc[mi * 4 + ni];
                unsigned* p = Wg + (((size_t)col * chE + eL) >> 1);
                p[0] = pack2(v[0], v[1]);
                p[1] = pack2(v[2], v[3]);
            }
        }
}

// ---------------------------------------------------------------------------
// kC1: layer-0 interact + invariants (wini f32, inv -> latf8)
// ---------------------------------------------------------------------------
__global__ __launch_bounds__(256, 1) void kC1(
    const float* __restrict__ winiF, const bf16* __restrict__ eaT,
    const float* __restrict__ envc, const int* __restrict__ eidx,
    unsigned* __restrict__ newfT, short* __restrict__ latf8s)
{
    const int e = blockIdx.x * 256 + threadIdx.x;
    const int ctr = eidx[e];
    float eav[9];
#pragma unroll
    for (int d = 0; d < 9; d++) eav[d] = b2f(eaT[(size_t)d * EE + e]);
    const float* ec = envc + ctr * 72;
    float inv[24];
#pragma unroll
    for (int uh = 0; uh < 4; uh++) {
        const int u0 = 2 * uh;
        float wi0[3], wi1[3];
#pragma unroll
        for (int i = 0; i < 3; i++) {
            wi0[i] = winiF[(size_t)(u0 * 3 + i) * EE + e];
            wi1[i] = winiF[(size_t)((u0 + 1) * 3 + i) * EE + e];
        }
        float nf0[9], nf1[9];
        const float ec00 = ec[u0 * 9 + 0];
        const float ec10 = ec[(u0 + 1) * 9 + 0];
        const float f00 = wi0[0] * eav[0];
        const float f10 = wi1[0] * eav[0];
#pragma unroll
        for (int d = 0; d < 9; d++) {
            const int irr = (d == 0) ? 0 : ((d < 4) ? 1 : 2);
            const float fa = wi0[irr] * eav[d];
            const float fb = wi1[irr] * eav[d];
            nf0[d] = fa * ec00 + ec[u0 * 9 + d] * f00;
            nf1[d] = fb * ec10 + ec[(u0 + 1) * 9 + d] * f10;
        }
#pragma unroll
        for (int d = 0; d < 9; d++) newfT[(size_t)(d * 4 + uh) * EE + e] = pack2(nf0[d], nf1[d]);
        inv[uh * 6 + 0] = sqrtf(nf0[0] * nf0[0] + 1e-8f);
        inv[uh * 6 + 1] = sqrtf(nf0[1]*nf0[1] + nf0[2]*nf0[2] + nf0[3]*nf0[3] + 1e-8f);
        inv[uh * 6 + 2] = sqrtf(nf0[4]*nf0[4] + nf0[5]*nf0[5] + nf0[6]*nf0[6] + nf0[7]*nf0[7] + nf0[8]*nf0[8] + 1e-8f);
        inv[uh * 6 + 3] = sqrtf(nf1[0] * nf1[0] + 1e-8f);
        inv[uh * 6 + 4] = sqrtf(nf1[1]*nf1[1] + nf1[2]*nf1[2] + nf1[3]*nf1[3] + 1e-8f);
        inv[uh * 6 + 5] = sqrtf(nf1[4]*nf1[4] + nf1[5]*nf1[5] + nf1[6]*nf1[6] + nf1[7]*nf1[7] + nf1[8]*nf1[8] + 1e-8f);
    }
    const size_t tb = (size_t)(e >> 5);
    const int el = e & 31;
#pragma unroll
    for (int j = 0; j < 3; j++) {
        bf16x8 iv;
#pragma unroll
        for (int jj = 0; jj < 8; jj++) iv[jj] = (short)bfbits(inv[j * 8 + jj]);
        *(bf16x8*)(latf8s + tb * 5120 + (16 + j) * 256 + el * 8) = iv;
    }
}

// ---------------------------------------------------------------------------
// kC2b: epilogue layer-0 pe_linear (reads generated W from Wg)
// ---------------------------------------------------------------------------
__global__ __launch_bounds__(256, 1) void kC2b(
    const short* __restrict__ Wg, int chE, int e0,
    const float* __restrict__ winiF, const bf16* __restrict__ eaT,
    const unsigned* __restrict__ newfT, unsigned* __restrict__ feat1T)
{
    const int eL = blockIdx.x * 256 + threadIdx.x;
    if (eL >= chE) return;
    const int e = e0 + eL;
    const int ir = blockIdx.y >> 1;
    const int uh2 = blockIdx.y & 1;
    const int d0 = (ir == 0) ? 0 : ((ir == 1) ? 1 : 4);
    const int nd = (ir == 0) ? 1 : ((ir == 1) ? 3 : 5);
    float accO[32], accN[32];
#pragma unroll
    for (int q = 0; q < 32; q++) {
        accO[q] = bs2f(Wg[(size_t)(ir * 64 + uh2 * 32 + q) * chE + eL]);
        accN[q] = bs2f(Wg[(size_t)(192 + ir * 64 + uh2 * 32 + q) * chE + eL]);
    }
    float wv[8];
#pragma unroll
    for (int v = 0; v < 8; v++) wv[v] = winiF[(size_t)(v * 3 + ir) * EE + e];
    for (int dd = 0; dd < nd; dd++) {
        const int d = d0 + dd;
        const float ead = b2f(eaT[(size_t)d * EE + e]);
        float nfv[8];
#pragma unroll
        for (int q = 0; q < 4; q++) unpack2(newfT[(size_t)(d * 4 + q) * EE + e], nfv[2 * q], nfv[2 * q + 1]);
        float s[4];
#pragma unroll
        for (int up = 0; up < 4; up++) {
            float tt = 0.0f;
#pragma unroll
            for (int v = 0; v < 8; v++)
                tt += accO[up * 8 + v] * (wv[v] * ead) + accN[up * 8 + v] * nfv[v];
            s[up] = tt * HALF_INV_SQM;
        }
        feat1T[(size_t)(d * 4 + uh2 * 2 + 0) * EE + e] = pack2(s[0], s[1]);
        feat1T[(size_t)(d * 4 + uh2 * 2 + 1) * EE + e] = pack2(s[2], s[3]);
    }
}

// ---------------------------------------------------------------------------
// kC3b: latent resnet (reads Wg3 = latf@latw) + env-MLP1 -> wcur1; updates latf8
// ---------------------------------------------------------------------------
__global__ __launch_bounds__(256, 1) void kC3b(
    short* __restrict__ latf8s, const short* __restrict__ Wg3,
    const float* __restrict__ wm1, const float* __restrict__ cutb,
    float* __restrict__ wcur1)
{
    __shared__ float wm1s[128 * 24];
    const int t = threadIdx.x;
    const int e = blockIdx.x * 256 + t;
#pragma unroll
    for (int p = 0; p < 12; p++) { const int idx = p * 256 + t; wm1s[idx] = wm1[idx]; }
    __syncthreads();
    const float cutv = cutb[e];
    float wc[24];
#pragma unroll
    for (int c = 0; c < 24; c++) wc[c] = 0.0f;
    const size_t tb = (size_t)(e >> 5);
    const int el = e & 31;
#pragma unroll
    for (int c = 0; c < 16; c++) {
        short* ap = latf8s + tb * 5120 + c * 256 + el * 8;
        const bf16x8 ov = *(const bf16x8*)ap;
        bf16x8 nv;
#pragma unroll
        for (int jj = 0; jj < 8; jj++) {
            const int j = c * 8 + jj;
            const float g = bs2f(Wg3[(size_t)j * EE + e]);
            const float o = bs2f(ov[jj]);
            const float l1 = 0.5f * o + 0.5f * silu_f(g) * cutv;
            nv[jj] = (short)bfbits(l1);
#pragma unroll
            for (int cc = 0; cc < 24; cc++) wc[cc] = fmaf(l1, wm1s[j * 24 + cc], wc[cc]);
        }
        *(bf16x8*)ap = nv;
    }
#pragma unroll
    for (int cc = 0; cc < 24; cc++) wcur1[(size_t)e * 24 + cc] = wc[cc];
}

// ---------------------------------------------------------------------------
// kE1: layer-1 interact + invariants
// ---------------------------------------------------------------------------
__global__ __launch_bounds__(256, 1) void kE1(
    const unsigned* __restrict__ feat1T, const float* __restrict__ envc,
    const int* __restrict__ eidx, unsigned* __restrict__ newfT,
    short* __restrict__ latf8s)
{
    const int e = blockIdx.x * 256 + threadIdx.x;
    const int ctr = eidx[e];
    const float* ec = envc + ctr * 72;
    float inv[24];
#pragma unroll
    for (int uh = 0; uh < 4; uh++) {
        const int u0 = 2 * uh;
        float f0[9], f1[9];
#pragma unroll
        for (int d = 0; d < 9; d++) unpack2(feat1T[(size_t)(d * 4 + uh) * EE + e], f0[d], f1[d]);
        const float ec00 = ec[u0 * 9 + 0];
        const float ec10 = ec[(u0 + 1) * 9 + 0];
        float nf0[9], nf1[9];
#pragma unroll
        for (int d = 0; d < 9; d++) {
            nf0[d] = f0[d] * ec00 + ec[u0 * 9 + d] * f0[0];
            nf1[d] = f1[d] * ec10 + ec[(u0 + 1) * 9 + d] * f1[0];
        }
#pragma unroll
        for (int d = 0; d < 9; d++) newfT[(size_t)(d * 4 + uh) * EE + e] = pack2(nf0[d], nf1[d]);
        inv[uh * 6 + 0] = sqrtf(nf0[0] * nf0[0] + 1e-8f);
        inv[uh * 6 + 1] = sqrtf(nf0[1]*nf0[1] + nf0[2]*nf0[2] + nf0[3]*nf0[3] + 1e-8f);
        inv[uh * 6 + 2] = sqrtf(nf0[4]*nf0[4] + nf0[5]*nf0[5] + nf0[6]*nf0[6] + nf0[7]*nf0[7] + nf0[8]*nf0[8] + 1e-8f);
        inv[uh * 6 + 3] = sqrtf(nf1[0] * nf1[0] + 1e-8f);
        inv[uh * 6 + 4] = sqrtf(nf1[1]*nf1[1] + nf1[2]*nf1[2] + nf1[3]*nf1[3] + 1e-8f);
        inv[uh * 6 + 5] = sqrtf(nf1[4]*nf1[4] + nf1[5]*nf1[5] + nf1[6]*nf1[6] + nf1[7]*nf1[7] + nf1[8]*nf1[8] + 1e-8f);
    }
    const size_t tb = (size_t)(e >> 5);
    const int el = e & 31;
#pragma unroll
    for (int j = 0; j < 3; j++) {
        bf16x8 iv;
#pragma unroll
        for (int jj = 0; jj < 8; jj++) iv[jj] = (short)bfbits(inv[j * 8 + jj]);
        *(bf16x8*)(latf8s + tb * 5120 + (16 + j) * 256 + el * 8) = iv;
    }
}

// ---------------------------------------------------------------------------
// kE2b: final epilogue (reads WgE), partials to pout
// ---------------------------------------------------------------------------
__global__ __launch_bounds__(256, 1) void kE2b(
    const short* __restrict__ WgE, int chE, int e0,
    const unsigned* __restrict__ feat1T, const unsigned* __restrict__ newfT,
    float* __restrict__ pout)
{
    const int eL = blockIdx.x * 256 + threadIdx.x;
    if (eL >= chE) return;
    const int e = e0 + eL;
    const int uh2 = blockIdx.y;
    float accO[32], accN[32], wf[4];
#pragma unroll
    for (int q = 0; q < 32; q++) {
        accO[q] = bs2f(WgE[(size_t)(uh2 * 32 + q) * chE + eL]);
        accN[q] = bs2f(WgE[(size_t)(64 + uh2 * 32 + q) * chE + eL]);
    }
#pragma unroll
    for (int m = 0; m < 4; m++) wf[m] = bs2f(WgE[(size_t)(128 + uh2 * 4 + m) * chE + eL]);
#pragma unroll
    for (int dd = 0; dd < 3; dd++) {
        const int d = 1 + dd;
        float f1v[8], nfv[8];
#pragma unroll
        for (int q = 0; q < 4; q++) {
            unpack2(feat1T[(size_t)(d * 4 + q) * EE + e], f1v[2 * q], f1v[2 * q + 1]);
            unpack2(newfT[(size_t)(d * 4 + q) * EE + e], nfv[2 * q], nfv[2 * q + 1]);
        }
        float od = 0.0f;
#pragma unroll
        for (int up = 0; up < 4; up++) {
            float s = 0.0f;
#pragma unroll
            for (int v = 0; v < 8; v++)
                s += accO[up * 8 + v] * f1v[v] + accN[up * 8 + v] * nfv[v];
            od = fmaf(wf[up], s, od);
        }
        pout[((size_t)uh2 * EE + e) * 3 + dd] = od * (HALF_INV_SQM * INV_SQM);
    }
}

__global__ void kOut(const float* __restrict__ pout, float* __restrict__ outp)
{
    const int t = blockIdx.x * 256 + threadIdx.x;
    if (t >= EE * 3) return;
    outp[t] = pout[t] + pout[(size_t)EE * 3 + t];
}

// ---------------------------------------------------------------------------
extern "C" void kernel_launch(void* const* d_in, const int* in_sizes, int n_in,
                              void* d_out, int out_size, void* d_ws, size_t ws_size,
                              hipStream_t stream)
{
    const float* ea   = (const float*)d_in[0];
    const float* eemb = (const float*)d_in[1];
    const float* nat  = (const float*)d_in[2];
    const float* elen = (const float*)d_in[3];
    const float* w0   = (const float*)d_in[4];
    const float* w1   = (const float*)d_in[5];
    const float* w2   = (const float*)d_in[6];
    const float* wm0  = (const float*)d_in[7];
    const float* wm1  = (const float*)d_in[8];
    const float* envl = (const float*)d_in[9];
    const float* latw = (const float*)d_in[10];
    const float* l2fn = (const float*)d_in[11];
    const float* l2fo = (const float*)d_in[12];
    const float* finw = (const float*)d_in[13];
    const int*   eidx = (const int*)d_in[14];

    char* ws = (char*)d_ws;
    short*    latf8s = (short*)(ws + 0);               // [E/32][20][32][8] bf16, 51.2MB
    unsigned* latf8w = (unsigned*)(ws + 0);
    short*    h08    = (short*)(ws + 51200000);        // [E/32][16][32][8] bf16, 40.96MB
    short*    WgS    = (short*)(ws + 51200000);        // aliased: Wg chunks (<=40.96MB)
    unsigned* WgU    = (unsigned*)(ws + 51200000);
    unsigned* newfT  = (unsigned*)(ws + 92160000);     // [36][EE] u32; aliased wcur0/wcur1
    unsigned* feat1T = (unsigned*)(ws + 115200000);    // [36][EE] u32
    float*    winiF  = (float*)(ws + 138240000);       // [24][EE] f32; aliased pout
    bf16*     eaT    = (bf16*)(ws + 153600000);        // [9][EE]
    float*    cutb   = (float*)(ws + 156480000);       // [E]
    float*    env0   = (float*)(ws + 157120000);       // [N*72]
    float*    env1   = (float*)(ws + 160000000);       // [N*72]
    int*      deg    = (int*)(ws + 162880000);
    int*      cur    = (int*)(ws + 162920000);
    int*      off    = (int*)(ws + 162960000);
    int*      elist  = (int*)(ws + 163000192);

    float* wcur0 = (float*)newfT;
    float* wcur1 = (float*)newfT;
    float* pout  = (float*)winiF;

    hipMemsetAsync(deg, 0, 80000, stream);

    kCnt <<<625, 256, 0, stream>>>(eidx, deg);
    kScan<<<1, 256, 0, stream>>>(deg, off);
    kFill<<<625, 256, 0, stream>>>(eidx, cur, off, elist);

    kA0<<<625, 256, 0, stream>>>(ea, eemb, nat, elen, w0, eidx, h08, latf8s, eaT, cutb);
    kAm<<<2500, 256, 0, stream>>>(h08, w1, w2, wm0, cutb, latf8w, winiF, wcur0);
    kEnvG<<<352, 256, 0, stream>>>(wcur0, ea, off, elist, envl + 0, env0);
    kC1<<<625, 256, 0, stream>>>(winiF, eaT, env0, eidx, newfT, latf8s);

    for (int c = 0; c < 4; c++) {
        const int e0 = c * 40000;
        kGemm<<<dim3(625, 3), 256, 0, stream>>>(latf8s, e0, 40000,
            l2fo, 192, 0, 192,  l2fn, 192, 0, 192,  l2fn, 192, 0, 0, WgU);
        kC2b<<<dim3(157, 6), 256, 0, stream>>>(WgS, 40000, e0, winiF, eaT, newfT, feat1T);
    }

    kGemm<<<dim3(2500, 1), 256, 0, stream>>>(latf8s, 0, EE,
        latw, 128, 0, 128,  latw, 128, 0, 0,  latw, 128, 0, 0, WgU);
    kC3b<<<625, 256, 0, stream>>>(latf8s, WgS, wm1, cutb, wcur1);
    kEnvG<<<352, 256, 0, stream>>>(wcur1, ea, off, elist, envl + 192, env1);
    kE1<<<625, 256, 0, stream>>>(feat1T, env1, eidx, newfT, latf8s);

    for (int c = 0; c < 2; c++) {
        const int e0 = c * 80000;
        kGemm<<<dim3(1250, 2), 256, 0, stream>>>(latf8s, e0, 80000,
            l2fo + 29184, 192, 64, 64,  l2fn + 29184, 192, 64, 64,  finw, 8, 0, 8, WgU);
        kE2b<<<dim3(313, 2), 256, 0, stream>>>(WgS, 80000, e0, feat1T, newfT, pout);
    }
    kOut<<<1875, 256, 0, stream>>>(pout, (float*)d_out);
}

// Round 6
// 473.611 us; speedup vs baseline: 6.2258x; 2.1010x over previous
//
#include <hip/hip_runtime.h>
#include <hip/hip_bf16.h>

#define EE 160000
#define NNODES 10000

using bf16 = __hip_bfloat16;
using bf16x8 = __attribute__((ext_vector_type(8))) short;
using f32x4  = __attribute__((ext_vector_type(4))) float;

__device__ __forceinline__ float silu_f(float x) { return x / (1.0f + __expf(-x)); }
__device__ __forceinline__ float b2f(bf16 v) { return __bfloat162float(v); }
__device__ __forceinline__ bf16 f2b(float v) { return __float2bfloat16(v); }

__device__ __forceinline__ unsigned bfbits(float v) {
    union { float f; unsigned u; } a; a.f = v;
    return (a.u + 0x7fffu + ((a.u >> 16) & 1u)) >> 16;
}
__device__ __forceinline__ unsigned pack2(float a, float b) {
    return bfbits(a) | (bfbits(b) << 16);
}
__device__ __forceinline__ void unpack2(unsigned u, float& a, float& b) {
    union { unsigned x; float f; } lo, hi;
    lo.x = u << 16; hi.x = u & 0xffff0000u;
    a = lo.f; b = hi.f;
}
__device__ __forceinline__ float bs2f(short s) {
    union { unsigned u; float f; } x; x.u = ((unsigned)(unsigned short)s) << 16;
    return x.f;
}

// 1/(16*sqrt(8)), 0.5/sqrt(8), 1/sqrt(8)
#define INV_AVGN_SQM 0.02209708691207961f
#define HALF_INV_SQM 0.17677669529663687f
#define INV_SQM      0.35355339059327373f

// ---------------------------------------------------------------------------
// CSR build
// ---------------------------------------------------------------------------
__global__ void kCnt(const int* __restrict__ eidx, int* __restrict__ deg)
{
    const int e = blockIdx.x * 256 + threadIdx.x;
    atomicAdd(&deg[eidx[e]], 1);
}

__global__ void kScan(const int* __restrict__ deg, int* __restrict__ off)
{
    __shared__ int part[256];
    const int t = threadIdx.x;
    int loc[40];
    int s = 0;
#pragma unroll
    for (int i = 0; i < 40; i++) {
        const int idx = t * 40 + i;
        const int v = (idx < NNODES) ? deg[idx] : 0;
        loc[i] = s;
        s += v;
    }
    part[t] = s;
    __syncthreads();
    for (int d = 1; d < 256; d <<= 1) {
        const int v = (t >= d) ? part[t - d] : 0;
        __syncthreads();
        part[t] += v;
        __syncthreads();
    }
    const int base = (t == 0) ? 0 : part[t - 1];
#pragma unroll
    for (int i = 0; i < 40; i++) {
        const int idx = t * 40 + i;
        if (idx < NNODES) off[idx] = base + loc[i];
    }
    if (t == 255) off[NNODES] = part[255];
}

__global__ void kFill(const int* __restrict__ eidx, int* __restrict__ cur,
                      const int* __restrict__ off, int* __restrict__ elist)
{
    const int e = blockIdx.x * 256 + threadIdx.x;
    const int c = eidx[e];
    const int pos = atomicAdd(&cur[c], 1);
    elist[off[c] + pos] = e;
}

// ---------------------------------------------------------------------------
// kPrepA: pre-transpose w1/w2/wm0 -> wAt bf16 [col][128k]
//   cols: 0..127 w1, 128..255 w2, 256..303 wm0
// ---------------------------------------------------------------------------
__global__ void kPrepA(const float* __restrict__ w1, const float* __restrict__ w2,
                       const float* __restrict__ wm0, short* __restrict__ wAt)
{
    const int t = blockIdx.x * 256 + threadIdx.x;
    if (t >= 38912) return;
    const int k = t & 127, c = t >> 7;
    float v;
    if (c < 128)      v = w1[k * 128 + c];
    else if (c < 256) v = w2[k * 128 + (c - 128)];
    else              v = wm0[k * 48 + (c - 256)];
    wAt[c * 128 + k] = (short)bfbits(v);
}

// ---------------------------------------------------------------------------
// kPrepB: pre-transpose K=152(->160 pad) GEMM weights -> Bt bf16 [col][160k]
//   cols: 0..191 l2fo0, 192..383 l2fn0, 384..511 latw,
//         512..575 l2fo1(+64), 576..639 l2fn1(+64), 640..647 finw
// ---------------------------------------------------------------------------
__global__ void kPrepB(const float* __restrict__ l2fo, const float* __restrict__ l2fn,
                       const float* __restrict__ latw, const float* __restrict__ l2fo1,
                       const float* __restrict__ l2fn1, const float* __restrict__ finw,
                       short* __restrict__ Bt)
{
    const int k = blockIdx.y;
    const int col = blockIdx.x * 256 + threadIdx.x;
    if (col >= 648) return;
    float v = 0.f;
    if (k < 152) {
        if (col < 192)       v = l2fo[k * 192 + col];
        else if (col < 384)  v = l2fn[k * 192 + (col - 192)];
        else if (col < 512)  v = latw[k * 128 + (col - 384)];
        else if (col < 576)  v = l2fo1[k * 192 + 64 + (col - 512)];
        else if (col < 640)  v = l2fn1[k * 192 + 64 + (col - 576)];
        else                 v = finw[k * 8 + (col - 640)];
    }
    Bt[(size_t)col * 160 + k] = (short)bfbits(v);
}

// ---------------------------------------------------------------------------
// kEnvG: gather env + fused env-linear (per node,d)
// ---------------------------------------------------------------------------
__global__ void kEnvG(const float* __restrict__ wcur, const float* __restrict__ ea,
                      const int* __restrict__ off, const int* __restrict__ elist,
                      const float* __restrict__ wl, float* __restrict__ envc)
{
    const int t = blockIdx.x * 256 + threadIdx.x;
    if (t >= NNODES * 9) return;
    const int n = t / 9;
    const int d = t - n * 9;
    const int irr = (d == 0) ? 0 : ((d < 4) ? 1 : 2);
    float v[8];
#pragma unroll
    for (int q = 0; q < 8; q++) v[q] = 0.0f;
    const int b = off[n], en = off[n + 1];
    for (int j = b; j < en; j++) {
        const int e = elist[j];
        const float ad = ea[e * 9 + d];
        const float* wr = wcur + (size_t)e * 24 + irr;
#pragma unroll
        for (int q = 0; q < 8; q++) v[q] = fmaf(wr[q * 3], ad, v[q]);
    }
#pragma unroll
    for (int u = 0; u < 8; u++) {
        float s = 0.0f;
#pragma unroll
        for (int q = 0; q < 8; q++) s = fmaf(wl[irr * 64 + u * 8 + q], v[q], s);
        envc[n * 72 + u * 9 + d] = s * INV_AVGN_SQM;
    }
}

// ---------------------------------------------------------------------------
// kA0: inputs gather + cutoff + stage0 (16->128) -> h08 tiled layout; eaT; pad
// ---------------------------------------------------------------------------
__global__ __launch_bounds__(256) void kA0(
    const float* __restrict__ ea, const float* __restrict__ eemb,
    const float* __restrict__ nat, const float* __restrict__ elen,
    const float* __restrict__ w0, const int* __restrict__ eidx,
    short* __restrict__ h08, short* __restrict__ latf8s,
    bf16* __restrict__ eaT, float* __restrict__ cutb)
{
    __shared__ float w0s[16 * 128];
    const int t = threadIdx.x;
    const int e = blockIdx.x * 256 + t;
#pragma unroll
    for (int p = 0; p < 8; p++) { const int idx = p * 256 + t; w0s[idx] = w0[idx]; }
    __syncthreads();

    const int ctr = eidx[e];
    const int ngb = eidx[EE + e];
    float tin[16];
#pragma unroll
    for (int k = 0; k < 4; k++) tin[k] = nat[ctr * 4 + k];
#pragma unroll
    for (int k = 0; k < 4; k++) tin[4 + k] = nat[ngb * 4 + k];
#pragma unroll
    for (int k = 0; k < 8; k++) tin[8 + k] = eemb[e * 8 + k];

    const float x = elen[e];
    const float x2 = x * x, x4 = x2 * x2, x6 = x4 * x2, x7 = x6 * x, x8 = x7 * x;
    float cutv = 1.0f - 28.0f * x6 + 48.0f * x7 - 21.0f * x8;
    cutv = (x < 1.0f) ? cutv : 0.0f;
    cutb[e] = cutv;

    const size_t tb = (size_t)(e >> 5);
    const int el = e & 31;
#pragma unroll
    for (int jc = 0; jc < 4; jc++) {
        float a[32];
#pragma unroll
        for (int j = 0; j < 32; j++) a[j] = 0.0f;
#pragma unroll
        for (int k = 0; k < 16; k++) {
            const float v = tin[k];
#pragma unroll
            for (int j = 0; j < 32; j++) a[j] = fmaf(v, w0s[k * 128 + jc * 32 + j], a[j]);
        }
#pragma unroll
        for (int cc = 0; cc < 4; cc++) {
            bf16x8 hv;
#pragma unroll
            for (int jj = 0; jj < 8; jj++) hv[jj] = (short)bfbits(silu_f(a[cc * 8 + jj]));
            *(bf16x8*)(h08 + tb * 4096 + (jc * 4 + cc) * 256 + el * 8) = hv;
        }
    }
    bf16x8 z;
#pragma unroll
    for (int jj = 0; jj < 8; jj++) z[jj] = 0;
    *(bf16x8*)(latf8s + tb * 5120 + 19 * 256 + el * 8) = z;

#pragma unroll
    for (int d = 0; d < 9; d++) eaT[(size_t)d * EE + e] = f2b(ea[e * 9 + d]);
}

// ---------------------------------------------------------------------------
// kAm: MFMA chain. Frag-major LDS [kc][n][8]; conflict-free; coalesced outputs.
// ---------------------------------------------------------------------------
__global__ __launch_bounds__(256, 2) void kAm(
    const short* __restrict__ h08, const short* __restrict__ wAt,
    const float* __restrict__ cutb, short* __restrict__ latf8s,
    float* __restrict__ winiF, float* __restrict__ wcur0)
{
    __shared__ short Bs[16 * 128 * 8];                       // 32 KB
    __shared__ alignas(16) char a2raw[16384];                // A2 / Cs (16 KB)
    __shared__ short A3[8192];                               // 16 KB
    short* A2 = (short*)a2raw;
    float* Cs = (float*)a2raw;

    const int t = threadIdx.x;
    const int eb = blockIdx.x * 64;
    const int lane = t & 63, wid = t >> 6;
    const int wm = wid >> 1, wn = wid & 1;
    const int l15 = lane & 15, kq = lane >> 4;
    const f32x4 zz = {0.f, 0.f, 0.f, 0.f};

    // stage Bs <- w1t
#pragma unroll
    for (int p = 0; p < 8; p++) {
        const int task = p * 256 + t;
        const int n = task & 127, kc = task >> 7;
        *(bf16x8*)(Bs + kc * 1024 + n * 8) = *(const bf16x8*)(wAt + n * 128 + kc * 8);
    }
    float cutR[2][4];
#pragma unroll
    for (int mi = 0; mi < 2; mi++)
#pragma unroll
        for (int r = 0; r < 4; r++)
            cutR[mi][r] = cutb[eb + wm * 32 + mi * 16 + kq * 4 + r];
    __syncthreads();

    // GEMM1: h1 = silu(h0 @ w1) -> A2
    {
        f32x4 acc[8];
#pragma unroll
        for (int q = 0; q < 8; q++) acc[q] = zz;
        const size_t ab = (size_t)((eb >> 5) + wm) * 4096 + l15 * 8;
#pragma unroll
        for (int ks = 0; ks < 4; ks++) {
            const int kc = ks * 4 + kq;
            const bf16x8 a0 = *(const bf16x8*)(h08 + ab + kc * 256);
            const bf16x8 a1 = *(const bf16x8*)(h08 + ab + kc * 256 + 128);
            const short* bp = Bs + kc * 1024 + (wn * 64 + l15) * 8;
#pragma unroll
            for (int ni = 0; ni < 4; ni++) {
                const bf16x8 b = *(const bf16x8*)(bp + ni * 128);
                acc[ni]     = __builtin_amdgcn_mfma_f32_16x16x32_bf16(a0, b, acc[ni], 0, 0, 0);
                acc[4 + ni] = __builtin_amdgcn_mfma_f32_16x16x32_bf16(a1, b, acc[4 + ni], 0, 0, 0);
            }
        }
#pragma unroll
        for (int mi = 0; mi < 2; mi++)
#pragma unroll
            for (int ni = 0; ni < 4; ni++) {
                const int kcol = wn * 64 + ni * 16 + l15;
                const int eb2 = wm * 32 + mi * 16 + (kq << 2);
#pragma unroll
                for (int r = 0; r < 4; r++)
                    A2[(kcol >> 3) * 512 + (eb2 + r) * 8 + (kcol & 7)] =
                        (short)bfbits(silu_f(acc[mi * 4 + ni][r]));
            }
    }
    __syncthreads();
    // stage Bs <- w2t
#pragma unroll
    for (int p = 0; p < 8; p++) {
        const int task = p * 256 + t;
        const int n = task & 127, kc = task >> 7;
        *(bf16x8*)(Bs + kc * 1024 + n * 8) = *(const bf16x8*)(wAt + 16384 + n * 128 + kc * 8);
    }
    __syncthreads();

    // GEMM2: latents = (h1 @ w2) * cut -> A3
    {
        f32x4 acc[8];
#pragma unroll
        for (int q = 0; q < 8; q++) acc[q] = zz;
#pragma unroll
        for (int ks = 0; ks < 4; ks++) {
            const int kc = ks * 4 + kq;
            const bf16x8 a0 = *(const bf16x8*)(A2 + kc * 512 + (wm * 32 + l15) * 8);
            const bf16x8 a1 = *(const bf16x8*)(A2 + kc * 512 + (wm * 32 + 16 + l15) * 8);
            const short* bp = Bs + kc * 1024 + (wn * 64 + l15) * 8;
#pragma unroll
            for (int ni = 0; ni < 4; ni++) {
                const bf16x8 b = *(const bf16x8*)(bp + ni * 128);
                acc[ni]     = __builtin_amdgcn_mfma_f32_16x16x32_bf16(a0, b, acc[ni], 0, 0, 0);
                acc[4 + ni] = __builtin_amdgcn_mfma_f32_16x16x32_bf16(a1, b, acc[4 + ni], 0, 0, 0);
            }
        }
#pragma unroll
        for (int mi = 0; mi < 2; mi++)
#pragma unroll
            for (int ni = 0; ni < 4; ni++) {
                const int kcol = wn * 64 + ni * 16 + l15;
                const int eb2 = wm * 32 + mi * 16 + (kq << 2);
#pragma unroll
                for (int r = 0; r < 4; r++)
                    A3[(kcol >> 3) * 512 + (eb2 + r) * 8 + (kcol & 7)] =
                        (short)bfbits(acc[mi * 4 + ni][r] * cutR[mi][r]);
            }
    }
    __syncthreads();
    // stage Bs <- wm0t (zero n>=48) ; copy A3 -> latf8 (coalesced)
#pragma unroll
    for (int p = 0; p < 8; p++) {
        const int task = p * 256 + t;
        const int n = task & 127, kc = task >> 7;
        bf16x8 bv;
        if (n < 48) bv = *(const bf16x8*)(wAt + 32768 + n * 128 + kc * 8);
        else {
#pragma unroll
            for (int jj = 0; jj < 8; jj++) bv[jj] = 0;
        }
        *(bf16x8*)(Bs + kc * 1024 + n * 8) = bv;
    }
#pragma unroll
    for (int p = 0; p < 4; p++) {
        const int i = p * 256 + t;
        const int e = i & 63, kc = i >> 6;
        const bf16x8 v = *(const bf16x8*)(A3 + kc * 512 + e * 8);
        const int eg = eb + e;
        *(bf16x8*)(latf8s + (size_t)(eg >> 5) * 5120 + kc * 256 + (eg & 31) * 8) = v;
    }
    __syncthreads();

    // GEMM3: ewv = latents @ wm0 (wn==0 waves) -> Cs [48][65]
    if (wn == 0) {
        f32x4 acc[6];
#pragma unroll
        for (int q = 0; q < 6; q++) acc[q] = zz;
#pragma unroll
        for (int ks = 0; ks < 4; ks++) {
            const int kc = ks * 4 + kq;
            const bf16x8 a0 = *(const bf16x8*)(A3 + kc * 512 + (wm * 32 + l15) * 8);
            const bf16x8 a1 = *(const bf16x8*)(A3 + kc * 512 + (wm * 32 + 16 + l15) * 8);
            const short* bp = Bs + kc * 1024 + l15 * 8;
#pragma unroll
            for (int ni = 0; ni < 3; ni++) {
                const bf16x8 b = *(const bf16x8*)(bp + ni * 128);
                acc[ni]     = __builtin_amdgcn_mfma_f32_16x16x32_bf16(a0, b, acc[ni], 0, 0, 0);
                acc[3 + ni] = __builtin_amdgcn_mfma_f32_16x16x32_bf16(a1, b, acc[3 + ni], 0, 0, 0);
            }
        }
#pragma unroll
        for (int mi = 0; mi < 2; mi++)
#pragma unroll
            for (int ni = 0; ni < 3; ni++) {
                const int c = ni * 16 + l15;
                const int eb2 = wm * 32 + mi * 16 + (kq << 2);
#pragma unroll
                for (int r = 0; r < 4; r++)
                    Cs[c * 65 + eb2 + r] = acc[mi * 3 + ni][r];
            }
    }
    __syncthreads();
    // coalesced outputs
    for (int i = t; i < 1536; i += 256) {
        const int c = i >> 6, e = i & 63;
        winiF[(size_t)c * EE + eb + e] = Cs[c * 65 + e];
    }
    for (int i = t; i < 1536; i += 256) {
        const int e2 = i / 24, c2 = i - e2 * 24;
        wcur0[(size_t)(eb + e2) * 24 + c2] = Cs[(24 + c2) * 65 + e2];
    }
}

// ---------------------------------------------------------------------------
// kGemm: C = latf8[e0..][160] @ Bt[colOff..], out bf16 Wg [col][chE]
// frag-major B LDS; C staged through LDS for coalesced writes
// ---------------------------------------------------------------------------
__global__ __launch_bounds__(256, 3) void kGemm(
    const short* __restrict__ A8, int e0, int chE,
    const short* __restrict__ Bt, int colOff, int Nval,
    unsigned* __restrict__ Wg)
{
    __shared__ alignas(16) char smraw[40960];
    short* Bs = (short*)smraw;
    float* Cs = (float*)smraw;
    const int t = threadIdx.x;
    const int colbase = blockIdx.y * 128;
#pragma unroll
    for (int p = 0; p < 10; p++) {
        const int task = p * 256 + t;
        const int n = task & 127, kc = task >> 7;
        const int ng = colbase + n;
        bf16x8 bv;
        if (ng < Nval) bv = *(const bf16x8*)(Bt + (size_t)(colOff + ng) * 160 + kc * 8);
        else {
#pragma unroll
            for (int jj = 0; jj < 8; jj++) bv[jj] = 0;
        }
        *(bf16x8*)(Bs + kc * 1024 + n * 8) = bv;
    }
    __syncthreads();

    const int lane = t & 63, wid = t >> 6;
    const int wm = wid >> 1, wn = wid & 1;
    const int l15 = lane & 15, kq = lane >> 4;
    const f32x4 zz = {0.f, 0.f, 0.f, 0.f};
    f32x4 acc[8];
#pragma unroll
    for (int q = 0; q < 8; q++) acc[q] = zz;
    const size_t ab = (size_t)(((e0 + blockIdx.x * 64) >> 5) + wm) * 5120 + l15 * 8;
#pragma unroll
    for (int ks = 0; ks < 5; ks++) {
        const int kc = ks * 4 + kq;
        const bf16x8 a0 = *(const bf16x8*)(A8 + ab + kc * 256);
        const bf16x8 a1 = *(const bf16x8*)(A8 + ab + kc * 256 + 128);
        const short* bp = Bs + kc * 1024 + (wn * 64 + l15) * 8;
#pragma unroll
        for (int ni = 0; ni < 4; ni++) {
            const bf16x8 b = *(const bf16x8*)(bp + ni * 128);
            acc[ni]     = __builtin_amdgcn_mfma_f32_16x16x32_bf16(a0, b, acc[ni], 0, 0, 0);
            acc[4 + ni] = __builtin_amdgcn_mfma_f32_16x16x32_bf16(a1, b, acc[4 + ni], 0, 0, 0);
        }
    }
    __syncthreads();
#pragma unroll
    for (int mi = 0; mi < 2; mi++)
#pragma unroll
        for (int ni = 0; ni < 4; ni++) {
            const int cl = wn * 64 + ni * 16 + l15;
            const int el = wm * 32 + mi * 16 + (kq << 2);
            const f32x4 v = acc[mi * 4 + ni];
#pragma unroll
            for (int r = 0; r < 4; r++) Cs[cl * 67 + el + r] = v[r];
        }
    __syncthreads();
    int nvc = Nval - colbase; if (nvc > 128) nvc = 128;
    const size_t ebase = (size_t)blockIdx.x * 64;
    for (int i = t; i < nvc * 32; i += 256) {
        const int col = i >> 5, j = i & 31;
        Wg[(((size_t)(colbase + col) * chE + ebase) >> 1) + j] =
            pack2(Cs[col * 67 + 2 * j], Cs[col * 67 + 2 * j + 1]);
    }
}

// ---------------------------------------------------------------------------
// kC1: layer-0 interact + invariants
// ---------------------------------------------------------------------------
__global__ __launch_bounds__(256, 1) void kC1(
    const float* __restrict__ winiF, const bf16* __restrict__ eaT,
    const float* __restrict__ envc, const int* __restrict__ eidx,
    unsigned* __restrict__ newfT, short* __restrict__ latf8s)
{
    const int e = blockIdx.x * 256 + threadIdx.x;
    const int ctr = eidx[e];
    float eav[9];
#pragma unroll
    for (int d = 0; d < 9; d++) eav[d] = b2f(eaT[(size_t)d * EE + e]);
    const float* ec = envc + ctr * 72;
    float inv[24];
#pragma unroll
    for (int uh = 0; uh < 4; uh++) {
        const int u0 = 2 * uh;
        float wi0[3], wi1[3];
#pragma unroll
        for (int i = 0; i < 3; i++) {
            wi0[i] = winiF[(size_t)(u0 * 3 + i) * EE + e];
            wi1[i] = winiF[(size_t)((u0 + 1) * 3 + i) * EE + e];
        }
        float nf0[9], nf1[9];
        const float ec00 = ec[u0 * 9 + 0];
        const float ec10 = ec[(u0 + 1) * 9 + 0];
        const float f00 = wi0[0] * eav[0];
        const float f10 = wi1[0] * eav[0];
#pragma unroll
        for (int d = 0; d < 9; d++) {
            const int irr = (d == 0) ? 0 : ((d < 4) ? 1 : 2);
            const float fa = wi0[irr] * eav[d];
            const float fb = wi1[irr] * eav[d];
            nf0[d] = fa * ec00 + ec[u0 * 9 + d] * f00;
            nf1[d] = fb * ec10 + ec[(u0 + 1) * 9 + d] * f10;
        }
#pragma unroll
        for (int d = 0; d < 9; d++) newfT[(size_t)(d * 4 + uh) * EE + e] = pack2(nf0[d], nf1[d]);
        inv[uh * 6 + 0] = sqrtf(nf0[0] * nf0[0] + 1e-8f);
        inv[uh * 6 + 1] = sqrtf(nf0[1]*nf0[1] + nf0[2]*nf0[2] + nf0[3]*nf0[3] + 1e-8f);
        inv[uh * 6 + 2] = sqrtf(nf0[4]*nf0[4] + nf0[5]*nf0[5] + nf0[6]*nf0[6] + nf0[7]*nf0[7] + nf0[8]*nf0[8] + 1e-8f);
        inv[uh * 6 + 3] = sqrtf(nf1[0] * nf1[0] + 1e-8f);
        inv[uh * 6 + 4] = sqrtf(nf1[1]*nf1[1] + nf1[2]*nf1[2] + nf1[3]*nf1[3] + 1e-8f);
        inv[uh * 6 + 5] = sqrtf(nf1[4]*nf1[4] + nf1[5]*nf1[5] + nf1[6]*nf1[6] + nf1[7]*nf1[7] + nf1[8]*nf1[8] + 1e-8f);
    }
    const size_t tb = (size_t)(e >> 5);
    const int el = e & 31;
#pragma unroll
    for (int j = 0; j < 3; j++) {
        bf16x8 iv;
#pragma unroll
        for (int jj = 0; jj < 8; jj++) iv[jj] = (short)bfbits(inv[j * 8 + jj]);
        *(bf16x8*)(latf8s + tb * 5120 + (16 + j) * 256 + el * 8) = iv;
    }
}

// ---------------------------------------------------------------------------
// kC2b: epilogue layer-0 pe_linear
// ---------------------------------------------------------------------------
__global__ __launch_bounds__(256, 1) void kC2b(
    const short* __restrict__ Wg, int chE, int e0,
    const float* __restrict__ winiF, const bf16* __restrict__ eaT,
    const unsigned* __restrict__ newfT, unsigned* __restrict__ feat1T)
{
    const int eL = blockIdx.x * 256 + threadIdx.x;
    if (eL >= chE) return;
    const int e = e0 + eL;
    const int ir = blockIdx.y >> 1;
    const int uh2 = blockIdx.y & 1;
    const int d0 = (ir == 0) ? 0 : ((ir == 1) ? 1 : 4);
    const int nd = (ir == 0) ? 1 : ((ir == 1) ? 3 : 5);
    float accO[32], accN[32];
#pragma unroll
    for (int q = 0; q < 32; q++) {
        accO[q] = bs2f(Wg[(size_t)(ir * 64 + uh2 * 32 + q) * chE + eL]);
        accN[q] = bs2f(Wg[(size_t)(192 + ir * 64 + uh2 * 32 + q) * chE + eL]);
    }
    float wv[8];
#pragma unroll
    for (int v = 0; v < 8; v++) wv[v] = winiF[(size_t)(v * 3 + ir) * EE + e];
    for (int dd = 0; dd < nd; dd++) {
        const int d = d0 + dd;
        const float ead = b2f(eaT[(size_t)d * EE + e]);
        float nfv[8];
#pragma unroll
        for (int q = 0; q < 4; q++) unpack2(newfT[(size_t)(d * 4 + q) * EE + e], nfv[2 * q], nfv[2 * q + 1]);
        float s[4];
#pragma unroll
        for (int up = 0; up < 4; up++) {
            float tt = 0.0f;
#pragma unroll
            for (int v = 0; v < 8; v++)
                tt += accO[up * 8 + v] * (wv[v] * ead) + accN[up * 8 + v] * nfv[v];
            s[up] = tt * HALF_INV_SQM;
        }
        feat1T[(size_t)(d * 4 + uh2 * 2 + 0) * EE + e] = pack2(s[0], s[1]);
        feat1T[(size_t)(d * 4 + uh2 * 2 + 1) * EE + e] = pack2(s[2], s[3]);
    }
}

// ---------------------------------------------------------------------------
// kC3b: latent resnet + env-MLP1 -> wcur1; updates latf8
// ---------------------------------------------------------------------------
__global__ __launch_bounds__(256, 1) void kC3b(
    short* __restrict__ latf8s, const short* __restrict__ Wg3,
    const float* __restrict__ wm1, const float* __restrict__ cutb,
    float* __restrict__ wcur1)
{
    __shared__ float wm1s[128 * 24];
    const int t = threadIdx.x;
    const int e = blockIdx.x * 256 + t;
#pragma unroll
    for (int p = 0; p < 12; p++) { const int idx = p * 256 + t; wm1s[idx] = wm1[idx]; }
    __syncthreads();
    const float cutv = cutb[e];
    float wc[24];
#pragma unroll
    for (int c = 0; c < 24; c++) wc[c] = 0.0f;
    const size_t tb = (size_t)(e >> 5);
    const int el = e & 31;
#pragma unroll
    for (int c = 0; c < 16; c++) {
        short* ap = latf8s + tb * 5120 + c * 256 + el * 8;
        const bf16x8 ov = *(const bf16x8*)ap;
        bf16x8 nv;
#pragma unroll
        for (int jj = 0; jj < 8; jj++) {
            const int j = c * 8 + jj;
            const float g = bs2f(Wg3[(size_t)j * EE + e]);
            const float o = bs2f(ov[jj]);
            const float l1 = 0.5f * o + 0.5f * silu_f(g) * cutv;
            nv[jj] = (short)bfbits(l1);
#pragma unroll
            for (int cc = 0; cc < 24; cc++) wc[cc] = fmaf(l1, wm1s[j * 24 + cc], wc[cc]);
        }
        *(bf16x8*)ap = nv;
    }
#pragma unroll
    for (int cc = 0; cc < 24; cc++) wcur1[(size_t)e * 24 + cc] = wc[cc];
}

// ---------------------------------------------------------------------------
// kE1: layer-1 interact + invariants
// ---------------------------------------------------------------------------
__global__ __launch_bounds__(256, 1) void kE1(
    const unsigned* __restrict__ feat1T, const float* __restrict__ envc,
    const int* __restrict__ eidx, unsigned* __restrict__ newfT,
    short* __restrict__ latf8s)
{
    const int e = blockIdx.x * 256 + threadIdx.x;
    const int ctr = eidx[e];
    const float* ec = envc + ctr * 72;
    float inv[24];
#pragma unroll
    for (int uh = 0; uh < 4; uh++) {
        const int u0 = 2 * uh;
        float f0[9], f1[9];
#pragma unroll
        for (int d = 0; d < 9; d++) unpack2(feat1T[(size_t)(d * 4 + uh) * EE + e], f0[d], f1[d]);
        const float ec00 = ec[u0 * 9 + 0];
        const float ec10 = ec[(u0 + 1) * 9 + 0];
        float nf0[9], nf1[9];
#pragma unroll
        for (int d = 0; d < 9; d++) {
            nf0[d] = f0[d] * ec00 + ec[u0 * 9 + d] * f0[0];
            nf1[d] = f1[d] * ec10 + ec[(u0 + 1) * 9 + d] * f1[0];
        }
#pragma unroll
        for (int d = 0; d < 9; d++) newfT[(size_t)(d * 4 + uh) * EE + e] = pack2(nf0[d], nf1[d]);
        inv[uh * 6 + 0] = sqrtf(nf0[0] * nf0[0] + 1e-8f);
        inv[uh * 6 + 1] = sqrtf(nf0[1]*nf0[1] + nf0[2]*nf0[2] + nf0[3]*nf0[3] + 1e-8f);
        inv[uh * 6 + 2] = sqrtf(nf0[4]*nf0[4] + nf0[5]*nf0[5] + nf0[6]*nf0[6] + nf0[7]*nf0[7] + nf0[8]*nf0[8] + 1e-8f);
        inv[uh * 6 + 3] = sqrtf(nf1[0] * nf1[0] + 1e-8f);
        inv[uh * 6 + 4] = sqrtf(nf1[1]*nf1[1] + nf1[2]*nf1[2] + nf1[3]*nf1[3] + 1e-8f);
        inv[uh * 6 + 5] = sqrtf(nf1[4]*nf1[4] + nf1[5]*nf1[5] + nf1[6]*nf1[6] + nf1[7]*nf1[7] + nf1[8]*nf1[8] + 1e-8f);
    }
    const size_t tb = (size_t)(e >> 5);
    const int el = e & 31;
#pragma unroll
    for (int j = 0; j < 3; j++) {
        bf16x8 iv;
#pragma unroll
        for (int jj = 0; jj < 8; jj++) iv[jj] = (short)bfbits(inv[j * 8 + jj]);
        *(bf16x8*)(latf8s + tb * 5120 + (16 + j) * 256 + el * 8) = iv;
    }
}

// ---------------------------------------------------------------------------
// kE2b: final epilogue, partials to pout
// ---------------------------------------------------------------------------
__global__ __launch_bounds__(256, 1) void kE2b(
    const short* __restrict__ WgE, int chE, int e0,
    const unsigned* __restrict__ feat1T, const unsigned* __restrict__ newfT,
    float* __restrict__ pout)
{
    const int eL = blockIdx.x * 256 + threadIdx.x;
    if (eL >= chE) return;
    const int e = e0 + eL;
    const int uh2 = blockIdx.y;
    float accO[32], accN[32], wf[4];
#pragma unroll
    for (int q = 0; q < 32; q++) {
        accO[q] = bs2f(WgE[(size_t)(uh2 * 32 + q) * chE + eL]);
        accN[q] = bs2f(WgE[(size_t)(64 + uh2 * 32 + q) * chE + eL]);
    }
#pragma unroll
    for (int m = 0; m < 4; m++) wf[m] = bs2f(WgE[(size_t)(128 + uh2 * 4 + m) * chE + eL]);
#pragma unroll
    for (int dd = 0; dd < 3; dd++) {
        const int d = 1 + dd;
        float f1v[8], nfv[8];
#pragma unroll
        for (int q = 0; q < 4; q++) {
            unpack2(feat1T[(size_t)(d * 4 + q) * EE + e], f1v[2 * q], f1v[2 * q + 1]);
            unpack2(newfT[(size_t)(d * 4 + q) * EE + e], nfv[2 * q], nfv[2 * q + 1]);
        }
        float od = 0.0f;
#pragma unroll
        for (int up = 0; up < 4; up++) {
            float s = 0.0f;
#pragma unroll
            for (int v = 0; v < 8; v++)
                s += accO[up * 8 + v] * f1v[v] + accN[up * 8 + v] * nfv[v];
            od = fmaf(wf[up], s, od);
        }
        pout[((size_t)uh2 * EE + e) * 3 + dd] = od * (HALF_INV_SQM * INV_SQM);
    }
}

__global__ void kOut(const float* __restrict__ pout, float* __restrict__ outp)
{
    const int t = blockIdx.x * 256 + threadIdx.x;
    if (t >= EE * 3) return;
    outp[t] = pout[t] + pout[(size_t)EE * 3 + t];
}

// ---------------------------------------------------------------------------
extern "C" void kernel_launch(void* const* d_in, const int* in_sizes, int n_in,
                              void* d_out, int out_size, void* d_ws, size_t ws_size,
                              hipStream_t stream)
{
    const float* ea   = (const float*)d_in[0];
    const float* eemb = (const float*)d_in[1];
    const float* nat  = (const float*)d_in[2];
    const float* elen = (const float*)d_in[3];
    const float* w0   = (const float*)d_in[4];
    const float* w1   = (const float*)d_in[5];
    const float* w2   = (const float*)d_in[6];
    const float* wm0  = (const float*)d_in[7];
    const float* wm1  = (const float*)d_in[8];
    const float* envl = (const float*)d_in[9];
    const float* latw = (const float*)d_in[10];
    const float* l2fn = (const float*)d_in[11];
    const float* l2fo = (const float*)d_in[12];
    const float* finw = (const float*)d_in[13];
    const int*   eidx = (const int*)d_in[14];

    char* ws = (char*)d_ws;
    short*    latf8s = (short*)(ws + 0);               // [E/32][20][32][8] bf16
    short*    h08    = (short*)(ws + 51200000);        // [E/32][16][32][8] bf16
    short*    WgS    = (short*)(ws + 51200000);        // aliased Wg chunks
    unsigned* WgU    = (unsigned*)(ws + 51200000);
    unsigned* newfT  = (unsigned*)(ws + 92160000);     // [36][EE] u32; aliased wcur0/1
    unsigned* feat1T = (unsigned*)(ws + 115200000);    // [36][EE] u32
    float*    winiF  = (float*)(ws + 138240000);       // [24][EE] f32; aliased pout
    bf16*     eaT    = (bf16*)(ws + 153600000);        // [9][EE]
    float*    cutb   = (float*)(ws + 156480000);       // [E]
    float*    env0   = (float*)(ws + 157120000);       // [N*72]
    float*    env1   = (float*)(ws + 160000000);       // [N*72]
    int*      deg    = (int*)(ws + 162880000);         // [N] (reused as wAt)
    int*      cur    = (int*)(ws + 162920000);
    int*      off    = (int*)(ws + 162960000);
    int*      elist  = (int*)(ws + 163000192);
    short*    wAt    = (short*)(ws + 162880000);       // [304][128] bf16 (77824 B)
    short*    Bt     = (short*)(ws + 163640192);       // [648][160] bf16 (207360 B)

    float* wcur0 = (float*)newfT;
    float* wcur1 = (float*)newfT;
    float* pout  = (float*)winiF;

    hipMemsetAsync(deg, 0, 80000, stream);

    kCnt <<<625, 256, 0, stream>>>(eidx, deg);
    kScan<<<1, 256, 0, stream>>>(deg, off);
    kFill<<<625, 256, 0, stream>>>(eidx, cur, off, elist);
    kPrepA<<<152, 256, 0, stream>>>(w1, w2, wm0, wAt);   // overwrites deg/cur (dead)
    kPrepB<<<dim3(3, 160), 256, 0, stream>>>(l2fo, l2fn, latw,
                                             l2fo + 29184, l2fn + 29184, finw, Bt);

    kA0<<<625, 256, 0, stream>>>(ea, eemb, nat, elen, w0, eidx, h08, latf8s, eaT, cutb);
    kAm<<<2500, 256, 0, stream>>>(h08, wAt, cutb, latf8s, winiF, wcur0);
    kEnvG<<<352, 256, 0, stream>>>(wcur0, ea, off, elist, envl + 0, env0);
    kC1<<<625, 256, 0, stream>>>(winiF, eaT, env0, eidx, newfT, latf8s);

    for (int c = 0; c < 4; c++) {
        const int e0 = c * 40000;
        kGemm<<<dim3(625, 3), 256, 0, stream>>>(latf8s, e0, 40000, Bt, 0, 384, WgU);
        kC2b<<<dim3(157, 6), 256, 0, stream>>>(WgS, 40000, e0, winiF, eaT, newfT, feat1T);
    }

    kGemm<<<dim3(2500, 1), 256, 0, stream>>>(latf8s, 0, EE, Bt, 384, 128, WgU);
    kC3b<<<625, 256, 0, stream>>>(latf8s, WgS, wm1, cutb, wcur1);
    kEnvG<<<352, 256, 0, stream>>>(wcur1, ea, off, elist, envl + 192, env1);
    kE1<<<625, 256, 0, stream>>>(feat1T, env1, eidx, newfT, latf8s);

    for (int c = 0; c < 2; c++) {
        const int e0 = c * 80000;
        kGemm<<<dim3(1250, 2), 256, 0, stream>>>(latf8s, e0, 80000, Bt, 512, 136, WgU);
        kE2b<<<dim3(313, 2), 256, 0, stream>>>(WgS, 80000, e0, feat1T, newfT, pout);
    }
    kOut<<<1875, 256, 0, stream>>>(pout, (float*)d_out);
}

// Round 7
// 452.046 us; speedup vs baseline: 6.5228x; 1.0477x over previous
//
#include <hip/hip_runtime.h>
#include <hip/hip_bf16.h>

#define EE 160000
#define NNODES 10000

using bf16 = __hip_bfloat16;
using bf16x8 = __attribute__((ext_vector_type(8))) short;
using short4v = __attribute__((ext_vector_type(4))) short;
using f32x4  = __attribute__((ext_vector_type(4))) float;

__device__ __forceinline__ float silu_f(float x) { return x / (1.0f + __expf(-x)); }
__device__ __forceinline__ float b2f(bf16 v) { return __bfloat162float(v); }
__device__ __forceinline__ bf16 f2b(float v) { return __float2bfloat16(v); }

__device__ __forceinline__ unsigned bfbits(float v) {
    union { float f; unsigned u; } a; a.f = v;
    return (a.u + 0x7fffu + ((a.u >> 16) & 1u)) >> 16;
}
__device__ __forceinline__ unsigned pack2(float a, float b) {
    return bfbits(a) | (bfbits(b) << 16);
}
__device__ __forceinline__ void unpack2(unsigned u, float& a, float& b) {
    union { unsigned x; float f; } lo, hi;
    lo.x = u << 16; hi.x = u & 0xffff0000u;
    a = lo.f; b = hi.f;
}
__device__ __forceinline__ float bs2f(short s) {
    union { unsigned u; float f; } x; x.u = ((unsigned)(unsigned short)s) << 16;
    return x.f;
}

// 1/(16*sqrt(8)), 0.5/sqrt(8), 1/sqrt(8)
#define INV_AVGN_SQM 0.02209708691207961f
#define HALF_INV_SQM 0.17677669529663687f
#define INV_SQM      0.35355339059327373f

// ---------------------------------------------------------------------------
// CSR build
// ---------------------------------------------------------------------------
__global__ void kCnt(const int* __restrict__ eidx, int* __restrict__ deg)
{
    const int e = blockIdx.x * 256 + threadIdx.x;
    atomicAdd(&deg[eidx[e]], 1);
}

__global__ void kScan(const int* __restrict__ deg, int* __restrict__ off)
{
    __shared__ int part[256];
    const int t = threadIdx.x;
    int loc[40];
    int s = 0;
#pragma unroll
    for (int i = 0; i < 40; i++) {
        const int idx = t * 40 + i;
        const int v = (idx < NNODES) ? deg[idx] : 0;
        loc[i] = s;
        s += v;
    }
    part[t] = s;
    __syncthreads();
    for (int d = 1; d < 256; d <<= 1) {
        const int v = (t >= d) ? part[t - d] : 0;
        __syncthreads();
        part[t] += v;
        __syncthreads();
    }
    const int base = (t == 0) ? 0 : part[t - 1];
#pragma unroll
    for (int i = 0; i < 40; i++) {
        const int idx = t * 40 + i;
        if (idx < NNODES) off[idx] = base + loc[i];
    }
    if (t == 255) off[NNODES] = part[255];
}

__global__ void kFill(const int* __restrict__ eidx, int* __restrict__ cur,
                      const int* __restrict__ off, int* __restrict__ elist)
{
    const int e = blockIdx.x * 256 + threadIdx.x;
    const int c = eidx[e];
    const int pos = atomicAdd(&cur[c], 1);
    elist[off[c] + pos] = e;
}

// ---------------------------------------------------------------------------
// kPrepA: pre-transpose w1/w2/wm0 -> wAt bf16 [col][128k]
// ---------------------------------------------------------------------------
__global__ void kPrepA(const float* __restrict__ w1, const float* __restrict__ w2,
                       const float* __restrict__ wm0, short* __restrict__ wAt)
{
    const int t = blockIdx.x * 256 + threadIdx.x;
    if (t >= 38912) return;
    const int k = t & 127, c = t >> 7;
    float v;
    if (c < 128)      v = w1[k * 128 + c];
    else if (c < 256) v = w2[k * 128 + (c - 128)];
    else              v = wm0[k * 48 + (c - 256)];
    wAt[c * 128 + k] = (short)bfbits(v);
}

// ---------------------------------------------------------------------------
// kPrepB: pre-transpose K=152(->160 pad) weights -> Bt bf16 [col][160k]
//  cols 0..383:  layer-0, per-irrep: cn = ir*128 + half*64 + (u*8+v)
//                half 0 = l2fo (old), half 1 = l2fn (new)
//  cols 384..511: latw
//  cols 512..575: l2fo1(+64) ; 576..639: l2fn1(+64) ; 640..647: finw
// ---------------------------------------------------------------------------
__global__ void kPrepB(const float* __restrict__ l2fo, const float* __restrict__ l2fn,
                       const float* __restrict__ latw, const float* __restrict__ l2fo1,
                       const float* __restrict__ l2fn1, const float* __restrict__ finw,
                       short* __restrict__ Bt)
{
    const int k = blockIdx.y;
    const int col = blockIdx.x * 256 + threadIdx.x;
    if (col >= 648) return;
    float v = 0.f;
    if (k < 152) {
        if (col < 384) {
            const int ir = col >> 7, half = (col >> 6) & 1, q = col & 63;
            const float* src = half ? l2fn : l2fo;
            v = src[k * 192 + ir * 64 + q];
        } else if (col < 512)  v = latw[k * 128 + (col - 384)];
        else if (col < 576)    v = l2fo1[k * 192 + 64 + (col - 512)];
        else if (col < 640)    v = l2fn1[k * 192 + 64 + (col - 576)];
        else                   v = finw[k * 8 + (col - 640)];
    }
    Bt[(size_t)col * 160 + k] = (short)bfbits(v);
}

// ---------------------------------------------------------------------------
// kEnvG: gather env + fused env-linear (per node,d)
// ---------------------------------------------------------------------------
__global__ void kEnvG(const float* __restrict__ wcur, const float* __restrict__ ea,
                      const int* __restrict__ off, const int* __restrict__ elist,
                      const float* __restrict__ wl, float* __restrict__ envc)
{
    const int t = blockIdx.x * 256 + threadIdx.x;
    if (t >= NNODES * 9) return;
    const int n = t / 9;
    const int d = t - n * 9;
    const int irr = (d == 0) ? 0 : ((d < 4) ? 1 : 2);
    float v[8];
#pragma unroll
    for (int q = 0; q < 8; q++) v[q] = 0.0f;
    const int b = off[n], en = off[n + 1];
    for (int j = b; j < en; j++) {
        const int e = elist[j];
        const float ad = ea[e * 9 + d];
        const float* wr = wcur + (size_t)e * 24 + irr;
#pragma unroll
        for (int q = 0; q < 8; q++) v[q] = fmaf(wr[q * 3], ad, v[q]);
    }
#pragma unroll
    for (int u = 0; u < 8; u++) {
        float s = 0.0f;
#pragma unroll
        for (int q = 0; q < 8; q++) s = fmaf(wl[irr * 64 + u * 8 + q], v[q], s);
        envc[n * 72 + u * 9 + d] = s * INV_AVGN_SQM;
    }
}

// ---------------------------------------------------------------------------
// kA0: inputs gather + cutoff + stage0 (16->128) -> h08; eaT; pad chunk
// ---------------------------------------------------------------------------
__global__ __launch_bounds__(256) void kA0(
    const float* __restrict__ ea, const float* __restrict__ eemb,
    const float* __restrict__ nat, const float* __restrict__ elen,
    const float* __restrict__ w0, const int* __restrict__ eidx,
    short* __restrict__ h08, short* __restrict__ latf8s,
    bf16* __restrict__ eaT, float* __restrict__ cutb)
{
    __shared__ float w0s[16 * 128];
    const int t = threadIdx.x;
    const int e = blockIdx.x * 256 + t;
#pragma unroll
    for (int p = 0; p < 8; p++) { const int idx = p * 256 + t; w0s[idx] = w0[idx]; }
    __syncthreads();

    const int ctr = eidx[e];
    const int ngb = eidx[EE + e];
    float tin[16];
#pragma unroll
    for (int k = 0; k < 4; k++) tin[k] = nat[ctr * 4 + k];
#pragma unroll
    for (int k = 0; k < 4; k++) tin[4 + k] = nat[ngb * 4 + k];
#pragma unroll
    for (int k = 0; k < 8; k++) tin[8 + k] = eemb[e * 8 + k];

    const float x = elen[e];
    const float x2 = x * x, x4 = x2 * x2, x6 = x4 * x2, x7 = x6 * x, x8 = x7 * x;
    float cutv = 1.0f - 28.0f * x6 + 48.0f * x7 - 21.0f * x8;
    cutv = (x < 1.0f) ? cutv : 0.0f;
    cutb[e] = cutv;

    const size_t tb = (size_t)(e >> 5);
    const int el = e & 31;
#pragma unroll
    for (int jc = 0; jc < 4; jc++) {
        float a[32];
#pragma unroll
        for (int j = 0; j < 32; j++) a[j] = 0.0f;
#pragma unroll
        for (int k = 0; k < 16; k++) {
            const float v = tin[k];
#pragma unroll
            for (int j = 0; j < 32; j++) a[j] = fmaf(v, w0s[k * 128 + jc * 32 + j], a[j]);
        }
#pragma unroll
        for (int cc = 0; cc < 4; cc++) {
            bf16x8 hv;
#pragma unroll
            for (int jj = 0; jj < 8; jj++) hv[jj] = (short)bfbits(silu_f(a[cc * 8 + jj]));
            *(bf16x8*)(h08 + tb * 4096 + (jc * 4 + cc) * 256 + el * 8) = hv;
        }
    }
    bf16x8 z;
#pragma unroll
    for (int jj = 0; jj < 8; jj++) z[jj] = 0;
    *(bf16x8*)(latf8s + tb * 5120 + 19 * 256 + el * 8) = z;

#pragma unroll
    for (int d = 0; d < 9; d++) eaT[(size_t)d * EE + e] = f2b(ea[e * 9 + d]);
}

// ---------------------------------------------------------------------------
// kAm: MFMA chain h0@w1 -> silu -> @w2 -> *cut ; latents@wm0 -> wini/wcur0
// ---------------------------------------------------------------------------
__global__ __launch_bounds__(256, 2) void kAm(
    const short* __restrict__ h08, const short* __restrict__ wAt,
    const float* __restrict__ cutb, short* __restrict__ latf8s,
    float* __restrict__ winiF, float* __restrict__ wcur0)
{
    __shared__ short Bs[16 * 128 * 8];                       // 32 KB
    __shared__ alignas(16) char a2raw[16384];                // A2 / Cs (16 KB)
    __shared__ short A3[8192];                               // 16 KB
    short* A2 = (short*)a2raw;
    float* Cs = (float*)a2raw;

    const int t = threadIdx.x;
    const int eb = blockIdx.x * 64;
    const int lane = t & 63, wid = t >> 6;
    const int wm = wid >> 1, wn = wid & 1;
    const int l15 = lane & 15, kq = lane >> 4;
    const f32x4 zz = {0.f, 0.f, 0.f, 0.f};

#pragma unroll
    for (int p = 0; p < 8; p++) {
        const int task = p * 256 + t;
        const int n = task & 127, kc = task >> 7;
        *(bf16x8*)(Bs + kc * 1024 + n * 8) = *(const bf16x8*)(wAt + n * 128 + kc * 8);
    }
    float cutR[2][4];
#pragma unroll
    for (int mi = 0; mi < 2; mi++)
#pragma unroll
        for (int r = 0; r < 4; r++)
            cutR[mi][r] = cutb[eb + wm * 32 + mi * 16 + kq * 4 + r];
    __syncthreads();

    // GEMM1: h1 = silu(h0 @ w1) -> A2
    {
        f32x4 acc[8];
#pragma unroll
        for (int q = 0; q < 8; q++) acc[q] = zz;
        const size_t ab = (size_t)((eb >> 5) + wm) * 4096 + l15 * 8;
#pragma unroll
        for (int ks = 0; ks < 4; ks++) {
            const int kc = ks * 4 + kq;
            const bf16x8 a0 = *(const bf16x8*)(h08 + ab + kc * 256);
            const bf16x8 a1 = *(const bf16x8*)(h08 + ab + kc * 256 + 128);
            const short* bp = Bs + kc * 1024 + (wn * 64 + l15) * 8;
#pragma unroll
            for (int ni = 0; ni < 4; ni++) {
                const bf16x8 b = *(const bf16x8*)(bp + ni * 128);
                acc[ni]     = __builtin_amdgcn_mfma_f32_16x16x32_bf16(a0, b, acc[ni], 0, 0, 0);
                acc[4 + ni] = __builtin_amdgcn_mfma_f32_16x16x32_bf16(a1, b, acc[4 + ni], 0, 0, 0);
            }
        }
#pragma unroll
        for (int mi = 0; mi < 2; mi++)
#pragma unroll
            for (int ni = 0; ni < 4; ni++) {
                const int kcol = wn * 64 + ni * 16 + l15;
                const int eb2 = wm * 32 + mi * 16 + (kq << 2);
#pragma unroll
                for (int r = 0; r < 4; r++)
                    A2[(kcol >> 3) * 512 + (eb2 + r) * 8 + (kcol & 7)] =
                        (short)bfbits(silu_f(acc[mi * 4 + ni][r]));
            }
    }
    __syncthreads();
#pragma unroll
    for (int p = 0; p < 8; p++) {
        const int task = p * 256 + t;
        const int n = task & 127, kc = task >> 7;
        *(bf16x8*)(Bs + kc * 1024 + n * 8) = *(const bf16x8*)(wAt + 16384 + n * 128 + kc * 8);
    }
    __syncthreads();

    // GEMM2: latents = (h1 @ w2) * cut -> A3
    {
        f32x4 acc[8];
#pragma unroll
        for (int q = 0; q < 8; q++) acc[q] = zz;
#pragma unroll
        for (int ks = 0; ks < 4; ks++) {
            const int kc = ks * 4 + kq;
            const bf16x8 a0 = *(const bf16x8*)(A2 + kc * 512 + (wm * 32 + l15) * 8);
            const bf16x8 a1 = *(const bf16x8*)(A2 + kc * 512 + (wm * 32 + 16 + l15) * 8);
            const short* bp = Bs + kc * 1024 + (wn * 64 + l15) * 8;
#pragma unroll
            for (int ni = 0; ni < 4; ni++) {
                const bf16x8 b = *(const bf16x8*)(bp + ni * 128);
                acc[ni]     = __builtin_amdgcn_mfma_f32_16x16x32_bf16(a0, b, acc[ni], 0, 0, 0);
                acc[4 + ni] = __builtin_amdgcn_mfma_f32_16x16x32_bf16(a1, b, acc[4 + ni], 0, 0, 0);
            }
        }
#pragma unroll
        for (int mi = 0; mi < 2; mi++)
#pragma unroll
            for (int ni = 0; ni < 4; ni++) {
                const int kcol = wn * 64 + ni * 16 + l15;
                const int eb2 = wm * 32 + mi * 16 + (kq << 2);
#pragma unroll
                for (int r = 0; r < 4; r++)
                    A3[(kcol >> 3) * 512 + (eb2 + r) * 8 + (kcol & 7)] =
                        (short)bfbits(acc[mi * 4 + ni][r] * cutR[mi][r]);
            }
    }
    __syncthreads();
#pragma unroll
    for (int p = 0; p < 8; p++) {
        const int task = p * 256 + t;
        const int n = task & 127, kc = task >> 7;
        bf16x8 bv;
        if (n < 48) bv = *(const bf16x8*)(wAt + 32768 + n * 128 + kc * 8);
        else {
#pragma unroll
            for (int jj = 0; jj < 8; jj++) bv[jj] = 0;
        }
        *(bf16x8*)(Bs + kc * 1024 + n * 8) = bv;
    }
#pragma unroll
    for (int p = 0; p < 4; p++) {
        const int i = p * 256 + t;
        const int e = i & 63, kc = i >> 6;
        const bf16x8 v = *(const bf16x8*)(A3 + kc * 512 + e * 8);
        const int eg = eb + e;
        *(bf16x8*)(latf8s + (size_t)(eg >> 5) * 5120 + kc * 256 + (eg & 31) * 8) = v;
    }
    __syncthreads();

    // GEMM3: ewv = latents @ wm0 (wn==0 waves) -> Cs [48][65]
    if (wn == 0) {
        f32x4 acc[6];
#pragma unroll
        for (int q = 0; q < 6; q++) acc[q] = zz;
#pragma unroll
        for (int ks = 0; ks < 4; ks++) {
            const int kc = ks * 4 + kq;
            const bf16x8 a0 = *(const bf16x8*)(A3 + kc * 512 + (wm * 32 + l15) * 8);
            const bf16x8 a1 = *(const bf16x8*)(A3 + kc * 512 + (wm * 32 + 16 + l15) * 8);
            const short* bp = Bs + kc * 1024 + l15 * 8;
#pragma unroll
            for (int ni = 0; ni < 3; ni++) {
                const bf16x8 b = *(const bf16x8*)(bp + ni * 128);
                acc[ni]     = __builtin_amdgcn_mfma_f32_16x16x32_bf16(a0, b, acc[ni], 0, 0, 0);
                acc[3 + ni] = __builtin_amdgcn_mfma_f32_16x16x32_bf16(a1, b, acc[3 + ni], 0, 0, 0);
            }
        }
#pragma unroll
        for (int mi = 0; mi < 2; mi++)
#pragma unroll
            for (int ni = 0; ni < 3; ni++) {
                const int c = ni * 16 + l15;
                const int eb2 = wm * 32 + mi * 16 + (kq << 2);
#pragma unroll
                for (int r = 0; r < 4; r++)
                    Cs[c * 65 + eb2 + r] = acc[mi * 3 + ni][r];
            }
    }
    __syncthreads();
    for (int i = t; i < 1536; i += 256) {
        const int c = i >> 6, e = i & 63;
        winiF[(size_t)c * EE + eb + e] = Cs[c * 65 + e];
    }
    for (int i = t; i < 1536; i += 256) {
        const int e2 = i / 24, c2 = i - e2 * 24;
        wcur0[(size_t)(eb + e2) * 24 + c2] = Cs[(24 + c2) * 65 + e2];
    }
}

// ---------------------------------------------------------------------------
// kC1: layer-0 interact + invariants
// ---------------------------------------------------------------------------
__global__ __launch_bounds__(256, 1) void kC1(
    const float* __restrict__ winiF, const bf16* __restrict__ eaT,
    const float* __restrict__ envc, const int* __restrict__ eidx,
    unsigned* __restrict__ newfT, short* __restrict__ latf8s)
{
    const int e = blockIdx.x * 256 + threadIdx.x;
    const int ctr = eidx[e];
    float eav[9];
#pragma unroll
    for (int d = 0; d < 9; d++) eav[d] = b2f(eaT[(size_t)d * EE + e]);
    const float* ec = envc + ctr * 72;
    float inv[24];
#pragma unroll
    for (int uh = 0; uh < 4; uh++) {
        const int u0 = 2 * uh;
        float wi0[3], wi1[3];
#pragma unroll
        for (int i = 0; i < 3; i++) {
            wi0[i] = winiF[(size_t)(u0 * 3 + i) * EE + e];
            wi1[i] = winiF[(size_t)((u0 + 1) * 3 + i) * EE + e];
        }
        float nf0[9], nf1[9];
        const float ec00 = ec[u0 * 9 + 0];
        const float ec10 = ec[(u0 + 1) * 9 + 0];
        const float f00 = wi0[0] * eav[0];
        const float f10 = wi1[0] * eav[0];
#pragma unroll
        for (int d = 0; d < 9; d++) {
            const int irr = (d == 0) ? 0 : ((d < 4) ? 1 : 2);
            const float fa = wi0[irr] * eav[d];
            const float fb = wi1[irr] * eav[d];
            nf0[d] = fa * ec00 + ec[u0 * 9 + d] * f00;
            nf1[d] = fb * ec10 + ec[(u0 + 1) * 9 + d] * f10;
        }
#pragma unroll
        for (int d = 0; d < 9; d++) newfT[(size_t)(d * 4 + uh) * EE + e] = pack2(nf0[d], nf1[d]);
        inv[uh * 6 + 0] = sqrtf(nf0[0] * nf0[0] + 1e-8f);
        inv[uh * 6 + 1] = sqrtf(nf0[1]*nf0[1] + nf0[2]*nf0[2] + nf0[3]*nf0[3] + 1e-8f);
        inv[uh * 6 + 2] = sqrtf(nf0[4]*nf0[4] + nf0[5]*nf0[5] + nf0[6]*nf0[6] + nf0[7]*nf0[7] + nf0[8]*nf0[8] + 1e-8f);
        inv[uh * 6 + 3] = sqrtf(nf1[0] * nf1[0] + 1e-8f);
        inv[uh * 6 + 4] = sqrtf(nf1[1]*nf1[1] + nf1[2]*nf1[2] + nf1[3]*nf1[3] + 1e-8f);
        inv[uh * 6 + 5] = sqrtf(nf1[4]*nf1[4] + nf1[5]*nf1[5] + nf1[6]*nf1[6] + nf1[7]*nf1[7] + nf1[8]*nf1[8] + 1e-8f);
    }
    const size_t tb = (size_t)(e >> 5);
    const int el = e & 31;
#pragma unroll
    for (int j = 0; j < 3; j++) {
        bf16x8 iv;
#pragma unroll
        for (int jj = 0; jj < 8; jj++) iv[jj] = (short)bfbits(inv[j * 8 + jj]);
        *(bf16x8*)(latf8s + tb * 5120 + (16 + j) * 256 + el * 8) = iv;
    }
}

// ---------------------------------------------------------------------------
// kF0: fused layer-0 pe_linear. Per 128-col chunk = one irrep (accO|accN).
// GEMM -> f32 C in LDS -> epilogue writes feat1T. No Wg traffic.
// ---------------------------------------------------------------------------
__global__ __launch_bounds__(256, 2) void kF0(
    const short* __restrict__ A8, const short* __restrict__ Bt,
    const float* __restrict__ winiF, const bf16* __restrict__ eaT,
    const unsigned* __restrict__ newfT, unsigned* __restrict__ feat1T)
{
    __shared__ short Bs[20480];      // [kc][128][8]
    __shared__ float Cs[128 * 67];
    const int t = threadIdx.x;
    const int eb = blockIdx.x * 64;
    const int lane = t & 63, wid = t >> 6;
    const int wm = wid >> 1, wn = wid & 1;
    const int l15 = lane & 15, kq = lane >> 4;
    const f32x4 zz = {0.f, 0.f, 0.f, 0.f};
    const size_t ab = (size_t)((eb >> 5) + wm) * 5120 + l15 * 8;
    const int te = t & 63, uh = t >> 6;
    const int eg = eb + te;

    for (int ir = 0; ir < 3; ir++) {
#pragma unroll
        for (int p = 0; p < 10; p++) {
            const int task = p * 256 + t;
            const int n = task & 127, kc = task >> 7;
            *(bf16x8*)(Bs + kc * 1024 + n * 8) =
                *(const bf16x8*)(Bt + (size_t)(ir * 128 + n) * 160 + kc * 8);
        }
        __syncthreads();
        f32x4 acc[8];
#pragma unroll
        for (int q = 0; q < 8; q++) acc[q] = zz;
#pragma unroll
        for (int ks = 0; ks < 5; ks++) {
            const int kc = ks * 4 + kq;
            const bf16x8 a0 = *(const bf16x8*)(A8 + ab + kc * 256);
            const bf16x8 a1 = *(const bf16x8*)(A8 + ab + kc * 256 + 128);
            const short* bp = Bs + kc * 1024 + (wn * 64 + l15) * 8;
#pragma unroll
            for (int ni = 0; ni < 4; ni++) {
                const bf16x8 b = *(const bf16x8*)(bp + ni * 128);
                acc[ni]     = __builtin_amdgcn_mfma_f32_16x16x32_bf16(a0, b, acc[ni], 0, 0, 0);
                acc[4 + ni] = __builtin_amdgcn_mfma_f32_16x16x32_bf16(a1, b, acc[4 + ni], 0, 0, 0);
            }
        }
#pragma unroll
        for (int mi = 0; mi < 2; mi++)
#pragma unroll
            for (int ni = 0; ni < 4; ni++) {
                const int cl = wn * 64 + ni * 16 + l15;
                const int el = wm * 32 + mi * 16 + (kq << 2);
                const f32x4 v = acc[mi * 4 + ni];
#pragma unroll
                for (int r = 0; r < 4; r++) Cs[cl * 67 + el + r] = v[r];
            }
        __syncthreads();
        // epilogue for this irrep: thread (te, uh) handles u = 2uh, 2uh+1
        const int d0 = (ir == 0) ? 0 : ((ir == 1) ? 1 : 4);
        const int nd = (ir == 0) ? 1 : ((ir == 1) ? 3 : 5);
        float wv[8];
#pragma unroll
        for (int v8 = 0; v8 < 8; v8++) wv[v8] = winiF[(size_t)(v8 * 3 + ir) * EE + eg];
        for (int dd = 0; dd < nd; dd++) {
            const int d = d0 + dd;
            const float ead = b2f(eaT[(size_t)d * EE + eg]);
            float nfv[8];
#pragma unroll
            for (int q = 0; q < 4; q++)
                unpack2(newfT[(size_t)(d * 4 + q) * EE + eg], nfv[2 * q], nfv[2 * q + 1]);
            float s0 = 0.f, s1 = 0.f;
#pragma unroll
            for (int v8 = 0; v8 < 8; v8++) {
                const float fe = wv[v8] * ead;
                s0 += Cs[(uh * 16 + v8) * 67 + te] * fe + Cs[(64 + uh * 16 + v8) * 67 + te] * nfv[v8];
                s1 += Cs[(uh * 16 + 8 + v8) * 67 + te] * fe + Cs[(64 + uh * 16 + 8 + v8) * 67 + te] * nfv[v8];
            }
            feat1T[(size_t)(d * 4 + uh) * EE + eg] = pack2(s0 * HALF_INV_SQM, s1 * HALF_INV_SQM);
        }
        // next iteration's post-stage __syncthreads protects Cs/Bs reuse
    }
}

// ---------------------------------------------------------------------------
// kF3: fused latw GEMM + latent resnet + env-MLP1. In-place latf8s update.
// ---------------------------------------------------------------------------
__global__ __launch_bounds__(256, 2) void kF3(
    short* __restrict__ A8, const short* __restrict__ Bt,
    const float* __restrict__ wm1, const float* __restrict__ cutb,
    float* __restrict__ wcur1)
{
    __shared__ short Bs[20480];
    __shared__ short Cc[128 * 68];   // bf16 C [col][e], stride 68
    __shared__ float wcf[64 * 24];
    const int t = threadIdx.x;
    const int eb = blockIdx.x * 64;
    const int lane = t & 63, wid = t >> 6;
    const int wm = wid >> 1, wn = wid & 1;
    const int l15 = lane & 15, kq = lane >> 4;
    const f32x4 zz = {0.f, 0.f, 0.f, 0.f};
    for (int i = t; i < 1536; i += 256) wcf[i] = 0.f;
#pragma unroll
    for (int p = 0; p < 10; p++) {
        const int task = p * 256 + t;
        const int n = task & 127, kc = task >> 7;
        *(bf16x8*)(Bs + kc * 1024 + n * 8) =
            *(const bf16x8*)(Bt + (size_t)(384 + n) * 160 + kc * 8);
    }
    __syncthreads();
    {
        f32x4 acc[8];
#pragma unroll
        for (int q = 0; q < 8; q++) acc[q] = zz;
        const size_t ab = (size_t)((eb >> 5) + wm) * 5120 + l15 * 8;
#pragma unroll
        for (int ks = 0; ks < 5; ks++) {
            const int kc = ks * 4 + kq;
            const bf16x8 a0 = *(const bf16x8*)(A8 + ab + kc * 256);
            const bf16x8 a1 = *(const bf16x8*)(A8 + ab + kc * 256 + 128);
            const short* bp = Bs + kc * 1024 + (wn * 64 + l15) * 8;
#pragma unroll
            for (int ni = 0; ni < 4; ni++) {
                const bf16x8 b = *(const bf16x8*)(bp + ni * 128);
                acc[ni]     = __builtin_amdgcn_mfma_f32_16x16x32_bf16(a0, b, acc[ni], 0, 0, 0);
                acc[4 + ni] = __builtin_amdgcn_mfma_f32_16x16x32_bf16(a1, b, acc[4 + ni], 0, 0, 0);
            }
        }
#pragma unroll
        for (int mi = 0; mi < 2; mi++)
#pragma unroll
            for (int ni = 0; ni < 4; ni++) {
                const int cl = wn * 64 + ni * 16 + l15;
                const int el = wm * 32 + mi * 16 + (kq << 2);
                const f32x4 v = acc[mi * 4 + ni];
                short4v pv;
#pragma unroll
                for (int r = 0; r < 4; r++) pv[r] = (short)bfbits(v[r]);
                *(short4v*)(Cc + cl * 68 + el) = pv;
            }
    }
    __syncthreads();
    // epilogue: thread (te, q-quarter of j)
    const int te = t & 63, q = t >> 6;
    const int eg = eb + te;
    const size_t tb = (size_t)(eg >> 5);
    const int el2 = eg & 31;
    const float cutv = cutb[eg];
    float wc[24];
#pragma unroll
    for (int c = 0; c < 24; c++) wc[c] = 0.f;
#pragma unroll
    for (int c = 0; c < 4; c++) {
        const int kc = q * 4 + c;
        short* ap = A8 + tb * 5120 + kc * 256 + el2 * 8;
        const bf16x8 ov = *(const bf16x8*)ap;
        bf16x8 nv;
#pragma unroll
        for (int jj = 0; jj < 8; jj++) {
            const int j = kc * 8 + jj;
            const float g = bs2f(Cc[j * 68 + te]);
            const float o = bs2f(ov[jj]);
            const float l1 = 0.5f * o + 0.5f * silu_f(g) * cutv;
            nv[jj] = (short)bfbits(l1);
#pragma unroll
            for (int cc = 0; cc < 24; cc++) wc[cc] = fmaf(l1, wm1[j * 24 + cc], wc[cc]);
        }
        *(bf16x8*)ap = nv;
    }
#pragma unroll
    for (int cc = 0; cc < 24; cc++) atomicAdd(&wcf[te * 24 + cc], wc[cc]);
    __syncthreads();
    for (int i = t; i < 1536; i += 256)
        wcur1[(size_t)eb * 24 + i] = wcf[i];
}

// ---------------------------------------------------------------------------
// kE1: layer-1 interact + invariants
// ---------------------------------------------------------------------------
__global__ __launch_bounds__(256, 1) void kE1(
    const unsigned* __restrict__ feat1T, const float* __restrict__ envc,
    const int* __restrict__ eidx, unsigned* __restrict__ newfT,
    short* __restrict__ latf8s)
{
    const int e = blockIdx.x * 256 + threadIdx.x;
    const int ctr = eidx[e];
    const float* ec = envc + ctr * 72;
    float inv[24];
#pragma unroll
    for (int uh = 0; uh < 4; uh++) {
        const int u0 = 2 * uh;
        float f0[9], f1[9];
#pragma unroll
        for (int d = 0; d < 9; d++) unpack2(feat1T[(size_t)(d * 4 + uh) * EE + e], f0[d], f1[d]);
        const float ec00 = ec[u0 * 9 + 0];
        const float ec10 = ec[(u0 + 1) * 9 + 0];
        float nf0[9], nf1[9];
#pragma unroll
        for (int d = 0; d < 9; d++) {
            nf0[d] = f0[d] * ec00 + ec[u0 * 9 + d] * f0[0];
            nf1[d] = f1[d] * ec10 + ec[(u0 + 1) * 9 + d] * f1[0];
        }
#pragma unroll
        for (int d = 0; d < 9; d++) newfT[(size_t)(d * 4 + uh) * EE + e] = pack2(nf0[d], nf1[d]);
        inv[uh * 6 + 0] = sqrtf(nf0[0] * nf0[0] + 1e-8f);
        inv[uh * 6 + 1] = sqrtf(nf0[1]*nf0[1] + nf0[2]*nf0[2] + nf0[3]*nf0[3] + 1e-8f);
        inv[uh * 6 + 2] = sqrtf(nf0[4]*nf0[4] + nf0[5]*nf0[5] + nf0[6]*nf0[6] + nf0[7]*nf0[7] + nf0[8]*nf0[8] + 1e-8f);
        inv[uh * 6 + 3] = sqrtf(nf1[0] * nf1[0] + 1e-8f);
        inv[uh * 6 + 4] = sqrtf(nf1[1]*nf1[1] + nf1[2]*nf1[2] + nf1[3]*nf1[3] + 1e-8f);
        inv[uh * 6 + 5] = sqrtf(nf1[4]*nf1[4] + nf1[5]*nf1[5] + nf1[6]*nf1[6] + nf1[7]*nf1[7] + nf1[8]*nf1[8] + 1e-8f);
    }
    const size_t tb = (size_t)(e >> 5);
    const int el = e & 31;
#pragma unroll
    for (int j = 0; j < 3; j++) {
        bf16x8 iv;
#pragma unroll
        for (int jj = 0; jj < 8; jj++) iv[jj] = (short)bfbits(inv[j * 8 + jj]);
        *(bf16x8*)(latf8s + tb * 5120 + (16 + j) * 256 + el * 8) = iv;
    }
}

// ---------------------------------------------------------------------------
// kF2: fused final GEMM (accO1|accN1 + finw) + epilogue -> d_out directly
// ---------------------------------------------------------------------------
__global__ __launch_bounds__(256, 2) void kF2(
    const short* __restrict__ A8, const short* __restrict__ Bt,
    const unsigned* __restrict__ feat1T, const unsigned* __restrict__ newfT,
    float* __restrict__ outp)
{
    __shared__ short Bs[20480];
    __shared__ float Cs[128 * 67];
    __shared__ float Cwf[16 * 67];
    const int t = threadIdx.x;
    const int eb = blockIdx.x * 64;
    const int lane = t & 63, wid = t >> 6;
    const int wm = wid >> 1, wn = wid & 1;
    const int l15 = lane & 15, kq = lane >> 4;
    const f32x4 zz = {0.f, 0.f, 0.f, 0.f};
    const size_t ab = (size_t)((eb >> 5) + wm) * 5120 + l15 * 8;
#pragma unroll
    for (int p = 0; p < 10; p++) {
        const int task = p * 256 + t;
        const int n = task & 127, kc = task >> 7;
        *(bf16x8*)(Bs + kc * 1024 + n * 8) =
            *(const bf16x8*)(Bt + (size_t)(512 + n) * 160 + kc * 8);
    }
    __syncthreads();
    {
        f32x4 acc[8];
#pragma unroll
        for (int q = 0; q < 8; q++) acc[q] = zz;
#pragma unroll
        for (int ks = 0; ks < 5; ks++) {
            const int kc = ks * 4 + kq;
            const bf16x8 a0 = *(const bf16x8*)(A8 + ab + kc * 256);
            const bf16x8 a1 = *(const bf16x8*)(A8 + ab + kc * 256 + 128);
            const short* bp = Bs + kc * 1024 + (wn * 64 + l15) * 8;
#pragma unroll
            for (int ni = 0; ni < 4; ni++) {
                const bf16x8 b = *(const bf16x8*)(bp + ni * 128);
                acc[ni]     = __builtin_amdgcn_mfma_f32_16x16x32_bf16(a0, b, acc[ni], 0, 0, 0);
                acc[4 + ni] = __builtin_amdgcn_mfma_f32_16x16x32_bf16(a1, b, acc[4 + ni], 0, 0, 0);
            }
        }
#pragma unroll
        for (int mi = 0; mi < 2; mi++)
#pragma unroll
            for (int ni = 0; ni < 4; ni++) {
                const int cl = wn * 64 + ni * 16 + l15;
                const int el = wm * 32 + mi * 16 + (kq << 2);
                const f32x4 v = acc[mi * 4 + ni];
#pragma unroll
                for (int r = 0; r < 4; r++) Cs[cl * 67 + el + r] = v[r];
            }
    }
    __syncthreads();
    // chunk1: finw (8 valid cols of 16)
    for (int i = t; i < 320; i += 256) {
        const int n = i & 15, kc = i >> 4;
        bf16x8 bv;
        if (n < 8) bv = *(const bf16x8*)(Bt + (size_t)(640 + n) * 160 + kc * 8);
        else {
#pragma unroll
            for (int jj = 0; jj < 8; jj++) bv[jj] = 0;
        }
        *(bf16x8*)(Bs + kc * 1024 + n * 8) = bv;
    }
    __syncthreads();
    {
        f32x4 a2[2] = {zz, zz};
#pragma unroll
        for (int ks = 0; ks < 5; ks++) {
            const int kc = ks * 4 + kq;
            const bf16x8 a0 = *(const bf16x8*)(A8 + ab + kc * 256);
            const bf16x8 a1 = *(const bf16x8*)(A8 + ab + kc * 256 + 128);
            const bf16x8 b = *(const bf16x8*)(Bs + kc * 1024 + l15 * 8);
            a2[0] = __builtin_amdgcn_mfma_f32_16x16x32_bf16(a0, b, a2[0], 0, 0, 0);
            a2[1] = __builtin_amdgcn_mfma_f32_16x16x32_bf16(a1, b, a2[1], 0, 0, 0);
        }
        if (wn == 0) {
#pragma unroll
            for (int mi = 0; mi < 2; mi++) {
                const int el = wm * 32 + mi * 16 + (kq << 2);
#pragma unroll
                for (int r = 0; r < 4; r++) Cwf[l15 * 67 + el + r] = a2[mi][r];
            }
        }
    }
    __syncthreads();
    if (t < 192) {
        const int te = t % 64;
        const int dd = t / 64;
        const int eg = eb + te;
        const int d = 1 + dd;
        float f1v[8], nfv[8];
#pragma unroll
        for (int q = 0; q < 4; q++) {
            unpack2(feat1T[(size_t)(d * 4 + q) * EE + eg], f1v[2 * q], f1v[2 * q + 1]);
            unpack2(newfT[(size_t)(d * 4 + q) * EE + eg], nfv[2 * q], nfv[2 * q + 1]);
        }
        float od = 0.f;
#pragma unroll
        for (int u = 0; u < 8; u++) {
            float s = 0.f;
#pragma unroll
            for (int v8 = 0; v8 < 8; v8++)
                s += Cs[(u * 8 + v8) * 67 + te] * f1v[v8] + Cs[(64 + u * 8 + v8) * 67 + te] * nfv[v8];
            od = fmaf(Cwf[u * 67 + te], s, od);
        }
        outp[(size_t)eg * 3 + dd] = od * (HALF_INV_SQM * INV_SQM);
    }
}

// ---------------------------------------------------------------------------
extern "C" void kernel_launch(void* const* d_in, const int* in_sizes, int n_in,
                              void* d_out, int out_size, void* d_ws, size_t ws_size,
                              hipStream_t stream)
{
    const float* ea   = (const float*)d_in[0];
    const float* eemb = (const float*)d_in[1];
    const float* nat  = (const float*)d_in[2];
    const float* elen = (const float*)d_in[3];
    const float* w0   = (const float*)d_in[4];
    const float* w1   = (const float*)d_in[5];
    const float* w2   = (const float*)d_in[6];
    const float* wm0  = (const float*)d_in[7];
    const float* wm1  = (const float*)d_in[8];
    const float* envl = (const float*)d_in[9];
    const float* latw = (const float*)d_in[10];
    const float* l2fn = (const float*)d_in[11];
    const float* l2fo = (const float*)d_in[12];
    const float* finw = (const float*)d_in[13];
    const int*   eidx = (const int*)d_in[14];

    char* ws = (char*)d_ws;
    short*    latf8s = (short*)(ws + 0);               // [E/32][20][32][8] bf16
    short*    h08    = (short*)(ws + 51200000);        // [E/32][16][32][8] bf16
    unsigned* newfT  = (unsigned*)(ws + 92160000);     // [36][EE] u32; aliased wcur0/1
    unsigned* feat1T = (unsigned*)(ws + 115200000);    // [36][EE] u32
    float*    winiF  = (float*)(ws + 138240000);       // [24][EE] f32
    bf16*     eaT    = (bf16*)(ws + 153600000);        // [9][EE]
    float*    cutb   = (float*)(ws + 156480000);       // [E]
    float*    env0   = (float*)(ws + 157120000);       // [N*72]
    float*    env1   = (float*)(ws + 160000000);       // [N*72]
    int*      deg    = (int*)(ws + 162880000);         // [N] (reused as wAt)
    int*      cur    = (int*)(ws + 162920000);
    int*      off    = (int*)(ws + 162960000);
    int*      elist  = (int*)(ws + 163000192);
    short*    wAt    = (short*)(ws + 162880000);       // [304][128] bf16
    short*    Bt     = (short*)(ws + 163640192);       // [648][160] bf16

    float* wcur0 = (float*)newfT;
    float* wcur1 = (float*)newfT;

    hipMemsetAsync(deg, 0, 80000, stream);

    kCnt <<<625, 256, 0, stream>>>(eidx, deg);
    kScan<<<1, 256, 0, stream>>>(deg, off);
    kFill<<<625, 256, 0, stream>>>(eidx, cur, off, elist);
    kPrepA<<<152, 256, 0, stream>>>(w1, w2, wm0, wAt);   // overwrites deg/cur (dead)
    kPrepB<<<dim3(3, 160), 256, 0, stream>>>(l2fo, l2fn, latw,
                                             l2fo + 29184, l2fn + 29184, finw, Bt);

    kA0<<<625, 256, 0, stream>>>(ea, eemb, nat, elen, w0, eidx, h08, latf8s, eaT, cutb);
    kAm<<<2500, 256, 0, stream>>>(h08, wAt, cutb, latf8s, winiF, wcur0);
    kEnvG<<<352, 256, 0, stream>>>(wcur0, ea, off, elist, envl + 0, env0);
    kC1<<<625, 256, 0, stream>>>(winiF, eaT, env0, eidx, newfT, latf8s);

    kF0<<<2500, 256, 0, stream>>>(latf8s, Bt, winiF, eaT, newfT, feat1T);
    kF3<<<2500, 256, 0, stream>>>(latf8s, Bt, wm1, cutb, wcur1);
    kEnvG<<<352, 256, 0, stream>>>(wcur1, ea, off, elist, envl + 192, env1);
    kE1<<<625, 256, 0, stream>>>(feat1T, env1, eidx, newfT, latf8s);
    kF2<<<2500, 256, 0, stream>>>(latf8s, Bt, feat1T, newfT, (float*)d_out);
}

// Round 9
// 343.531 us; speedup vs baseline: 8.5833x; 1.3159x over previous
//
#include <hip/hip_runtime.h>
#include <hip/hip_bf16.h>

#define EE 160000
#define NNODES 10000

using bf16 = __hip_bfloat16;
using bf16x8 = __attribute__((ext_vector_type(8))) short;
using short4v = __attribute__((ext_vector_type(4))) short;
using f32x4  = __attribute__((ext_vector_type(4))) float;

__device__ __forceinline__ float silu_f(float x) { return x / (1.0f + __expf(-x)); }
__device__ __forceinline__ float b2f(bf16 v) { return __bfloat162float(v); }
__device__ __forceinline__ bf16 f2b(float v) { return __float2bfloat16(v); }

__device__ __forceinline__ unsigned bfbits(float v) {
    union { float f; unsigned u; } a; a.f = v;
    return (a.u + 0x7fffu + ((a.u >> 16) & 1u)) >> 16;
}
__device__ __forceinline__ unsigned pack2(float a, float b) {
    return bfbits(a) | (bfbits(b) << 16);
}
__device__ __forceinline__ void unpack2(unsigned u, float& a, float& b) {
    union { unsigned x; float f; } lo, hi;
    lo.x = u << 16; hi.x = u & 0xffff0000u;
    a = lo.f; b = hi.f;
}
__device__ __forceinline__ float bs2f(short s) {
    union { unsigned u; float f; } x; x.u = ((unsigned)(unsigned short)s) << 16;
    return x.f;
}

// 1/(16*sqrt(8)), 0.5/sqrt(8), 1/sqrt(8)
#define INV_AVGN_SQM 0.02209708691207961f
#define HALF_INV_SQM 0.17677669529663687f
#define INV_SQM      0.35355339059327373f

// ---------------------------------------------------------------------------
// CSR build
// ---------------------------------------------------------------------------
__global__ void kCnt(const int* __restrict__ eidx, int* __restrict__ deg)
{
    const int e = blockIdx.x * 256 + threadIdx.x;
    atomicAdd(&deg[eidx[e]], 1);
}

__global__ void kScan(const int* __restrict__ deg, int* __restrict__ off)
{
    __shared__ int part[256];
    const int t = threadIdx.x;
    int loc[40];
    int s = 0;
#pragma unroll
    for (int i = 0; i < 40; i++) {
        const int idx = t * 40 + i;
        const int v = (idx < NNODES) ? deg[idx] : 0;
        loc[i] = s;
        s += v;
    }
    part[t] = s;
    __syncthreads();
    for (int d = 1; d < 256; d <<= 1) {
        const int v = (t >= d) ? part[t - d] : 0;
        __syncthreads();
        part[t] += v;
        __syncthreads();
    }
    const int base = (t == 0) ? 0 : part[t - 1];
#pragma unroll
    for (int i = 0; i < 40; i++) {
        const int idx = t * 40 + i;
        if (idx < NNODES) off[idx] = base + loc[i];
    }
    if (t == 255) off[NNODES] = part[255];
}

__global__ void kFill(const int* __restrict__ eidx, int* __restrict__ cur,
                      const int* __restrict__ off, int* __restrict__ elist)
{
    const int e = blockIdx.x * 256 + threadIdx.x;
    const int c = eidx[e];
    const int pos = atomicAdd(&cur[c], 1);
    elist[off[c] + pos] = e;
}

// ---------------------------------------------------------------------------
// kPrepA: pre-transpose w1/w2/wm0 -> wAt bf16 [col][128k]
// ---------------------------------------------------------------------------
__global__ void kPrepA(const float* __restrict__ w1, const float* __restrict__ w2,
                       const float* __restrict__ wm0, short* __restrict__ wAt)
{
    const int t = blockIdx.x * 256 + threadIdx.x;
    if (t >= 38912) return;
    const int k = t & 127, c = t >> 7;
    float v;
    if (c < 128)      v = w1[k * 128 + c];
    else if (c < 256) v = w2[k * 128 + (c - 128)];
    else              v = wm0[k * 48 + (c - 256)];
    wAt[c * 128 + k] = (short)bfbits(v);
}

// ---------------------------------------------------------------------------
// kPrepB: pre-transpose K=152(->160 pad) weights -> Bt bf16 [col][160k]
//  cols 0..383:  layer-0, per-irrep: cn = ir*128 + half*64 + (u*8+v)
//  cols 384..511: latw ; 512..575: l2fo1(+64) ; 576..639: l2fn1(+64)
//  cols 640..647: finw ; 648..671: wm1 (K=128)
// ---------------------------------------------------------------------------
__global__ void kPrepB(const float* __restrict__ l2fo, const float* __restrict__ l2fn,
                       const float* __restrict__ latw, const float* __restrict__ l2fo1,
                       const float* __restrict__ l2fn1, const float* __restrict__ finw,
                       const float* __restrict__ wm1, short* __restrict__ Bt)
{
    const int k = blockIdx.y;
    const int col = blockIdx.x * 256 + threadIdx.x;
    if (col >= 672) return;
    float v = 0.f;
    if (col < 648) {
        if (k < 152) {
            if (col < 384) {
                const int ir = col >> 7, half = (col >> 6) & 1, q = col & 63;
                const float* src = half ? l2fn : l2fo;
                v = src[k * 192 + ir * 64 + q];
            } else if (col < 512)  v = latw[k * 128 + (col - 384)];
            else if (col < 576)    v = l2fo1[k * 192 + 64 + (col - 512)];
            else if (col < 640)    v = l2fn1[k * 192 + 64 + (col - 576)];
            else                   v = finw[k * 8 + (col - 640)];
        }
    } else {
        if (k < 128) v = wm1[k * 24 + (col - 648)];
    }
    Bt[(size_t)col * 160 + k] = (short)bfbits(v);
}

// ---------------------------------------------------------------------------
// kEnvG: gather env + fused env-linear (per node,d)
// ---------------------------------------------------------------------------
__global__ void kEnvG(const float* __restrict__ wcur, const float* __restrict__ ea,
                      const int* __restrict__ off, const int* __restrict__ elist,
                      const float* __restrict__ wl, float* __restrict__ envc)
{
    const int t = blockIdx.x * 256 + threadIdx.x;
    if (t >= NNODES * 9) return;
    const int n = t / 9;
    const int d = t - n * 9;
    const int irr = (d == 0) ? 0 : ((d < 4) ? 1 : 2);
    float v[8];
#pragma unroll
    for (int q = 0; q < 8; q++) v[q] = 0.0f;
    const int b = off[n], en = off[n + 1];
    for (int j = b; j < en; j++) {
        const int e = elist[j];
        const float ad = ea[e * 9 + d];
        const float* wr = wcur + (size_t)e * 24 + irr;
#pragma unroll
        for (int q = 0; q < 8; q++) v[q] = fmaf(wr[q * 3], ad, v[q]);
    }
#pragma unroll
    for (int u = 0; u < 8; u++) {
        float s = 0.0f;
#pragma unroll
        for (int q = 0; q < 8; q++) s = fmaf(wl[irr * 64 + u * 8 + q], v[q], s);
        envc[n * 72 + u * 9 + d] = s * INV_AVGN_SQM;
    }
}

// ---------------------------------------------------------------------------
// kA0: inputs gather + cutoff + stage0 (16->128) -> h08; eaT; pad chunk
// ---------------------------------------------------------------------------
__global__ __launch_bounds__(256) void kA0(
    const float* __restrict__ ea, const float* __restrict__ eemb,
    const float* __restrict__ nat, const float* __restrict__ elen,
    const float* __restrict__ w0, const int* __restrict__ eidx,
    short* __restrict__ h08, short* __restrict__ latf8s,
    bf16* __restrict__ eaT, float* __restrict__ cutb)
{
    __shared__ float w0s[16 * 128];
    const int t = threadIdx.x;
    const int e = blockIdx.x * 256 + t;
#pragma unroll
    for (int p = 0; p < 8; p++) { const int idx = p * 256 + t; w0s[idx] = w0[idx]; }
    __syncthreads();

    const int ctr = eidx[e];
    const int ngb = eidx[EE + e];
    float tin[16];
#pragma unroll
    for (int k = 0; k < 4; k++) tin[k] = nat[ctr * 4 + k];
#pragma unroll
    for (int k = 0; k < 4; k++) tin[4 + k] = nat[ngb * 4 + k];
#pragma unroll
    for (int k = 0; k < 8; k++) tin[8 + k] = eemb[e * 8 + k];

    const float x = elen[e];
    const float x2 = x * x, x4 = x2 * x2, x6 = x4 * x2, x7 = x6 * x, x8 = x7 * x;
    float cutv = 1.0f - 28.0f * x6 + 48.0f * x7 - 21.0f * x8;
    cutv = (x < 1.0f) ? cutv : 0.0f;
    cutb[e] = cutv;

    const size_t tb = (size_t)(e >> 5);
    const int el = e & 31;
#pragma unroll
    for (int jc = 0; jc < 4; jc++) {
        float a[32];
#pragma unroll
        for (int j = 0; j < 32; j++) a[j] = 0.0f;
#pragma unroll
        for (int k = 0; k < 16; k++) {
            const float v = tin[k];
#pragma unroll
            for (int j = 0; j < 32; j++) a[j] = fmaf(v, w0s[k * 128 + jc * 32 + j], a[j]);
        }
#pragma unroll
        for (int cc = 0; cc < 4; cc++) {
            bf16x8 hv;
#pragma unroll
            for (int jj = 0; jj < 8; jj++) hv[jj] = (short)bfbits(silu_f(a[cc * 8 + jj]));
            *(bf16x8*)(h08 + tb * 4096 + (jc * 4 + cc) * 256 + el * 8) = hv;
        }
    }
    bf16x8 z;
#pragma unroll
    for (int jj = 0; jj < 8; jj++) z[jj] = 0;
    *(bf16x8*)(latf8s + tb * 5120 + 19 * 256 + el * 8) = z;

#pragma unroll
    for (int d = 0; d < 9; d++) eaT[(size_t)d * EE + e] = f2b(ea[e * 9 + d]);
}

// ---------------------------------------------------------------------------
// kAm: MFMA chain h0@w1 -> silu -> @w2 -> *cut ; latents@wm0 -> wini/wcur0
// ---------------------------------------------------------------------------
__global__ __launch_bounds__(256, 2) void kAm(
    const short* __restrict__ h08, const short* __restrict__ wAt,
    const float* __restrict__ cutb, short* __restrict__ latf8s,
    float* __restrict__ winiF, float* __restrict__ wcur0)
{
    __shared__ short Bs[16 * 128 * 8];                       // 32 KB
    __shared__ alignas(16) char a2raw[16384];                // A2 / Cs (16 KB)
    __shared__ short A3[8192];                               // 16 KB
    short* A2 = (short*)a2raw;
    float* Cs = (float*)a2raw;

    const int t = threadIdx.x;
    const int eb = blockIdx.x * 64;
    const int lane = t & 63, wid = t >> 6;
    const int wm = wid >> 1, wn = wid & 1;
    const int l15 = lane & 15, kq = lane >> 4;
    const f32x4 zz = {0.f, 0.f, 0.f, 0.f};

#pragma unroll
    for (int p = 0; p < 8; p++) {
        const int task = p * 256 + t;
        const int n = task & 127, kc = task >> 7;
        *(bf16x8*)(Bs + kc * 1024 + n * 8) = *(const bf16x8*)(wAt + n * 128 + kc * 8);
    }
    float cutR[2][4];
#pragma unroll
    for (int mi = 0; mi < 2; mi++)
#pragma unroll
        for (int r = 0; r < 4; r++)
            cutR[mi][r] = cutb[eb + wm * 32 + mi * 16 + kq * 4 + r];
    __syncthreads();

    // GEMM1: h1 = silu(h0 @ w1) -> A2
    {
        f32x4 acc[8];
#pragma unroll
        for (int q = 0; q < 8; q++) acc[q] = zz;
        const size_t ab = (size_t)((eb >> 5) + wm) * 4096 + l15 * 8;
#pragma unroll
        for (int ks = 0; ks < 4; ks++) {
            const int kc = ks * 4 + kq;
            const bf16x8 a0 = *(const bf16x8*)(h08 + ab + kc * 256);
            const bf16x8 a1 = *(const bf16x8*)(h08 + ab + kc * 256 + 128);
            const short* bp = Bs + kc * 1024 + (wn * 64 + l15) * 8;
#pragma unroll
            for (int ni = 0; ni < 4; ni++) {
                const bf16x8 b = *(const bf16x8*)(bp + ni * 128);
                acc[ni]     = __builtin_amdgcn_mfma_f32_16x16x32_bf16(a0, b, acc[ni], 0, 0, 0);
                acc[4 + ni] = __builtin_amdgcn_mfma_f32_16x16x32_bf16(a1, b, acc[4 + ni], 0, 0, 0);
            }
        }
#pragma unroll
        for (int mi = 0; mi < 2; mi++)
#pragma unroll
            for (int ni = 0; ni < 4; ni++) {
                const int kcol = wn * 64 + ni * 16 + l15;
                const int eb2 = wm * 32 + mi * 16 + (kq << 2);
#pragma unroll
                for (int r = 0; r < 4; r++)
                    A2[(kcol >> 3) * 512 + (eb2 + r) * 8 + (kcol & 7)] =
                        (short)bfbits(silu_f(acc[mi * 4 + ni][r]));
            }
    }
    __syncthreads();
#pragma unroll
    for (int p = 0; p < 8; p++) {
        const int task = p * 256 + t;
        const int n = task & 127, kc = task >> 7;
        *(bf16x8*)(Bs + kc * 1024 + n * 8) = *(const bf16x8*)(wAt + 16384 + n * 128 + kc * 8);
    }
    __syncthreads();

    // GEMM2: latents = (h1 @ w2) * cut -> A3
    {
        f32x4 acc[8];
#pragma unroll
        for (int q = 0; q < 8; q++) acc[q] = zz;
#pragma unroll
        for (int ks = 0; ks < 4; ks++) {
            const int kc = ks * 4 + kq;
            const bf16x8 a0 = *(const bf16x8*)(A2 + kc * 512 + (wm * 32 + l15) * 8);
            const bf16x8 a1 = *(const bf16x8*)(A2 + kc * 512 + (wm * 32 + 16 + l15) * 8);
            const short* bp = Bs + kc * 1024 + (wn * 64 + l15) * 8;
#pragma unroll
            for (int ni = 0; ni < 4; ni++) {
                const bf16x8 b = *(const bf16x8*)(bp + ni * 128);
                acc[ni]     = __builtin_amdgcn_mfma_f32_16x16x32_bf16(a0, b, acc[ni], 0, 0, 0);
                acc[4 + ni] = __builtin_amdgcn_mfma_f32_16x16x32_bf16(a1, b, acc[4 + ni], 0, 0, 0);
            }
        }
#pragma unroll
        for (int mi = 0; mi < 2; mi++)
#pragma unroll
            for (int ni = 0; ni < 4; ni++) {
                const int kcol = wn * 64 + ni * 16 + l15;
                const int eb2 = wm * 32 + mi * 16 + (kq << 2);
#pragma unroll
                for (int r = 0; r < 4; r++)
                    A3[(kcol >> 3) * 512 + (eb2 + r) * 8 + (kcol & 7)] =
                        (short)bfbits(acc[mi * 4 + ni][r] * cutR[mi][r]);
            }
    }
    __syncthreads();
#pragma unroll
    for (int p = 0; p < 8; p++) {
        const int task = p * 256 + t;
        const int n = task & 127, kc = task >> 7;
        bf16x8 bv;
        if (n < 48) bv = *(const bf16x8*)(wAt + 32768 + n * 128 + kc * 8);
        else {
#pragma unroll
            for (int jj = 0; jj < 8; jj++) bv[jj] = 0;
        }
        *(bf16x8*)(Bs + kc * 1024 + n * 8) = bv;
    }
#pragma unroll
    for (int p = 0; p < 4; p++) {
        const int i = p * 256 + t;
        const int e = i & 63, kc = i >> 6;
        const bf16x8 v = *(const bf16x8*)(A3 + kc * 512 + e * 8);
        const int eg = eb + e;
        *(bf16x8*)(latf8s + (size_t)(eg >> 5) * 5120 + kc * 256 + (eg & 31) * 8) = v;
    }
    __syncthreads();

    // GEMM3: ewv = latents @ wm0 (wn==0 waves) -> Cs [48][65]
    if (wn == 0) {
        f32x4 acc[6];
#pragma unroll
        for (int q = 0; q < 6; q++) acc[q] = zz;
#pragma unroll
        for (int ks = 0; ks < 4; ks++) {
            const int kc = ks * 4 + kq;
            const bf16x8 a0 = *(const bf16x8*)(A3 + kc * 512 + (wm * 32 + l15) * 8);
            const bf16x8 a1 = *(const bf16x8*)(A3 + kc * 512 + (wm * 32 + 16 + l15) * 8);
            const short* bp = Bs + kc * 1024 + l15 * 8;
#pragma unroll
            for (int ni = 0; ni < 3; ni++) {
                const bf16x8 b = *(const bf16x8*)(bp + ni * 128);
                acc[ni]     = __builtin_amdgcn_mfma_f32_16x16x32_bf16(a0, b, acc[ni], 0, 0, 0);
                acc[3 + ni] = __builtin_amdgcn_mfma_f32_16x16x32_bf16(a1, b, acc[3 + ni], 0, 0, 0);
            }
        }
#pragma unroll
        for (int mi = 0; mi < 2; mi++)
#pragma unroll
            for (int ni = 0; ni < 3; ni++) {
                const int c = ni * 16 + l15;
                const int eb2 = wm * 32 + mi * 16 + (kq << 2);
#pragma unroll
                for (int r = 0; r < 4; r++)
                    Cs[c * 65 + eb2 + r] = acc[mi * 3 + ni][r];
            }
    }
    __syncthreads();
    for (int i = t; i < 1536; i += 256) {
        const int c = i >> 6, e = i & 63;
        winiF[(size_t)c * EE + eb + e] = Cs[c * 65 + e];
    }
    for (int i = t; i < 1536; i += 256) {
        const int e2 = i / 24, c2 = i - e2 * 24;
        wcur0[(size_t)(eb + e2) * 24 + c2] = Cs[(24 + c2) * 65 + e2];
    }
}

// ---------------------------------------------------------------------------
// kC1: layer-0 interact + invariants
// ---------------------------------------------------------------------------
__global__ __launch_bounds__(256, 1) void kC1(
    const float* __restrict__ winiF, const bf16* __restrict__ eaT,
    const float* __restrict__ envc, const int* __restrict__ eidx,
    unsigned* __restrict__ newfT, short* __restrict__ latf8s)
{
    const int e = blockIdx.x * 256 + threadIdx.x;
    const int ctr = eidx[e];
    float eav[9];
#pragma unroll
    for (int d = 0; d < 9; d++) eav[d] = b2f(eaT[(size_t)d * EE + e]);
    const float* ec = envc + ctr * 72;
    float inv[24];
#pragma unroll
    for (int uh = 0; uh < 4; uh++) {
        const int u0 = 2 * uh;
        float wi0[3], wi1[3];
#pragma unroll
        for (int i = 0; i < 3; i++) {
            wi0[i] = winiF[(size_t)(u0 * 3 + i) * EE + e];
            wi1[i] = winiF[(size_t)((u0 + 1) * 3 + i) * EE + e];
        }
        float nf0[9], nf1[9];
        const float ec00 = ec[u0 * 9 + 0];
        const float ec10 = ec[(u0 + 1) * 9 + 0];
        const float f00 = wi0[0] * eav[0];
        const float f10 = wi1[0] * eav[0];
#pragma unroll
        for (int d = 0; d < 9; d++) {
            const int irr = (d == 0) ? 0 : ((d < 4) ? 1 : 2);
            const float fa = wi0[irr] * eav[d];
            const float fb = wi1[irr] * eav[d];
            nf0[d] = fa * ec00 + ec[u0 * 9 + d] * f00;
            nf1[d] = fb * ec10 + ec[(u0 + 1) * 9 + d] * f10;
        }
#pragma unroll
        for (int d = 0; d < 9; d++) newfT[(size_t)(d * 4 + uh) * EE + e] = pack2(nf0[d], nf1[d]);
        inv[uh * 6 + 0] = sqrtf(nf0[0] * nf0[0] + 1e-8f);
        inv[uh * 6 + 1] = sqrtf(nf0[1]*nf0[1] + nf0[2]*nf0[2] + nf0[3]*nf0[3] + 1e-8f);
        inv[uh * 6 + 2] = sqrtf(nf0[4]*nf0[4] + nf0[5]*nf0[5] + nf0[6]*nf0[6] + nf0[7]*nf0[7] + nf0[8]*nf0[8] + 1e-8f);
        inv[uh * 6 + 3] = sqrtf(nf1[0] * nf1[0] + 1e-8f);
        inv[uh * 6 + 4] = sqrtf(nf1[1]*nf1[1] + nf1[2]*nf1[2] + nf1[3]*nf1[3] + 1e-8f);
        inv[uh * 6 + 5] = sqrtf(nf1[4]*nf1[4] + nf1[5]*nf1[5] + nf1[6]*nf1[6] + nf1[7]*nf1[7] + nf1[8]*nf1[8] + 1e-8f);
    }
    const size_t tb = (size_t)(e >> 5);
    const int el = e & 31;
#pragma unroll
    for (int j = 0; j < 3; j++) {
        bf16x8 iv;
#pragma unroll
        for (int jj = 0; jj < 8; jj++) iv[jj] = (short)bfbits(inv[j * 8 + jj]);
        *(bf16x8*)(latf8s + tb * 5120 + (16 + j) * 256 + el * 8) = iv;
    }
}

// ---------------------------------------------------------------------------
// kF0: fused layer-0 pe_linear. Per 128-col chunk = one irrep (accO|accN).
// ---------------------------------------------------------------------------
__global__ __launch_bounds__(256, 2) void kF0(
    const short* __restrict__ A8, const short* __restrict__ Bt,
    const float* __restrict__ winiF, const bf16* __restrict__ eaT,
    const unsigned* __restrict__ newfT, unsigned* __restrict__ feat1T)
{
    __shared__ short Bs[20480];      // [kc][128][8]
    __shared__ float Cs[128 * 67];
    const int t = threadIdx.x;
    const int eb = blockIdx.x * 64;
    const int lane = t & 63, wid = t >> 6;
    const int wm = wid >> 1, wn = wid & 1;
    const int l15 = lane & 15, kq = lane >> 4;
    const f32x4 zz = {0.f, 0.f, 0.f, 0.f};
    const size_t ab = (size_t)((eb >> 5) + wm) * 5120 + l15 * 8;
    const int te = t & 63, uh = t >> 6;
    const int eg = eb + te;

    for (int ir = 0; ir < 3; ir++) {
#pragma unroll
        for (int p = 0; p < 10; p++) {
            const int task = p * 256 + t;
            const int n = task & 127, kc = task >> 7;
            *(bf16x8*)(Bs + kc * 1024 + n * 8) =
                *(const bf16x8*)(Bt + (size_t)(ir * 128 + n) * 160 + kc * 8);
        }
        __syncthreads();
        f32x4 acc[8];
#pragma unroll
        for (int q = 0; q < 8; q++) acc[q] = zz;
#pragma unroll
        for (int ks = 0; ks < 5; ks++) {
            const int kc = ks * 4 + kq;
            const bf16x8 a0 = *(const bf16x8*)(A8 + ab + kc * 256);
            const bf16x8 a1 = *(const bf16x8*)(A8 + ab + kc * 256 + 128);
            const short* bp = Bs + kc * 1024 + (wn * 64 + l15) * 8;
#pragma unroll
            for (int ni = 0; ni < 4; ni++) {
                const bf16x8 b = *(const bf16x8*)(bp + ni * 128);
                acc[ni]     = __builtin_amdgcn_mfma_f32_16x16x32_bf16(a0, b, acc[ni], 0, 0, 0);
                acc[4 + ni] = __builtin_amdgcn_mfma_f32_16x16x32_bf16(a1, b, acc[4 + ni], 0, 0, 0);
            }
        }
#pragma unroll
        for (int mi = 0; mi < 2; mi++)
#pragma unroll
            for (int ni = 0; ni < 4; ni++) {
                const int cl = wn * 64 + ni * 16 + l15;
                const int el = wm * 32 + mi * 16 + (kq << 2);
                const f32x4 v = acc[mi * 4 + ni];
#pragma unroll
                for (int r = 0; r < 4; r++) Cs[cl * 67 + el + r] = v[r];
            }
        __syncthreads();
        const int d0 = (ir == 0) ? 0 : ((ir == 1) ? 1 : 4);
        const int nd = (ir == 0) ? 1 : ((ir == 1) ? 3 : 5);
        float wv[8];
#pragma unroll
        for (int v8 = 0; v8 < 8; v8++) wv[v8] = winiF[(size_t)(v8 * 3 + ir) * EE + eg];
        for (int dd = 0; dd < nd; dd++) {
            const int d = d0 + dd;
            const float ead = b2f(eaT[(size_t)d * EE + eg]);
            float nfv[8];
#pragma unroll
            for (int q = 0; q < 4; q++)
                unpack2(newfT[(size_t)(d * 4 + q) * EE + eg], nfv[2 * q], nfv[2 * q + 1]);
            float s0 = 0.f, s1 = 0.f;
#pragma unroll
            for (int v8 = 0; v8 < 8; v8++) {
                const float fe = wv[v8] * ead;
                s0 += Cs[(uh * 16 + v8) * 67 + te] * fe + Cs[(64 + uh * 16 + v8) * 67 + te] * nfv[v8];
                s1 += Cs[(uh * 16 + 8 + v8) * 67 + te] * fe + Cs[(64 + uh * 16 + 8 + v8) * 67 + te] * nfv[v8];
            }
            feat1T[(size_t)(d * 4 + uh) * EE + eg] = pack2(s0 * HALF_INV_SQM, s1 * HALF_INV_SQM);
        }
    }
}

// ---------------------------------------------------------------------------
// kF3: fused latw GEMM + latent resnet + env-MLP1 (as MFMA mini-GEMM).
// In-place latf8s update; wcur1 via l1s @ wm1t on matrix cores.
// ---------------------------------------------------------------------------
__global__ __launch_bounds__(256, 2) void kF3(
    short* __restrict__ A8, const short* __restrict__ Bt,
    const float* __restrict__ cutb, float* __restrict__ wcur1)
{
    __shared__ short Bs[20480];                 // latw panel; reused for wm1t
    __shared__ alignas(16) short Cc[128 * 68];  // bf16 lat_new [col][e]; reused as Cw (f32)
    __shared__ short l1s[16 * 512];             // l1 A-fragment tile [kc][e][8]
    float* Cw = (float*)Cc;
    const int t = threadIdx.x;
    const int eb = blockIdx.x * 64;
    const int lane = t & 63, wid = t >> 6;
    const int wm = wid >> 1, wn = wid & 1;
    const int l15 = lane & 15, kq = lane >> 4;
    const f32x4 zz = {0.f, 0.f, 0.f, 0.f};

#pragma unroll
    for (int p = 0; p < 10; p++) {
        const int task = p * 256 + t;
        const int n = task & 127, kc = task >> 7;
        *(bf16x8*)(Bs + kc * 1024 + n * 8) =
            *(const bf16x8*)(Bt + (size_t)(384 + n) * 160 + kc * 8);
    }
    __syncthreads();
    {
        f32x4 acc[8];
#pragma unroll
        for (int q = 0; q < 8; q++) acc[q] = zz;
        const size_t ab = (size_t)((eb >> 5) + wm) * 5120 + l15 * 8;
#pragma unroll
        for (int ks = 0; ks < 5; ks++) {
            const int kc = ks * 4 + kq;
            const bf16x8 a0 = *(const bf16x8*)(A8 + ab + kc * 256);
            const bf16x8 a1 = *(const bf16x8*)(A8 + ab + kc * 256 + 128);
            const short* bp = Bs + kc * 1024 + (wn * 64 + l15) * 8;
#pragma unroll
            for (int ni = 0; ni < 4; ni++) {
                const bf16x8 b = *(const bf16x8*)(bp + ni * 128);
                acc[ni]     = __builtin_amdgcn_mfma_f32_16x16x32_bf16(a0, b, acc[ni], 0, 0, 0);
                acc[4 + ni] = __builtin_amdgcn_mfma_f32_16x16x32_bf16(a1, b, acc[4 + ni], 0, 0, 0);
            }
        }
#pragma unroll
        for (int mi = 0; mi < 2; mi++)
#pragma unroll
            for (int ni = 0; ni < 4; ni++) {
                const int cl = wn * 64 + ni * 16 + l15;
                const int el = wm * 32 + mi * 16 + (kq << 2);
                const f32x4 v = acc[mi * 4 + ni];
                short4v pv;
#pragma unroll
                for (int r = 0; r < 4; r++) pv[r] = (short)bfbits(v[r]);
                *(short4v*)(Cc + cl * 68 + el) = pv;
            }
    }
    __syncthreads();
    // epilogue: l1 = 0.5*old + 0.5*silu(lat_new)*cut -> A8 (in place) + l1s
    {
        const int te = t & 63, q = t >> 6;
        const int eg = eb + te;
        const size_t tb = (size_t)(eg >> 5);
        const int el2 = eg & 31;
        const float cutv = cutb[eg];
#pragma unroll
        for (int c = 0; c < 4; c++) {
            const int kc = q * 4 + c;
            short* ap = A8 + tb * 5120 + kc * 256 + el2 * 8;
            const bf16x8 ov = *(const bf16x8*)ap;
            bf16x8 nv;
#pragma unroll
            for (int jj = 0; jj < 8; jj++) {
                const int j = kc * 8 + jj;
                const float g = bs2f(Cc[j * 68 + te]);
                const float o = bs2f(ov[jj]);
                nv[jj] = (short)bfbits(0.5f * o + 0.5f * silu_f(g) * cutv);
            }
            *(bf16x8*)ap = nv;
            *(bf16x8*)(l1s + kc * 512 + te * 8) = nv;
        }
    }
    // stage wm1t (24 cols x 16 kc) into Bs (concurrent with epilogue, Bs is dead)
    for (int i = t; i < 384; i += 256) {
        const int n = i % 24, kc = i / 24;
        *(bf16x8*)(Bs + kc * 1024 + n * 8) =
            *(const bf16x8*)(Bt + (size_t)(648 + n) * 160 + kc * 8);
    }
    __syncthreads();
    // mini-GEMM: wcur1 = l1 @ wm1 (wn==0 waves; cols 0..23 valid)
    if (wn == 0) {
        f32x4 acc[4] = {zz, zz, zz, zz};
#pragma unroll
        for (int ks = 0; ks < 4; ks++) {
            const int kc = ks * 4 + kq;
            const bf16x8 a0 = *(const bf16x8*)(l1s + kc * 512 + (wm * 32 + l15) * 8);
            const bf16x8 a1 = *(const bf16x8*)(l1s + kc * 512 + (wm * 32 + 16 + l15) * 8);
            const short* bp = Bs + kc * 1024 + l15 * 8;
#pragma unroll
            for (int ni = 0; ni < 2; ni++) {
                const bf16x8 b = *(const bf16x8*)(bp + ni * 128);
                acc[ni]     = __builtin_amdgcn_mfma_f32_16x16x32_bf16(a0, b, acc[ni], 0, 0, 0);
                acc[2 + ni] = __builtin_amdgcn_mfma_f32_16x16x32_bf16(a1, b, acc[2 + ni], 0, 0, 0);
            }
        }
#pragma unroll
        for (int mi = 0; mi < 2; mi++)
#pragma unroll
            for (int ni = 0; ni < 2; ni++) {
                const int c = ni * 16 + l15;
                if (c < 24) {
                    const int el = wm * 32 + mi * 16 + (kq << 2);
#pragma unroll
                    for (int r = 0; r < 4; r++) Cw[c * 65 + el + r] = acc[mi * 2 + ni][r];
                }
            }
    }
    __syncthreads();
    for (int i = t; i < 1536; i += 256) {
        const int e2 = i / 24, c2 = i - e2 * 24;
        wcur1[(size_t)(eb + e2) * 24 + c2] = Cw[c2 * 65 + e2];
    }
}

// ---------------------------------------------------------------------------
// kE1: layer-1 interact + invariants
// ---------------------------------------------------------------------------
__global__ __launch_bounds__(256, 1) void kE1(
    const unsigned* __restrict__ feat1T, const float* __restrict__ envc,
    const int* __restrict__ eidx, unsigned* __restrict__ newfT,
    short* __restrict__ latf8s)
{
    const int e = blockIdx.x * 256 + threadIdx.x;
    const int ctr = eidx[e];
    const float* ec = envc + ctr * 72;
    float inv[24];
#pragma unroll
    for (int uh = 0; uh < 4; uh++) {
        const int u0 = 2 * uh;
        float f0[9], f1[9];
#pragma unroll
        for (int d = 0; d < 9; d++) unpack2(feat1T[(size_t)(d * 4 + uh) * EE + e], f0[d], f1[d]);
        const float ec00 = ec[u0 * 9 + 0];
        const float ec10 = ec[(u0 + 1) * 9 + 0];
        float nf0[9], nf1[9];
#pragma unroll
        for (int d = 0; d < 9; d++) {
            nf0[d] = f0[d] * ec00 + ec[u0 * 9 + d] * f0[0];
            nf1[d] = f1[d] * ec10 + ec[(u0 + 1) * 9 + d] * f1[0];
        }
#pragma unroll
        for (int d = 0; d < 9; d++) newfT[(size_t)(d * 4 + uh) * EE + e] = pack2(nf0[d], nf1[d]);
        inv[uh * 6 + 0] = sqrtf(nf0[0] * nf0[0] + 1e-8f);
        inv[uh * 6 + 1] = sqrtf(nf0[1]*nf0[1] + nf0[2]*nf0[2] + nf0[3]*nf0[3] + 1e-8f);
        inv[uh * 6 + 2] = sqrtf(nf0[4]*nf0[4] + nf0[5]*nf0[5] + nf0[6]*nf0[6] + nf0[7]*nf0[7] + nf0[8]*nf0[8] + 1e-8f);
        inv[uh * 6 + 3] = sqrtf(nf1[0] * nf1[0] + 1e-8f);
        inv[uh * 6 + 4] = sqrtf(nf1[1]*nf1[1] + nf1[2]*nf1[2] + nf1[3]*nf1[3] + 1e-8f);
        inv[uh * 6 + 5] = sqrtf(nf1[4]*nf1[4] + nf1[5]*nf1[5] + nf1[6]*nf1[6] + nf1[7]*nf1[7] + nf1[8]*nf1[8] + 1e-8f);
    }
    const size_t tb = (size_t)(e >> 5);
    const int el = e & 31;
#pragma unroll
    for (int j = 0; j < 3; j++) {
        bf16x8 iv;
#pragma unroll
        for (int jj = 0; jj < 8; jj++) iv[jj] = (short)bfbits(inv[j * 8 + jj]);
        *(bf16x8*)(latf8s + tb * 5120 + (16 + j) * 256 + el * 8) = iv;
    }
}

// ---------------------------------------------------------------------------
// kF2: fused final GEMM (accO1|accN1 + finw) + epilogue -> d_out directly
// ---------------------------------------------------------------------------
__global__ __launch_bounds__(256, 2) void kF2(
    const short* __restrict__ A8, const short* __restrict__ Bt,
    const unsigned* __restrict__ feat1T, const unsigned* __restrict__ newfT,
    float* __restrict__ outp)
{
    __shared__ short Bs[20480];
    __shared__ float Cs[128 * 67];
    __shared__ float Cwf[16 * 67];
    const int t = threadIdx.x;
    const int eb = blockIdx.x * 64;
    const int lane = t & 63, wid = t >> 6;
    const int wm = wid >> 1, wn = wid & 1;
    const int l15 = lane & 15, kq = lane >> 4;
    const f32x4 zz = {0.f, 0.f, 0.f, 0.f};
    const size_t ab = (size_t)((eb >> 5) + wm) * 5120 + l15 * 8;
#pragma unroll
    for (int p = 0; p < 10; p++) {
        const int task = p * 256 + t;
        const int n = task & 127, kc = task >> 7;
        *(bf16x8*)(Bs + kc * 1024 + n * 8) =
            *(const bf16x8*)(Bt + (size_t)(512 + n) * 160 + kc * 8);
    }
    __syncthreads();
    {
        f32x4 acc[8];
#pragma unroll
        for (int q = 0; q < 8; q++) acc[q] = zz;
#pragma unroll
        for (int ks = 0; ks < 5; ks++) {
            const int kc = ks * 4 + kq;
            const bf16x8 a0 = *(const bf16x8*)(A8 + ab + kc * 256);
            const bf16x8 a1 = *(const bf16x8*)(A8 + ab + kc * 256 + 128);
            const short* bp = Bs + kc * 1024 + (wn * 64 + l15) * 8;
#pragma unroll
            for (int ni = 0; ni < 4; ni++) {
                const bf16x8 b = *(const bf16x8*)(bp + ni * 128);
                acc[ni]     = __builtin_amdgcn_mfma_f32_16x16x32_bf16(a0, b, acc[ni], 0, 0, 0);
                acc[4 + ni] = __builtin_amdgcn_mfma_f32_16x16x32_bf16(a1, b, acc[4 + ni], 0, 0, 0);
            }
        }
#pragma unroll
        for (int mi = 0; mi < 2; mi++)
#pragma unroll
            for (int ni = 0; ni < 4; ni++) {
                const int cl = wn * 64 + ni * 16 + l15;
                const int el = wm * 32 + mi * 16 + (kq << 2);
                const f32x4 v = acc[mi * 4 + ni];
#pragma unroll
                for (int r = 0; r < 4; r++) Cs[cl * 67 + el + r] = v[r];
            }
    }
    __syncthreads();
    for (int i = t; i < 320; i += 256) {
        const int n = i & 15, kc = i >> 4;
        bf16x8 bv;
        if (n < 8) bv = *(const bf16x8*)(Bt + (size_t)(640 + n) * 160 + kc * 8);
        else {
#pragma unroll
            for (int jj = 0; jj < 8; jj++) bv[jj] = 0;
        }
        *(bf16x8*)(Bs + kc * 1024 + n * 8) = bv;
    }
    __syncthreads();
    {
        f32x4 a2[2] = {zz, zz};
#pragma unroll
        for (int ks = 0; ks < 5; ks++) {
            const int kc = ks * 4 + kq;
            const bf16x8 a0 = *(const bf16x8*)(A8 + ab + kc * 256);
            const bf16x8 a1 = *(const bf16x8*)(A8 + ab + kc * 256 + 128);
            const bf16x8 b = *(const bf16x8*)(Bs + kc * 1024 + l15 * 8);
            a2[0] = __builtin_amdgcn_mfma_f32_16x16x32_bf16(a0, b, a2[0], 0, 0, 0);
            a2[1] = __builtin_amdgcn_mfma_f32_16x16x32_bf16(a1, b, a2[1], 0, 0, 0);
        }
        if (wn == 0) {
#pragma unroll
            for (int mi = 0; mi < 2; mi++) {
                const int el = wm * 32 + mi * 16 + (kq << 2);
#pragma unroll
                for (int r = 0; r < 4; r++) Cwf[l15 * 67 + el + r] = a2[mi][r];
            }
        }
    }
    __syncthreads();
    if (t < 192) {
        const int te = t % 64;
        const int dd = t / 64;
        const int eg = eb + te;
        const int d = 1 + dd;
        float f1v[8], nfv[8];
#pragma unroll
        for (int q = 0; q < 4; q++) {
            unpack2(feat1T[(size_t)(d * 4 + q) * EE + eg], f1v[2 * q], f1v[2 * q + 1]);
            unpack2(newfT[(size_t)(d * 4 + q) * EE + eg], nfv[2 * q], nfv[2 * q + 1]);
        }
        float od = 0.f;
#pragma unroll
        for (int u = 0; u < 8; u++) {
            float s = 0.f;
#pragma unroll
            for (int v8 = 0; v8 < 8; v8++)
                s += Cs[(u * 8 + v8) * 67 + te] * f1v[v8] + Cs[(64 + u * 8 + v8) * 67 + te] * nfv[v8];
            od = fmaf(Cwf[u * 67 + te], s, od);
        }
        outp[(size_t)eg * 3 + dd] = od * (HALF_INV_SQM * INV_SQM);
    }
}

// ---------------------------------------------------------------------------
extern "C" void kernel_launch(void* const* d_in, const int* in_sizes, int n_in,
                              void* d_out, int out_size, void* d_ws, size_t ws_size,
                              hipStream_t stream)
{
    const float* ea   = (const float*)d_in[0];
    const float* eemb = (const float*)d_in[1];
    const float* nat  = (const float*)d_in[2];
    const float* elen = (const float*)d_in[3];
    const float* w0   = (const float*)d_in[4];
    const float* w1   = (const float*)d_in[5];
    const float* w2   = (const float*)d_in[6];
    const float* wm0  = (const float*)d_in[7];
    const float* wm1  = (const float*)d_in[8];
    const float* envl = (const float*)d_in[9];
    const float* latw = (const float*)d_in[10];
    const float* l2fn = (const float*)d_in[11];
    const float* l2fo = (const float*)d_in[12];
    const float* finw = (const float*)d_in[13];
    const int*   eidx = (const int*)d_in[14];

    char* ws = (char*)d_ws;
    short*    latf8s = (short*)(ws + 0);               // [E/32][20][32][8] bf16
    short*    h08    = (short*)(ws + 51200000);        // [E/32][16][32][8] bf16
    unsigned* newfT  = (unsigned*)(ws + 92160000);     // [36][EE] u32; aliased wcur0/1
    unsigned* feat1T = (unsigned*)(ws + 115200000);    // [36][EE] u32
    float*    winiF  = (float*)(ws + 138240000);       // [24][EE] f32
    bf16*     eaT    = (bf16*)(ws + 153600000);        // [9][EE]
    float*    cutb   = (float*)(ws + 156480000);       // [E]
    float*    env0   = (float*)(ws + 157120000);       // [N*72]
    float*    env1   = (float*)(ws + 160000000);       // [N*72]
    int*      deg    = (int*)(ws + 162880000);         // [N] (reused as wAt)
    int*      cur    = (int*)(ws + 162920000);
    int*      off    = (int*)(ws + 162960000);
    int*      elist  = (int*)(ws + 163000192);
    short*    wAt    = (short*)(ws + 162880000);       // [304][128] bf16
    short*    Bt     = (short*)(ws + 163640192);       // [672][160] bf16

    float* wcur0 = (float*)newfT;
    float* wcur1 = (float*)newfT;

    hipMemsetAsync(deg, 0, 80000, stream);

    kCnt <<<625, 256, 0, stream>>>(eidx, deg);
    kScan<<<1, 256, 0, stream>>>(deg, off);
    kFill<<<625, 256, 0, stream>>>(eidx, cur, off, elist);
    kPrepA<<<152, 256, 0, stream>>>(w1, w2, wm0, wAt);   // overwrites deg/cur (dead)
    kPrepB<<<dim3(3, 160), 256, 0, stream>>>(l2fo, l2fn, latw,
                                             l2fo + 29184, l2fn + 29184, finw, wm1, Bt);

    kA0<<<625, 256, 0, stream>>>(ea, eemb, nat, elen, w0, eidx, h08, latf8s, eaT, cutb);
    kAm<<<2500, 256, 0, stream>>>(h08, wAt, cutb, latf8s, winiF, wcur0);
    kEnvG<<<352, 256, 0, stream>>>(wcur0, ea, off, elist, envl + 0, env0);
    kC1<<<625, 256, 0, stream>>>(winiF, eaT, env0, eidx, newfT, latf8s);

    kF0<<<2500, 256, 0, stream>>>(latf8s, Bt, winiF, eaT, newfT, feat1T);
    kF3<<<2500, 256, 0, stream>>>(latf8s, Bt, cutb, wcur1);
    kEnvG<<<352, 256, 0, stream>>>(wcur1, ea, off, elist, envl + 192, env1);
    kE1<<<625, 256, 0, stream>>>(feat1T, env1, eidx, newfT, latf8s);
    kF2<<<2500, 256, 0, stream>>>(latf8s, Bt, feat1T, newfT, (float*)d_out);
}